// Round 1
// baseline (4540.585 us; speedup 1.0000x reference)
//
#include <hip/hip_runtime.h>
#include <math.h>

// Problem constants (structural)
#define HCH 256   // H*C
#define NHD 4     // heads
#define CCH 64    // channels per head

__device__ __forceinline__ unsigned fmap(float f){
  unsigned b = __float_as_uint(f);
  return (b & 0x80000000u) ? ~b : (b | 0x80000000u);
}
__device__ __forceinline__ float funmap(unsigned u){
  unsigned b = (u & 0x80000000u) ? (u ^ 0x80000000u) : ~u;
  return __uint_as_float(b);
}
__device__ __forceinline__ float eluf(float x){ return x > 0.f ? x : (expf(x) - 1.f); }

// ---------------- GAT1 GEMM: x[N,10] @ W1[10,256] + es/ed epilogue ----------------
__global__ void k_gemm1(const float* __restrict__ x, const float* __restrict__ W1,
                        const float* __restrict__ a_s, const float* __restrict__ a_d,
                        float* __restrict__ hW, float* __restrict__ es, float* __restrict__ ed,
                        int n)
{
  __shared__ float xl[4][10];
  int tid = threadIdx.x;
  int n0 = blockIdx.x * 4;
  if (tid < 40) {
    int m = tid / 10, k = tid % 10;
    int nn = n0 + m;
    xl[m][k] = (nn < n) ? x[(size_t)nn * 10 + k] : 0.f;
  }
  __syncthreads();
  float acc[4] = {0.f, 0.f, 0.f, 0.f};
  #pragma unroll
  for (int k = 0; k < 10; k++) {
    float w = W1[k * 256 + tid];
    acc[0] += xl[0][k] * w; acc[1] += xl[1][k] * w;
    acc[2] += xl[2][k] * w; acc[3] += xl[3][k] * w;
  }
  int wave = tid >> 6, lane = tid & 63;
  float sa = a_s[tid], da = a_d[tid];
  #pragma unroll
  for (int m = 0; m < 4; m++) {
    int nn = n0 + m;
    float pes = acc[m] * sa, ped = acc[m] * da;
    for (int off = 1; off < 64; off <<= 1) {
      pes += __shfl_xor(pes, off, 64);
      ped += __shfl_xor(ped, off, 64);
    }
    if (nn < n) {
      hW[(size_t)nn * 256 + tid] = acc[m];
      if (lane == 0) { es[nn * 4 + wave] = pes; ed[nn * 4 + wave] = ped; }
    }
  }
}

// ---------------- GEMM [N,256]@[256,256] (opt. attention epilogue) ----------------
template<bool ATT>
__global__ void k_gemm256(const float* __restrict__ in, const float* __restrict__ W,
                          float* __restrict__ out, const float* __restrict__ a_s,
                          const float* __restrict__ a_d, float* __restrict__ es,
                          float* __restrict__ ed, int n)
{
  __shared__ float lds[32][256];
  int tid = threadIdx.x;
  int n0 = blockIdx.x * 32;
  for (int r = 0; r < 32; r++)
    lds[r][tid] = (n0 + r < n) ? in[(size_t)(n0 + r) * 256 + tid] : 0.f;
  __syncthreads();
  int wave = tid >> 6, lane = tid & 63;
  int c4 = lane * 4;
  float acc[8][4] = {};
  for (int k0 = 0; k0 < 64; k0++) {
    const float* wp = &W[(size_t)k0 * 4 * 256 + c4];
    float4 w0 = *(const float4*)(wp);
    float4 w1 = *(const float4*)(wp + 256);
    float4 w2 = *(const float4*)(wp + 512);
    float4 w3 = *(const float4*)(wp + 768);
    #pragma unroll
    for (int m = 0; m < 8; m++) {
      float4 h4 = *(const float4*)&lds[wave * 8 + m][k0 * 4];
      acc[m][0] += h4.x * w0.x + h4.y * w1.x + h4.z * w2.x + h4.w * w3.x;
      acc[m][1] += h4.x * w0.y + h4.y * w1.y + h4.z * w2.y + h4.w * w3.y;
      acc[m][2] += h4.x * w0.z + h4.y * w1.z + h4.z * w2.z + h4.w * w3.z;
      acc[m][3] += h4.x * w0.w + h4.y * w1.w + h4.z * w2.w + h4.w * w3.w;
    }
  }
  float4 as4 = make_float4(0,0,0,0), ad4 = make_float4(0,0,0,0);
  if (ATT) { as4 = *(const float4*)&a_s[c4]; ad4 = *(const float4*)&a_d[c4]; }
  #pragma unroll
  for (int m = 0; m < 8; m++) {
    int nn = n0 + wave * 8 + m;
    bool ok = nn < n;
    if (ok)
      *(float4*)&out[(size_t)nn * 256 + c4] = make_float4(acc[m][0], acc[m][1], acc[m][2], acc[m][3]);
    if (ATT) {
      float pes = acc[m][0]*as4.x + acc[m][1]*as4.y + acc[m][2]*as4.z + acc[m][3]*as4.w;
      float ped = acc[m][0]*ad4.x + acc[m][1]*ad4.y + acc[m][2]*ad4.z + acc[m][3]*ad4.w;
      for (int off = 1; off < 16; off <<= 1) {
        pes += __shfl_xor(pes, off, 64);
        ped += __shfl_xor(ped, off, 64);
      }
      if (ok && (lane & 15) == 0) {
        es[nn * 4 + (lane >> 4)] = pes;
        ed[nn * 4 + (lane >> 4)] = ped;
      }
    }
  }
}

// ---------------- GCN GEMM [N,256]@[256,64] ----------------
__global__ void k_gemm64(const float* __restrict__ in, const float* __restrict__ W,
                         float* __restrict__ out, int n)
{
  __shared__ float lds[32][256];
  int tid = threadIdx.x;
  int n0 = blockIdx.x * 32;
  for (int r = 0; r < 32; r++)
    lds[r][tid] = (n0 + r < n) ? in[(size_t)(n0 + r) * 256 + tid] : 0.f;
  __syncthreads();
  int wave = tid >> 6, lane = tid & 63;
  int slot = lane >> 4, cg = (lane & 15) * 4;
  int nb = wave * 8 + slot * 2;
  float acc[2][4] = {};
  for (int k0 = 0; k0 < 64; k0++) {
    const float* wp = &W[(size_t)k0 * 4 * 64 + cg];
    float4 w0 = *(const float4*)(wp);
    float4 w1 = *(const float4*)(wp + 64);
    float4 w2 = *(const float4*)(wp + 128);
    float4 w3 = *(const float4*)(wp + 192);
    #pragma unroll
    for (int m = 0; m < 2; m++) {
      float4 h4 = *(const float4*)&lds[nb + m][k0 * 4];
      acc[m][0] += h4.x * w0.x + h4.y * w1.x + h4.z * w2.x + h4.w * w3.x;
      acc[m][1] += h4.x * w0.y + h4.y * w1.y + h4.z * w2.y + h4.w * w3.y;
      acc[m][2] += h4.x * w0.z + h4.y * w1.z + h4.z * w2.z + h4.w * w3.z;
      acc[m][3] += h4.x * w0.w + h4.y * w1.w + h4.z * w2.w + h4.w * w3.w;
    }
  }
  #pragma unroll
  for (int m = 0; m < 2; m++) {
    int nn = n0 + nb + m;
    if (nn < n)
      *(float4*)&out[(size_t)nn * 64 + cg] = make_float4(acc[m][0], acc[m][1], acc[m][2], acc[m][3]);
  }
}

// ---------------- Edge pass 1: att = lrelu(es[src]+ed[dst]); segment max ----------------
__global__ void k_att_p1(const int* __restrict__ ei, const float* __restrict__ es,
                         const float* __restrict__ ed, float* __restrict__ eatt,
                         unsigned* __restrict__ mu, int ne, int n, int tot4)
{
  int t = blockIdx.x * 256 + threadIdx.x;
  if (t >= tot4) return;
  int e = t >> 2, hd = t & 3;
  int src, dst;
  if (e < ne) { src = ei[e]; dst = ei[ne + e]; } else { src = dst = e - ne; }
  float a = es[src * 4 + hd] + ed[dst * 4 + hd];
  a = a > 0.f ? a : 0.2f * a;
  eatt[t] = a;
  atomicMax(&mu[dst * 4 + hd], fmap(a));
}

// ---------------- Edge pass 2: s += exp(att - m) ----------------
__global__ void k_att_p2(const int* __restrict__ ei, const float* __restrict__ eatt,
                         const unsigned* __restrict__ mu, float* __restrict__ s,
                         int ne, int tot4)
{
  int t = blockIdx.x * 256 + threadIdx.x;
  if (t >= tot4) return;
  int e = t >> 2, hd = t & 3;
  int dst = (e < ne) ? ei[ne + e] : e - ne;
  float ex = expf(eatt[t] - funmap(mu[dst * 4 + hd]));
  atomicAdd(&s[dst * 4 + hd], ex);
}

// ---------------- Edge pass 3: alpha = exp(att-m)/(s+eps), overwrite eatt ----------------
__global__ void k_alpha(const int* __restrict__ ei, float* __restrict__ eatt,
                        const unsigned* __restrict__ mu, const float* __restrict__ s,
                        int ne, int tot4)
{
  int t = blockIdx.x * 256 + threadIdx.x;
  if (t >= tot4) return;
  int e = t >> 2, hd = t & 3;
  int dst = (e < ne) ? ei[ne + e] : e - ne;
  float ex = expf(eatt[t] - funmap(mu[dst * 4 + hd]));
  eatt[t] = ex / (s[dst * 4 + hd] + 1e-16f);
}

// ---------------- Edge pass 4: acc[dst] += hW[src] * alpha (wave per edge) ----------------
__global__ void k_scatter(const int* __restrict__ ei, const float* __restrict__ eatt,
                          const float* __restrict__ hW, float* __restrict__ acc,
                          int ne, int e2)
{
  int tid = blockIdx.x * 256 + threadIdx.x;
  int e = tid >> 6;
  if (e >= e2) return;
  int lane = tid & 63;
  int src, dst;
  if (e < ne) { src = ei[e]; dst = ei[ne + e]; } else { src = dst = e - ne; }
  float alpha = eatt[e * 4 + (lane >> 4)];
  float4 h4 = *(const float4*)&hW[(size_t)src * 256 + lane * 4];
  float* ap = &acc[(size_t)dst * 256 + lane * 4];
  atomicAdd(ap + 0, h4.x * alpha);
  atomicAdd(ap + 1, h4.y * alpha);
  atomicAdd(ap + 2, h4.z * alpha);
  atomicAdd(ap + 3, h4.w * alpha);
}

// ---------------- bias + BN(eval) + ELU, vectorized ----------------
__global__ void k_bnelu(const float* __restrict__ in, float* __restrict__ outp,
                        const float* __restrict__ bias, const float* __restrict__ gg,
                        const float* __restrict__ bb, const float* __restrict__ mm,
                        const float* __restrict__ vv, int colmask, int total4)
{
  int i4 = blockIdx.x * 256 + threadIdx.x;
  if (i4 >= total4) return;
  size_t idx = (size_t)i4 * 4;
  int c = (int)(idx & (size_t)colmask);
  float4 v  = *(const float4*)&in[idx];
  float4 bi = *(const float4*)&bias[c];
  float4 g4 = *(const float4*)&gg[c];
  float4 b4 = *(const float4*)&bb[c];
  float4 m4 = *(const float4*)&mm[c];
  float4 v4 = *(const float4*)&vv[c];
  float r0 = ((v.x + bi.x) - m4.x) * rsqrtf(v4.x + 1e-5f) * g4.x + b4.x;
  float r1 = ((v.y + bi.y) - m4.y) * rsqrtf(v4.y + 1e-5f) * g4.y + b4.y;
  float r2 = ((v.z + bi.z) - m4.z) * rsqrtf(v4.z + 1e-5f) * g4.z + b4.z;
  float r3 = ((v.w + bi.w) - m4.w) * rsqrtf(v4.w + 1e-5f) * g4.w + b4.w;
  *(float4*)&outp[idx] = make_float4(eluf(r0), eluf(r1), eluf(r2), eluf(r3));
}

// ---------------- GCN degree ----------------
__global__ void k_deg(const int* __restrict__ ei, float* __restrict__ deg, int ne, int e2)
{
  int t = blockIdx.x * 256 + threadIdx.x;
  if (t >= e2) return;
  if (t < ne) atomicAdd(&deg[ei[ne + t]], 1.f);
  else        atomicAdd(&deg[t - ne], 1.f);
}

// ---------------- GCN scatter: acc3[dst] += xw[src]*norm ----------------
__global__ void k_gcn_scatter(const int* __restrict__ ei, const float* __restrict__ deg,
                              const float* __restrict__ xw, float* __restrict__ acc3,
                              int ne, int e2)
{
  int tid = blockIdx.x * 256 + threadIdx.x;
  int e = tid >> 6;
  if (e >= e2) return;
  int lane = tid & 63;
  int src, dst;
  if (e < ne) { src = ei[e]; dst = ei[ne + e]; } else { src = dst = e - ne; }
  float norm = rsqrtf(fmaxf(deg[src], 1.f)) * rsqrtf(fmaxf(deg[dst], 1.f));
  atomicAdd(&acc3[(size_t)dst * 64 + lane], xw[(size_t)src * 64 + lane] * norm);
}

// ---------------- pooling (sum/max/cnt per graph) ----------------
__global__ void k_pool(const float* __restrict__ hout, const int* __restrict__ batch,
                       float* __restrict__ psum, unsigned* __restrict__ pmaxu,
                       float* __restrict__ cnt, int n)
{
  int node = blockIdx.x * 4 + (threadIdx.x >> 6);
  if (node >= n) return;
  int lane = threadIdx.x & 63;
  int g = batch[node];
  float v = hout[(size_t)node * 64 + lane];
  atomicAdd(&psum[g * 64 + lane], v);
  atomicMax(&pmaxu[g * 64 + lane], fmap(v));
  if (lane == 0) atomicAdd(&cnt[g], 1.f);
}

// ---------------- per-graph heads ----------------
__global__ void k_heads(const float* __restrict__ psum, const unsigned* __restrict__ pmaxu,
                        const float* __restrict__ cnt,
                        const float* __restrict__ Wr, const float* __restrict__ br,
                        const float* __restrict__ Wh1, const float* __restrict__ bh1,
                        const float* __restrict__ Wh2, const float* __restrict__ bh2,
                        const float* __restrict__ Wh3, const float* __restrict__ bh3,
                        const float* __restrict__ Wl1, const float* __restrict__ bl1,
                        const float* __restrict__ Wl2, const float* __restrict__ bl2,
                        const float* __restrict__ We1, const float* __restrict__ be1,
                        const float* __restrict__ We2, const float* __restrict__ be2,
                        float* __restrict__ outp, int xg_off)
{
  __shared__ float cat[128], xg[64], t1[32], t2[16], l1[32], e1[16];
  int g = blockIdx.x, c = threadIdx.x;  // 64 threads
  float cg = cnt[g];
  float mean = psum[g * 64 + c] / fmaxf(cg, 1.f);
  float mx = (cg > 0.f) ? funmap(pmaxu[g * 64 + c]) : 0.f;
  cat[c] = mean; cat[64 + c] = mx;
  __syncthreads();
  float a = br[c];
  for (int i = 0; i < 128; i++) a += cat[i] * Wr[i * 64 + c];
  xg[c] = a;
  outp[xg_off + g * 64 + c] = a;
  __syncthreads();
  if (c < 32) {
    float u = bh1[c]; for (int i = 0; i < 64; i++) u += xg[i] * Wh1[i * 32 + c];
    t1[c] = fmaxf(u, 0.f);
    float v = bl1[c]; for (int i = 0; i < 64; i++) v += xg[i] * Wl1[i * 32 + c];
    l1[c] = fmaxf(v, 0.f);
  }
  __syncthreads();
  if (c < 16) {
    float u = bh2[c]; for (int i = 0; i < 32; i++) u += t1[i] * Wh2[i * 16 + c];
    t2[c] = fmaxf(u, 0.f);
    float v = be1[c]; for (int i = 0; i < 64; i++) v += xg[i] * We1[i * 16 + c];
    e1[c] = fmaxf(v, 0.f);
  }
  __syncthreads();
  if (c < 8) {
    float v = bl2[c]; for (int i = 0; i < 32; i++) v += l1[i] * Wl2[i * 8 + c];
    outp[64 + g * 8 + c] = v;
  }
  if (c == 0) {
    float u = bh3[0]; for (int i = 0; i < 16; i++) u += t2[i] * Wh3[i];
    outp[g] = 100.f / (1.f + expf(-u));
    float v = be2[0]; for (int i = 0; i < 16; i++) v += e1[i] * We2[i];
    outp[576 + g] = v;
  }
}

extern "C" void kernel_launch(void* const* d_in, const int* in_sizes, int n_in,
                              void* d_out, int out_size, void* d_ws, size_t ws_size,
                              hipStream_t stream)
{
  const float* x    = (const float*)d_in[0];
  const int*   ei   = (const int*)d_in[1];
  const int*   batch= (const int*)d_in[2];
  const float* W1   = (const float*)d_in[3];
  const float* as1  = (const float*)d_in[4];
  const float* ad1  = (const float*)d_in[5];
  const float* bi1  = (const float*)d_in[6];
  const float* W2   = (const float*)d_in[7];
  const float* as2  = (const float*)d_in[8];
  const float* ad2  = (const float*)d_in[9];
  const float* bi2  = (const float*)d_in[10];
  const float* bn1g = (const float*)d_in[11];
  const float* bn1b = (const float*)d_in[12];
  const float* bn1m = (const float*)d_in[13];
  const float* bn1v = (const float*)d_in[14];
  const float* bn2g = (const float*)d_in[15];
  const float* bn2b = (const float*)d_in[16];
  const float* bn2m = (const float*)d_in[17];
  const float* bn2v = (const float*)d_in[18];
  const float* bn3g = (const float*)d_in[19];
  const float* bn3b = (const float*)d_in[20];
  const float* bn3m = (const float*)d_in[21];
  const float* bn3v = (const float*)d_in[22];
  const float* Wg   = (const float*)d_in[23];
  const float* bg   = (const float*)d_in[24];
  const float* Wr   = (const float*)d_in[25];
  const float* br   = (const float*)d_in[26];
  const float* Wh1  = (const float*)d_in[27];
  const float* bh1  = (const float*)d_in[28];
  const float* Wh2  = (const float*)d_in[29];
  const float* bh2  = (const float*)d_in[30];
  const float* Wh3  = (const float*)d_in[31];
  const float* bh3  = (const float*)d_in[32];
  const float* Wl1  = (const float*)d_in[33];
  const float* bl1  = (const float*)d_in[34];
  const float* Wl2  = (const float*)d_in[35];
  const float* bl2  = (const float*)d_in[36];
  const float* We1  = (const float*)d_in[37];
  const float* be1  = (const float*)d_in[38];
  const float* We2  = (const float*)d_in[39];
  const float* be2  = (const float*)d_in[40];

  const int n  = in_sizes[2];         // 50000 nodes
  const int ne = in_sizes[1] / 2;     // 500000 edges
  const int e2 = ne + n;              // with self-loops
  const int tot4 = e2 * 4;

  float* ws = (float*)d_ws;
  size_t off = 0;
  float* bufA = ws + off; off += (size_t)n * 256;   // hW (layer1 then layer2)
  float* bufB = ws + off; off += (size_t)n * 256;   // aggregation / activations
  float* eatt = ws + off; off += (size_t)e2 * 4;
  float* es   = ws + off; off += (size_t)n * 4;
  float* ed   = ws + off; off += (size_t)n * 4;
  unsigned* mu = (unsigned*)(ws + off); off += (size_t)n * 4;
  float* sbuf = ws + off; off += (size_t)n * 4;
  float* deg  = ws + off; off += (size_t)n;
  float* cnt  = ws + off; off += 64;
  float* psum = ws + off; off += 64 * 64;
  unsigned* pmaxu = (unsigned*)(ws + off); off += 64 * 64;
  // aliases (bufA is dead after GAT2 scatter)
  float* xw   = bufA;
  float* acc3 = bufA + (size_t)n * 64;

  float* outp = (float*)d_out;
  float* hout = outp + 640;            // node embeddings region
  const int xg_off = 640 + n * 64;     // 3200640

  const int eb  = (tot4 + 255) / 256;
  const int sb  = (e2 * 64 + 255) / 256;
  const int gb1 = (n + 3) / 4;
  const int gb2 = (n + 31) / 32;
  const int bn256 = ((n * 64) + 255) / 256;   // total4 for 256-col bnelu
  const int bn64  = ((n * 16) + 255) / 256;   // total4 for 64-col bnelu

  // ---------- GAT layer 1 ----------
  hipMemsetAsync(mu, 0, (size_t)n * 4 * sizeof(unsigned), stream);
  hipMemsetAsync(sbuf, 0, (size_t)n * 4 * sizeof(float), stream);
  hipMemsetAsync(bufB, 0, (size_t)n * 256 * sizeof(float), stream);
  k_gemm1<<<gb1, 256, 0, stream>>>(x, W1, as1, ad1, bufA, es, ed, n);
  k_att_p1<<<eb, 256, 0, stream>>>(ei, es, ed, eatt, mu, ne, n, tot4);
  k_att_p2<<<eb, 256, 0, stream>>>(ei, eatt, mu, sbuf, ne, tot4);
  k_alpha<<<eb, 256, 0, stream>>>(ei, eatt, mu, sbuf, ne, tot4);
  k_scatter<<<sb, 256, 0, stream>>>(ei, eatt, bufA, bufB, ne, e2);
  k_bnelu<<<bn256, 256, 0, stream>>>(bufB, bufB, bi1, bn1g, bn1b, bn1m, bn1v, 255, n * 64);

  // ---------- GAT layer 2 ----------
  k_gemm256<true><<<gb2, 256, 0, stream>>>(bufB, W2, bufA, as2, ad2, es, ed, n);
  hipMemsetAsync(mu, 0, (size_t)n * 4 * sizeof(unsigned), stream);
  hipMemsetAsync(sbuf, 0, (size_t)n * 4 * sizeof(float), stream);
  hipMemsetAsync(bufB, 0, (size_t)n * 256 * sizeof(float), stream);
  k_att_p1<<<eb, 256, 0, stream>>>(ei, es, ed, eatt, mu, ne, n, tot4);
  k_att_p2<<<eb, 256, 0, stream>>>(ei, eatt, mu, sbuf, ne, tot4);
  k_alpha<<<eb, 256, 0, stream>>>(ei, eatt, mu, sbuf, ne, tot4);
  k_scatter<<<sb, 256, 0, stream>>>(ei, eatt, bufA, bufB, ne, e2);
  k_bnelu<<<bn256, 256, 0, stream>>>(bufB, bufB, bi2, bn2g, bn2b, bn2m, bn2v, 255, n * 64);

  // ---------- GCN ----------
  hipMemsetAsync(deg, 0, (size_t)n * sizeof(float), stream);
  hipMemsetAsync(acc3, 0, (size_t)n * 64 * sizeof(float), stream);
  k_deg<<<(e2 + 255) / 256, 256, 0, stream>>>(ei, deg, ne, e2);
  k_gemm64<<<gb2, 256, 0, stream>>>(bufB, Wg, xw, n);
  k_gcn_scatter<<<(e2 * 64 + 255) / 256, 256, 0, stream>>>(ei, deg, xw, acc3, ne, e2);
  k_bnelu<<<bn64, 256, 0, stream>>>(acc3, hout, bg, bn3g, bn3b, bn3m, bn3v, 63, n * 16);

  // ---------- pooling + heads ----------
  hipMemsetAsync(cnt, 0, 64 * sizeof(float), stream);
  hipMemsetAsync(psum, 0, 64 * 64 * sizeof(float), stream);
  hipMemsetAsync(pmaxu, 0, 64 * 64 * sizeof(unsigned), stream);
  k_pool<<<(n + 3) / 4, 256, 0, stream>>>(hout, batch, psum, pmaxu, cnt, n);
  k_heads<<<64, 64, 0, stream>>>(psum, pmaxu, cnt, Wr, br,
                                 Wh1, bh1, Wh2, bh2, Wh3, bh3,
                                 Wl1, bl1, Wl2, bl2, We1, be1, We2, be2,
                                 outp, xg_off);
}

// Round 2
// 926.026 us; speedup vs baseline: 4.9033x; 4.9033x over previous
//
#include <hip/hip_runtime.h>
#include <math.h>

#define SCAN_BLK 1024

__device__ __forceinline__ unsigned fmap(float f){
  unsigned b = __float_as_uint(f);
  return (b & 0x80000000u) ? ~b : (b | 0x80000000u);
}
__device__ __forceinline__ float funmap(unsigned u){
  unsigned b = (u & 0x80000000u) ? (u ^ 0x80000000u) : ~u;
  return __uint_as_float(b);
}
__device__ __forceinline__ float eluf(float x){ return x > 0.f ? x : (expf(x) - 1.f); }

// ---------------- CSR build ----------------
__global__ void k_count(const int* __restrict__ ei, int* __restrict__ deg, int ne, int e2)
{
  int t = blockIdx.x * 256 + threadIdx.x;
  if (t >= e2) return;
  int dst = (t < ne) ? ei[ne + t] : t - ne;
  atomicAdd(&deg[dst], 1);
}

__global__ void k_scan1(const int* __restrict__ deg, int* __restrict__ rowptr,
                        int* __restrict__ partials, int n)
{
  __shared__ int sh[SCAN_BLK];
  int t = threadIdx.x, base = blockIdx.x * SCAN_BLK;
  int v = (base + t < n) ? deg[base + t] : 0;
  sh[t] = v;
  __syncthreads();
  for (int off = 1; off < SCAN_BLK; off <<= 1) {
    int u = 0;
    if (t >= off) u = sh[t - off];
    __syncthreads();
    if (t >= off) sh[t] += u;
    __syncthreads();
  }
  if (base + t < n) rowptr[base + t] = sh[t] - v;   // exclusive
  if (t == SCAN_BLK - 1) partials[blockIdx.x] = sh[t];
}

__global__ void k_scan2(int* __restrict__ rowptr, const int* __restrict__ partials, int n)
{
  int base = blockIdx.x * SCAN_BLK;
  int add = 0;
  for (int i = 0; i < blockIdx.x; i++) add += partials[i];
  int t = threadIdx.x;
  if (base + t < n) rowptr[base + t] += add;
}

__global__ void k_fill(const int* __restrict__ ei, const int* __restrict__ rowptr,
                       int* __restrict__ cursor, int* __restrict__ col, int ne, int e2)
{
  int t = blockIdx.x * 256 + threadIdx.x;
  if (t >= e2) return;
  int src, dst;
  if (t < ne) { src = ei[t]; dst = ei[ne + t]; } else { src = dst = t - ne; }
  int pos = rowptr[dst] + atomicAdd(&cursor[dst], 1);
  col[pos] = src;
}

// ---------------- GAT1 GEMM: x[N,10] @ W1[10,256] + es/ed epilogue ----------------
__global__ void k_gemm1(const float* __restrict__ x, const float* __restrict__ W1,
                        const float* __restrict__ a_s, const float* __restrict__ a_d,
                        float* __restrict__ hW, float* __restrict__ es, float* __restrict__ ed,
                        int n)
{
  __shared__ float xl[4][10];
  int tid = threadIdx.x;
  int n0 = blockIdx.x * 4;
  if (tid < 40) {
    int m = tid / 10, k = tid % 10;
    int nn = n0 + m;
    xl[m][k] = (nn < n) ? x[(size_t)nn * 10 + k] : 0.f;
  }
  __syncthreads();
  float acc[4] = {0.f, 0.f, 0.f, 0.f};
  #pragma unroll
  for (int k = 0; k < 10; k++) {
    float w = W1[k * 256 + tid];
    acc[0] += xl[0][k] * w; acc[1] += xl[1][k] * w;
    acc[2] += xl[2][k] * w; acc[3] += xl[3][k] * w;
  }
  int wave = tid >> 6, lane = tid & 63;
  float sa = a_s[tid], da = a_d[tid];
  #pragma unroll
  for (int m = 0; m < 4; m++) {
    int nn = n0 + m;
    float pes = acc[m] * sa, ped = acc[m] * da;
    for (int off = 1; off < 64; off <<= 1) {
      pes += __shfl_xor(pes, off, 64);
      ped += __shfl_xor(ped, off, 64);
    }
    if (nn < n) {
      hW[(size_t)nn * 256 + tid] = acc[m];
      if (lane == 0) { es[nn * 4 + wave] = pes; ed[nn * 4 + wave] = ped; }
    }
  }
}

// ---------------- GEMM [N,256]@[256,256] with attention epilogue ----------------
template<bool ATT>
__global__ void k_gemm256(const float* __restrict__ in, const float* __restrict__ W,
                          float* __restrict__ out, const float* __restrict__ a_s,
                          const float* __restrict__ a_d, float* __restrict__ es,
                          float* __restrict__ ed, int n)
{
  __shared__ float lds[32][256];
  int tid = threadIdx.x;
  int n0 = blockIdx.x * 32;
  for (int r = 0; r < 32; r++)
    lds[r][tid] = (n0 + r < n) ? in[(size_t)(n0 + r) * 256 + tid] : 0.f;
  __syncthreads();
  int wave = tid >> 6, lane = tid & 63;
  int c4 = lane * 4;
  float acc[8][4] = {};
  for (int k0 = 0; k0 < 64; k0++) {
    const float* wp = &W[(size_t)k0 * 4 * 256 + c4];
    float4 w0 = *(const float4*)(wp);
    float4 w1 = *(const float4*)(wp + 256);
    float4 w2 = *(const float4*)(wp + 512);
    float4 w3 = *(const float4*)(wp + 768);
    #pragma unroll
    for (int m = 0; m < 8; m++) {
      float4 h4 = *(const float4*)&lds[wave * 8 + m][k0 * 4];
      acc[m][0] += h4.x * w0.x + h4.y * w1.x + h4.z * w2.x + h4.w * w3.x;
      acc[m][1] += h4.x * w0.y + h4.y * w1.y + h4.z * w2.y + h4.w * w3.y;
      acc[m][2] += h4.x * w0.z + h4.y * w1.z + h4.z * w2.z + h4.w * w3.z;
      acc[m][3] += h4.x * w0.w + h4.y * w1.w + h4.z * w2.w + h4.w * w3.w;
    }
  }
  float4 as4 = make_float4(0,0,0,0), ad4 = make_float4(0,0,0,0);
  if (ATT) { as4 = *(const float4*)&a_s[c4]; ad4 = *(const float4*)&a_d[c4]; }
  #pragma unroll
  for (int m = 0; m < 8; m++) {
    int nn = n0 + wave * 8 + m;
    bool ok = nn < n;
    if (ok)
      *(float4*)&out[(size_t)nn * 256 + c4] = make_float4(acc[m][0], acc[m][1], acc[m][2], acc[m][3]);
    if (ATT) {
      float pes = acc[m][0]*as4.x + acc[m][1]*as4.y + acc[m][2]*as4.z + acc[m][3]*as4.w;
      float ped = acc[m][0]*ad4.x + acc[m][1]*ad4.y + acc[m][2]*ad4.z + acc[m][3]*ad4.w;
      for (int off = 1; off < 16; off <<= 1) {
        pes += __shfl_xor(pes, off, 64);
        ped += __shfl_xor(ped, off, 64);
      }
      if (ok && (lane & 15) == 0) {
        es[nn * 4 + (lane >> 4)] = pes;
        ed[nn * 4 + (lane >> 4)] = ped;
      }
    }
  }
}

// ---------------- GCN GEMM [N,256]@[256,64] ----------------
__global__ void k_gemm64(const float* __restrict__ in, const float* __restrict__ W,
                         float* __restrict__ out, int n)
{
  __shared__ float lds[32][256];
  int tid = threadIdx.x;
  int n0 = blockIdx.x * 32;
  for (int r = 0; r < 32; r++)
    lds[r][tid] = (n0 + r < n) ? in[(size_t)(n0 + r) * 256 + tid] : 0.f;
  __syncthreads();
  int wave = tid >> 6, lane = tid & 63;
  int slot = lane >> 4, cg = (lane & 15) * 4;
  int nb = wave * 8 + slot * 2;
  float acc[2][4] = {};
  for (int k0 = 0; k0 < 64; k0++) {
    const float* wp = &W[(size_t)k0 * 4 * 64 + cg];
    float4 w0 = *(const float4*)(wp);
    float4 w1 = *(const float4*)(wp + 64);
    float4 w2 = *(const float4*)(wp + 128);
    float4 w3 = *(const float4*)(wp + 192);
    #pragma unroll
    for (int m = 0; m < 2; m++) {
      float4 h4 = *(const float4*)&lds[nb + m][k0 * 4];
      acc[m][0] += h4.x * w0.x + h4.y * w1.x + h4.z * w2.x + h4.w * w3.x;
      acc[m][1] += h4.x * w0.y + h4.y * w1.y + h4.z * w2.y + h4.w * w3.y;
      acc[m][2] += h4.x * w0.z + h4.y * w1.z + h4.z * w2.z + h4.w * w3.z;
      acc[m][3] += h4.x * w0.w + h4.y * w1.w + h4.z * w2.w + h4.w * w3.w;
    }
  }
  #pragma unroll
  for (int m = 0; m < 2; m++) {
    int nn = n0 + nb + m;
    if (nn < n)
      *(float4*)&out[(size_t)nn * 64 + cg] = make_float4(acc[m][0], acc[m][1], acc[m][2], acc[m][3]);
  }
}

// ---------------- GAT aggregate: per-dst softmax + gather + BN/ELU ----------------
// one wave per dst node; 4 dsts per 256-thread block
__global__ void k_gat_agg(const int* __restrict__ rowptr, const int* __restrict__ deg,
                          const int* __restrict__ col,
                          const float* __restrict__ es, const float* __restrict__ ed,
                          const float* __restrict__ hW,
                          const float* __restrict__ bias,
                          const float* __restrict__ gg, const float* __restrict__ bb,
                          const float* __restrict__ mm, const float* __restrict__ vv,
                          float* __restrict__ outp, int n)
{
  int d = blockIdx.x * 4 + (threadIdx.x >> 6);
  if (d >= n) return;
  int lane = threadIdx.x & 63;
  int head = lane >> 4, sub = lane & 15;
  int start = rowptr[d], cnt = deg[d];
  float edh = ed[d * 4 + head];

  // phase A: per-head max over incoming edges (16 lanes per head, strided)
  float m = -1e30f;
  for (int i = sub; i < cnt; i += 16) {
    int s = col[start + i];
    float a = es[s * 4 + head] + edh;
    a = a > 0.f ? a : 0.2f * a;
    m = fmaxf(m, a);
  }
  #pragma unroll
  for (int off = 1; off < 16; off <<= 1) m = fmaxf(m, __shfl_xor(m, off, 16));

  // per-head sum of exp
  float ssum = 0.f;
  for (int i = sub; i < cnt; i += 16) {
    int s = col[start + i];
    float a = es[s * 4 + head] + edh;
    a = a > 0.f ? a : 0.2f * a;
    ssum += expf(a - m);
  }
  #pragma unroll
  for (int off = 1; off < 16; off <<= 1) ssum += __shfl_xor(ssum, off, 16);
  float inv_s = 1.f / (ssum + 1e-16f);

  // phase B: weighted gather; lane owns channels c=lane*4..+3 (head = lane>>4)
  float4 acc = make_float4(0.f, 0.f, 0.f, 0.f);
  for (int i = 0; i < cnt; i++) {
    int s = col[start + i];
    float a = es[s * 4 + head] + edh;
    a = a > 0.f ? a : 0.2f * a;
    float alpha = expf(a - m) * inv_s;
    float4 h4 = *(const float4*)&hW[(size_t)s * 256 + lane * 4];
    acc.x += h4.x * alpha; acc.y += h4.y * alpha;
    acc.z += h4.z * alpha; acc.w += h4.w * alpha;
  }
  int c = lane * 4;
  float4 bi = *(const float4*)&bias[c];
  float4 g4 = *(const float4*)&gg[c];
  float4 b4 = *(const float4*)&bb[c];
  float4 m4 = *(const float4*)&mm[c];
  float4 v4 = *(const float4*)&vv[c];
  float r0 = ((acc.x + bi.x) - m4.x) * rsqrtf(v4.x + 1e-5f) * g4.x + b4.x;
  float r1 = ((acc.y + bi.y) - m4.y) * rsqrtf(v4.y + 1e-5f) * g4.y + b4.y;
  float r2 = ((acc.z + bi.z) - m4.z) * rsqrtf(v4.z + 1e-5f) * g4.z + b4.z;
  float r3 = ((acc.w + bi.w) - m4.w) * rsqrtf(v4.w + 1e-5f) * g4.w + b4.w;
  *(float4*)&outp[(size_t)d * 256 + c] =
      make_float4(eluf(r0), eluf(r1), eluf(r2), eluf(r3));
}

// ---------------- GCN aggregate: per-dst gather + BN/ELU ----------------
__global__ void k_gcn_agg(const int* __restrict__ rowptr, const int* __restrict__ deg,
                          const int* __restrict__ col, const float* __restrict__ xw,
                          const float* __restrict__ bias,
                          const float* __restrict__ gg, const float* __restrict__ bb,
                          const float* __restrict__ mm, const float* __restrict__ vv,
                          float* __restrict__ hout, int n)
{
  int d = blockIdx.x * 4 + (threadIdx.x >> 6);
  if (d >= n) return;
  int lane = threadIdx.x & 63;
  int start = rowptr[d], cnt = deg[d];
  float dinvd = rsqrtf(fmaxf((float)cnt, 1.f));
  float acc = 0.f;
  for (int i = 0; i < cnt; i++) {
    int s = col[start + i];
    float norm = rsqrtf(fmaxf((float)deg[s], 1.f)) * dinvd;
    acc += xw[(size_t)s * 64 + lane] * norm;
  }
  float r = ((acc + bias[lane]) - mm[lane]) * rsqrtf(vv[lane] + 1e-5f) * gg[lane] + bb[lane];
  hout[(size_t)d * 64 + lane] = eluf(r);
}

// ---------------- pooling (sum/max/cnt per graph) ----------------
__global__ void k_pool(const float* __restrict__ hout, const int* __restrict__ batch,
                       float* __restrict__ psum, unsigned* __restrict__ pmaxu,
                       float* __restrict__ cnt, int n)
{
  int node = blockIdx.x * 4 + (threadIdx.x >> 6);
  if (node >= n) return;
  int lane = threadIdx.x & 63;
  int g = batch[node];
  float v = hout[(size_t)node * 64 + lane];
  atomicAdd(&psum[g * 64 + lane], v);
  atomicMax(&pmaxu[g * 64 + lane], fmap(v));
  if (lane == 0) atomicAdd(&cnt[g], 1.f);
}

// ---------------- per-graph heads ----------------
__global__ void k_heads(const float* __restrict__ psum, const unsigned* __restrict__ pmaxu,
                        const float* __restrict__ cnt,
                        const float* __restrict__ Wr, const float* __restrict__ br,
                        const float* __restrict__ Wh1, const float* __restrict__ bh1,
                        const float* __restrict__ Wh2, const float* __restrict__ bh2,
                        const float* __restrict__ Wh3, const float* __restrict__ bh3,
                        const float* __restrict__ Wl1, const float* __restrict__ bl1,
                        const float* __restrict__ Wl2, const float* __restrict__ bl2,
                        const float* __restrict__ We1, const float* __restrict__ be1,
                        const float* __restrict__ We2, const float* __restrict__ be2,
                        float* __restrict__ outp, int xg_off)
{
  __shared__ float cat[128], xg[64], t1[32], t2[16], l1[32], e1[16];
  int g = blockIdx.x, c = threadIdx.x;  // 64 threads
  float cg = cnt[g];
  float mean = psum[g * 64 + c] / fmaxf(cg, 1.f);
  float mx = (cg > 0.f) ? funmap(pmaxu[g * 64 + c]) : 0.f;
  cat[c] = mean; cat[64 + c] = mx;
  __syncthreads();
  float a = br[c];
  for (int i = 0; i < 128; i++) a += cat[i] * Wr[i * 64 + c];
  xg[c] = a;
  outp[xg_off + g * 64 + c] = a;
  __syncthreads();
  if (c < 32) {
    float u = bh1[c]; for (int i = 0; i < 64; i++) u += xg[i] * Wh1[i * 32 + c];
    t1[c] = fmaxf(u, 0.f);
    float v = bl1[c]; for (int i = 0; i < 64; i++) v += xg[i] * Wl1[i * 32 + c];
    l1[c] = fmaxf(v, 0.f);
  }
  __syncthreads();
  if (c < 16) {
    float u = bh2[c]; for (int i = 0; i < 32; i++) u += t1[i] * Wh2[i * 16 + c];
    t2[c] = fmaxf(u, 0.f);
    float v = be1[c]; for (int i = 0; i < 64; i++) v += xg[i] * We1[i * 16 + c];
    e1[c] = fmaxf(v, 0.f);
  }
  __syncthreads();
  if (c < 8) {
    float v = bl2[c]; for (int i = 0; i < 32; i++) v += l1[i] * Wl2[i * 8 + c];
    outp[64 + g * 8 + c] = v;
  }
  if (c == 0) {
    float u = bh3[0]; for (int i = 0; i < 16; i++) u += t2[i] * Wh3[i];
    outp[g] = 100.f / (1.f + expf(-u));
    float v = be2[0]; for (int i = 0; i < 16; i++) v += e1[i] * We2[i];
    outp[576 + g] = v;
  }
}

extern "C" void kernel_launch(void* const* d_in, const int* in_sizes, int n_in,
                              void* d_out, int out_size, void* d_ws, size_t ws_size,
                              hipStream_t stream)
{
  const float* x    = (const float*)d_in[0];
  const int*   ei   = (const int*)d_in[1];
  const int*   batch= (const int*)d_in[2];
  const float* W1   = (const float*)d_in[3];
  const float* as1  = (const float*)d_in[4];
  const float* ad1  = (const float*)d_in[5];
  const float* bi1  = (const float*)d_in[6];
  const float* W2   = (const float*)d_in[7];
  const float* as2  = (const float*)d_in[8];
  const float* ad2  = (const float*)d_in[9];
  const float* bi2  = (const float*)d_in[10];
  const float* bn1g = (const float*)d_in[11];
  const float* bn1b = (const float*)d_in[12];
  const float* bn1m = (const float*)d_in[13];
  const float* bn1v = (const float*)d_in[14];
  const float* bn2g = (const float*)d_in[15];
  const float* bn2b = (const float*)d_in[16];
  const float* bn2m = (const float*)d_in[17];
  const float* bn2v = (const float*)d_in[18];
  const float* bn3g = (const float*)d_in[19];
  const float* bn3b = (const float*)d_in[20];
  const float* bn3m = (const float*)d_in[21];
  const float* bn3v = (const float*)d_in[22];
  const float* Wg   = (const float*)d_in[23];
  const float* bg   = (const float*)d_in[24];
  const float* Wr   = (const float*)d_in[25];
  const float* br   = (const float*)d_in[26];
  const float* Wh1  = (const float*)d_in[27];
  const float* bh1  = (const float*)d_in[28];
  const float* Wh2  = (const float*)d_in[29];
  const float* bh2  = (const float*)d_in[30];
  const float* Wh3  = (const float*)d_in[31];
  const float* bh3  = (const float*)d_in[32];
  const float* Wl1  = (const float*)d_in[33];
  const float* bl1  = (const float*)d_in[34];
  const float* Wl2  = (const float*)d_in[35];
  const float* bl2  = (const float*)d_in[36];
  const float* We1  = (const float*)d_in[37];
  const float* be1  = (const float*)d_in[38];
  const float* We2  = (const float*)d_in[39];
  const float* be2  = (const float*)d_in[40];

  const int n  = in_sizes[2];         // 50000 nodes
  const int ne = in_sizes[1] / 2;     // 500000 edges
  const int e2 = ne + n;              // with self-loops

  float* ws = (float*)d_ws;
  size_t off = 0;
  float* bufA = ws + off; off += (size_t)n * 256;   // hW (layer1 then layer2)
  float* bufB = ws + off; off += (size_t)n * 256;   // activations
  float* es   = ws + off; off += (size_t)n * 4;
  float* ed   = ws + off; off += (size_t)n * 4;
  int* rowptr = (int*)(ws + off); off += (size_t)n + 1;
  int* deg    = (int*)(ws + off); off += (size_t)n;
  int* cursor = (int*)(ws + off); off += (size_t)n;
  int* col    = (int*)(ws + off); off += (size_t)e2;
  int* partials = (int*)(ws + off); off += 64;
  float* cnt  = ws + off; off += 64;
  float* psum = ws + off; off += 64 * 64;
  unsigned* pmaxu = (unsigned*)(ws + off); off += 64 * 64;
  float* xw = bufA;   // alias: bufA dead after GAT2 aggregate

  float* outp = (float*)d_out;
  float* hout = outp + 640;            // node embeddings region
  const int xg_off = 640 + n * 64;

  const int eb   = (e2 + 255) / 256;
  const int gb1  = (n + 3) / 4;        // 4 nodes per block kernels
  const int gb2  = (n + 31) / 32;
  const int nsb  = (n + SCAN_BLK - 1) / SCAN_BLK;

  // ---------- CSR build (by destination) ----------
  hipMemsetAsync(deg, 0, (size_t)n * sizeof(int), stream);
  hipMemsetAsync(cursor, 0, (size_t)n * sizeof(int), stream);
  k_count<<<eb, 256, 0, stream>>>(ei, deg, ne, e2);
  k_scan1<<<nsb, SCAN_BLK, 0, stream>>>(deg, rowptr, partials, n);
  k_scan2<<<nsb, SCAN_BLK, 0, stream>>>(rowptr, partials, n);
  k_fill<<<eb, 256, 0, stream>>>(ei, rowptr, cursor, col, ne, e2);

  // ---------- GAT layer 1 ----------
  k_gemm1<<<gb1, 256, 0, stream>>>(x, W1, as1, ad1, bufA, es, ed, n);
  k_gat_agg<<<gb1, 256, 0, stream>>>(rowptr, deg, col, es, ed, bufA,
                                     bi1, bn1g, bn1b, bn1m, bn1v, bufB, n);

  // ---------- GAT layer 2 ----------
  k_gemm256<true><<<gb2, 256, 0, stream>>>(bufB, W2, bufA, as2, ad2, es, ed, n);
  k_gat_agg<<<gb1, 256, 0, stream>>>(rowptr, deg, col, es, ed, bufA,
                                     bi2, bn2g, bn2b, bn2m, bn2v, bufB, n);

  // ---------- GCN ----------
  k_gemm64<<<gb2, 256, 0, stream>>>(bufB, Wg, xw, n);
  k_gcn_agg<<<gb1, 256, 0, stream>>>(rowptr, deg, col, xw,
                                     bg, bn3g, bn3b, bn3m, bn3v, hout, n);

  // ---------- pooling + heads ----------
  hipMemsetAsync(cnt, 0, 64 * sizeof(float), stream);
  hipMemsetAsync(psum, 0, 64 * 64 * sizeof(float), stream);
  hipMemsetAsync(pmaxu, 0, 64 * 64 * sizeof(unsigned), stream);
  k_pool<<<gb1, 256, 0, stream>>>(hout, batch, psum, pmaxu, cnt, n);
  k_heads<<<64, 64, 0, stream>>>(psum, pmaxu, cnt, Wr, br,
                                 Wh1, bh1, Wh2, bh2, Wh3, bh3,
                                 Wl1, bl1, Wl2, bl2, We1, be1, We2, be2,
                                 outp, xg_off);
}

// Round 3
// 606.395 us; speedup vs baseline: 7.4878x; 1.5271x over previous
//
#include <hip/hip_runtime.h>
#include <math.h>

#define SCAN_BLK 1024

__device__ __forceinline__ float eluf(float x){ return x > 0.f ? x : (expf(x) - 1.f); }

// ---------------- CSR build ----------------
__global__ void k_count(const int* __restrict__ ei, int* __restrict__ deg, int ne, int e2)
{
  int t = blockIdx.x * 256 + threadIdx.x;
  if (t >= e2) return;
  int dst = (t < ne) ? ei[ne + t] : t - ne;
  atomicAdd(&deg[dst], 1);
}

__global__ void k_scan1(const int* __restrict__ deg, int* __restrict__ rowptr,
                        int* __restrict__ partials, int n)
{
  __shared__ int sh[SCAN_BLK];
  int t = threadIdx.x, base = blockIdx.x * SCAN_BLK;
  int v = (base + t < n) ? deg[base + t] : 0;
  sh[t] = v;
  __syncthreads();
  for (int off = 1; off < SCAN_BLK; off <<= 1) {
    int u = 0;
    if (t >= off) u = sh[t - off];
    __syncthreads();
    if (t >= off) sh[t] += u;
    __syncthreads();
  }
  if (base + t < n) rowptr[base + t] = sh[t] - v;   // exclusive
  if (t == SCAN_BLK - 1) partials[blockIdx.x] = sh[t];
}

__global__ void k_scan2(int* __restrict__ rowptr, const int* __restrict__ partials, int n)
{
  int base = blockIdx.x * SCAN_BLK;
  int add = 0;
  for (int i = 0; i < blockIdx.x; i++) add += partials[i];
  int t = threadIdx.x;
  if (base + t < n) rowptr[base + t] += add;
}

__global__ void k_fill(const int* __restrict__ ei, const int* __restrict__ rowptr,
                       int* __restrict__ cursor, int* __restrict__ col, int ne, int e2)
{
  int t = blockIdx.x * 256 + threadIdx.x;
  if (t >= e2) return;
  int src, dst;
  if (t < ne) { src = ei[t]; dst = ei[ne + t]; } else { src = dst = t - ne; }
  int pos = rowptr[dst] + atomicAdd(&cursor[dst], 1);
  col[pos] = src;
}

// ---------------- GAT1 GEMM: x[N,10] @ W1[10,256] + es/ed epilogue ----------------
__global__ void k_gemm1(const float* __restrict__ x, const float* __restrict__ W1,
                        const float* __restrict__ a_s, const float* __restrict__ a_d,
                        float* __restrict__ hW, float* __restrict__ es, float* __restrict__ ed,
                        int n)
{
  __shared__ float xl[4][10];
  int tid = threadIdx.x;
  int n0 = blockIdx.x * 4;
  if (tid < 40) {
    int m = tid / 10, k = tid % 10;
    int nn = n0 + m;
    xl[m][k] = (nn < n) ? x[(size_t)nn * 10 + k] : 0.f;
  }
  __syncthreads();
  float acc[4] = {0.f, 0.f, 0.f, 0.f};
  #pragma unroll
  for (int k = 0; k < 10; k++) {
    float w = W1[k * 256 + tid];
    acc[0] += xl[0][k] * w; acc[1] += xl[1][k] * w;
    acc[2] += xl[2][k] * w; acc[3] += xl[3][k] * w;
  }
  int wave = tid >> 6, lane = tid & 63;
  float sa = a_s[tid], da = a_d[tid];
  #pragma unroll
  for (int m = 0; m < 4; m++) {
    int nn = n0 + m;
    float pes = acc[m] * sa, ped = acc[m] * da;
    for (int off = 1; off < 64; off <<= 1) {
      pes += __shfl_xor(pes, off, 64);
      ped += __shfl_xor(ped, off, 64);
    }
    if (nn < n) {
      hW[(size_t)nn * 256 + tid] = acc[m];
      if (lane == 0) { es[nn * 4 + wave] = pes; ed[nn * 4 + wave] = ped; }
    }
  }
}

// ---------------- GEMM [N,256]@[256,256] with attention epilogue ----------------
template<bool ATT>
__global__ void k_gemm256(const float* __restrict__ in, const float* __restrict__ W,
                          float* __restrict__ out, const float* __restrict__ a_s,
                          const float* __restrict__ a_d, float* __restrict__ es,
                          float* __restrict__ ed, int n)
{
  __shared__ float lds[32][256];
  int tid = threadIdx.x;
  int n0 = blockIdx.x * 32;
  for (int r = 0; r < 32; r++)
    lds[r][tid] = (n0 + r < n) ? in[(size_t)(n0 + r) * 256 + tid] : 0.f;
  __syncthreads();
  int wave = tid >> 6, lane = tid & 63;
  int c4 = lane * 4;
  float acc[8][4] = {};
  for (int k0 = 0; k0 < 64; k0++) {
    const float* wp = &W[(size_t)k0 * 4 * 256 + c4];
    float4 w0 = *(const float4*)(wp);
    float4 w1 = *(const float4*)(wp + 256);
    float4 w2 = *(const float4*)(wp + 512);
    float4 w3 = *(const float4*)(wp + 768);
    #pragma unroll
    for (int m = 0; m < 8; m++) {
      float4 h4 = *(const float4*)&lds[wave * 8 + m][k0 * 4];
      acc[m][0] += h4.x * w0.x + h4.y * w1.x + h4.z * w2.x + h4.w * w3.x;
      acc[m][1] += h4.x * w0.y + h4.y * w1.y + h4.z * w2.y + h4.w * w3.y;
      acc[m][2] += h4.x * w0.z + h4.y * w1.z + h4.z * w2.z + h4.w * w3.z;
      acc[m][3] += h4.x * w0.w + h4.y * w1.w + h4.z * w2.w + h4.w * w3.w;
    }
  }
  float4 as4 = make_float4(0,0,0,0), ad4 = make_float4(0,0,0,0);
  if (ATT) { as4 = *(const float4*)&a_s[c4]; ad4 = *(const float4*)&a_d[c4]; }
  #pragma unroll
  for (int m = 0; m < 8; m++) {
    int nn = n0 + wave * 8 + m;
    bool ok = nn < n;
    if (ok)
      *(float4*)&out[(size_t)nn * 256 + c4] = make_float4(acc[m][0], acc[m][1], acc[m][2], acc[m][3]);
    if (ATT) {
      float pes = acc[m][0]*as4.x + acc[m][1]*as4.y + acc[m][2]*as4.z + acc[m][3]*as4.w;
      float ped = acc[m][0]*ad4.x + acc[m][1]*ad4.y + acc[m][2]*ad4.z + acc[m][3]*ad4.w;
      for (int off = 1; off < 16; off <<= 1) {
        pes += __shfl_xor(pes, off, 64);
        ped += __shfl_xor(ped, off, 64);
      }
      if (ok && (lane & 15) == 0) {
        es[nn * 4 + (lane >> 4)] = pes;
        ed[nn * 4 + (lane >> 4)] = ped;
      }
    }
  }
}

// ---------------- GCN GEMM [N,256]@[256,64] ----------------
__global__ void k_gemm64(const float* __restrict__ in, const float* __restrict__ W,
                         float* __restrict__ out, int n)
{
  __shared__ float lds[32][256];
  int tid = threadIdx.x;
  int n0 = blockIdx.x * 32;
  for (int r = 0; r < 32; r++)
    lds[r][tid] = (n0 + r < n) ? in[(size_t)(n0 + r) * 256 + tid] : 0.f;
  __syncthreads();
  int wave = tid >> 6, lane = tid & 63;
  int slot = lane >> 4, cg = (lane & 15) * 4;
  int nb = wave * 8 + slot * 2;
  float acc[2][4] = {};
  for (int k0 = 0; k0 < 64; k0++) {
    const float* wp = &W[(size_t)k0 * 4 * 64 + cg];
    float4 w0 = *(const float4*)(wp);
    float4 w1 = *(const float4*)(wp + 64);
    float4 w2 = *(const float4*)(wp + 128);
    float4 w3 = *(const float4*)(wp + 192);
    #pragma unroll
    for (int m = 0; m < 2; m++) {
      float4 h4 = *(const float4*)&lds[nb + m][k0 * 4];
      acc[m][0] += h4.x * w0.x + h4.y * w1.x + h4.z * w2.x + h4.w * w3.x;
      acc[m][1] += h4.x * w0.y + h4.y * w1.y + h4.z * w2.y + h4.w * w3.y;
      acc[m][2] += h4.x * w0.z + h4.y * w1.z + h4.z * w2.z + h4.w * w3.z;
      acc[m][3] += h4.x * w0.w + h4.y * w1.w + h4.z * w2.w + h4.w * w3.w;
    }
  }
  #pragma unroll
  for (int m = 0; m < 2; m++) {
    int nn = n0 + nb + m;
    if (nn < n)
      *(float4*)&out[(size_t)nn * 64 + cg] = make_float4(acc[m][0], acc[m][1], acc[m][2], acc[m][3]);
  }
}

// ---------------- GAT aggregate: per-dst softmax + gather + BN/ELU ----------------
__global__ void k_gat_agg(const int* __restrict__ rowptr, const int* __restrict__ deg,
                          const int* __restrict__ col,
                          const float* __restrict__ es, const float* __restrict__ ed,
                          const float* __restrict__ hW,
                          const float* __restrict__ bias,
                          const float* __restrict__ gg, const float* __restrict__ bb,
                          const float* __restrict__ mm, const float* __restrict__ vv,
                          float* __restrict__ outp, int n)
{
  int d = blockIdx.x * 4 + (threadIdx.x >> 6);
  if (d >= n) return;
  int lane = threadIdx.x & 63;
  int head = lane >> 4, sub = lane & 15;
  int start = rowptr[d], cnt = deg[d];
  float edh = ed[d * 4 + head];

  float m = -1e30f;
  for (int i = sub; i < cnt; i += 16) {
    int s = col[start + i];
    float a = es[s * 4 + head] + edh;
    a = a > 0.f ? a : 0.2f * a;
    m = fmaxf(m, a);
  }
  #pragma unroll
  for (int off = 1; off < 16; off <<= 1) m = fmaxf(m, __shfl_xor(m, off, 16));

  float ssum = 0.f;
  for (int i = sub; i < cnt; i += 16) {
    int s = col[start + i];
    float a = es[s * 4 + head] + edh;
    a = a > 0.f ? a : 0.2f * a;
    ssum += expf(a - m);
  }
  #pragma unroll
  for (int off = 1; off < 16; off <<= 1) ssum += __shfl_xor(ssum, off, 16);
  float inv_s = 1.f / (ssum + 1e-16f);

  float4 acc = make_float4(0.f, 0.f, 0.f, 0.f);
  for (int i = 0; i < cnt; i++) {
    int s = col[start + i];
    float a = es[s * 4 + head] + edh;
    a = a > 0.f ? a : 0.2f * a;
    float alpha = expf(a - m) * inv_s;
    float4 h4 = *(const float4*)&hW[(size_t)s * 256 + lane * 4];
    acc.x += h4.x * alpha; acc.y += h4.y * alpha;
    acc.z += h4.z * alpha; acc.w += h4.w * alpha;
  }
  int c = lane * 4;
  float4 bi = *(const float4*)&bias[c];
  float4 g4 = *(const float4*)&gg[c];
  float4 b4 = *(const float4*)&bb[c];
  float4 m4 = *(const float4*)&mm[c];
  float4 v4 = *(const float4*)&vv[c];
  float r0 = ((acc.x + bi.x) - m4.x) * rsqrtf(v4.x + 1e-5f) * g4.x + b4.x;
  float r1 = ((acc.y + bi.y) - m4.y) * rsqrtf(v4.y + 1e-5f) * g4.y + b4.y;
  float r2 = ((acc.z + bi.z) - m4.z) * rsqrtf(v4.z + 1e-5f) * g4.z + b4.z;
  float r3 = ((acc.w + bi.w) - m4.w) * rsqrtf(v4.w + 1e-5f) * g4.w + b4.w;
  *(float4*)&outp[(size_t)d * 256 + c] =
      make_float4(eluf(r0), eluf(r1), eluf(r2), eluf(r3));
}

// ---------------- GCN aggregate: per-dst gather + BN/ELU ----------------
__global__ void k_gcn_agg(const int* __restrict__ rowptr, const int* __restrict__ deg,
                          const int* __restrict__ col, const float* __restrict__ xw,
                          const float* __restrict__ bias,
                          const float* __restrict__ gg, const float* __restrict__ bb,
                          const float* __restrict__ mm, const float* __restrict__ vv,
                          float* __restrict__ hout, int n)
{
  int d = blockIdx.x * 4 + (threadIdx.x >> 6);
  if (d >= n) return;
  int lane = threadIdx.x & 63;
  int start = rowptr[d], cnt = deg[d];
  float dinvd = rsqrtf(fmaxf((float)cnt, 1.f));
  float acc = 0.f;
  for (int i = 0; i < cnt; i++) {
    int s = col[start + i];
    float norm = rsqrtf(fmaxf((float)deg[s], 1.f)) * dinvd;
    acc += xw[(size_t)s * 64 + lane] * norm;
  }
  float r = ((acc + bias[lane]) - mm[lane]) * rsqrtf(vv[lane] + 1e-5f) * gg[lane] + bb[lane];
  hout[(size_t)d * 64 + lane] = eluf(r);
}

// ---------------- fused pooling + heads: one block per graph ----------------
// batch is sorted; block g binary-searches its node range, reduces sum/max
// in registers + LDS (no atomics), then computes all three MLP heads.
__global__ void k_poolheads(const float* __restrict__ hout, const int* __restrict__ batch,
                            const float* __restrict__ Wr, const float* __restrict__ br,
                            const float* __restrict__ Wh1, const float* __restrict__ bh1,
                            const float* __restrict__ Wh2, const float* __restrict__ bh2,
                            const float* __restrict__ Wh3, const float* __restrict__ bh3,
                            const float* __restrict__ Wl1, const float* __restrict__ bl1,
                            const float* __restrict__ Wl2, const float* __restrict__ bl2,
                            const float* __restrict__ We1, const float* __restrict__ be1,
                            const float* __restrict__ We2, const float* __restrict__ be2,
                            float* __restrict__ outp, int n, int xg_off)
{
  __shared__ float ssum[4][64], smax[4][64];
  __shared__ float cat[128], xg[64], t1[32], t2[16], l1[32], e1[16];
  int g = blockIdx.x;
  int tid = threadIdx.x, wave = tid >> 6, lane = tid & 63;

  // lower_bound(batch, g) and lower_bound(batch, g+1)
  int lo = 0, hi = n;
  while (lo < hi) { int mid = (lo + hi) >> 1; if (batch[mid] < g) lo = mid + 1; else hi = mid; }
  int start = lo;
  lo = start; hi = n;
  while (lo < hi) { int mid = (lo + hi) >> 1; if (batch[mid] < g + 1) lo = mid + 1; else hi = mid; }
  int end = lo;
  int cntg = end - start;

  float s = 0.f, mx = -1e30f;
  for (int node = start + wave; node < end; node += 4) {
    float v = hout[(size_t)node * 64 + lane];
    s += v;
    mx = fmaxf(mx, v);
  }
  ssum[wave][lane] = s;
  smax[wave][lane] = mx;
  __syncthreads();

  int c = tid;  // only first 64 threads proceed to heads
  if (c < 64) {
    float su = ssum[0][c] + ssum[1][c] + ssum[2][c] + ssum[3][c];
    float mu = fmaxf(fmaxf(ssum[0][c] * 0.f - 1e30f, smax[0][c]),
                     fmaxf(smax[1][c], fmaxf(smax[2][c], smax[3][c])));
    float mean = su / fmaxf((float)cntg, 1.f);
    float mxv = (cntg > 0) ? mu : 0.f;
    cat[c] = mean; cat[64 + c] = mxv;
  }
  __syncthreads();
  if (c < 64) {
    float a = br[c];
    for (int i = 0; i < 128; i++) a += cat[i] * Wr[i * 64 + c];
    xg[c] = a;
    outp[xg_off + g * 64 + c] = a;
  }
  __syncthreads();
  if (c < 32) {
    float u = bh1[c]; for (int i = 0; i < 64; i++) u += xg[i] * Wh1[i * 32 + c];
    t1[c] = fmaxf(u, 0.f);
    float v = bl1[c]; for (int i = 0; i < 64; i++) v += xg[i] * Wl1[i * 32 + c];
    l1[c] = fmaxf(v, 0.f);
  }
  __syncthreads();
  if (c < 16) {
    float u = bh2[c]; for (int i = 0; i < 32; i++) u += t1[i] * Wh2[i * 16 + c];
    t2[c] = fmaxf(u, 0.f);
    float v = be1[c]; for (int i = 0; i < 64; i++) v += xg[i] * We1[i * 16 + c];
    e1[c] = fmaxf(v, 0.f);
  }
  __syncthreads();
  if (c < 8) {
    float v = bl2[c]; for (int i = 0; i < 32; i++) v += l1[i] * Wl2[i * 8 + c];
    outp[64 + g * 8 + c] = v;
  }
  if (c == 0) {
    float u = bh3[0]; for (int i = 0; i < 16; i++) u += t2[i] * Wh3[i];
    outp[g] = 100.f / (1.f + expf(-u));
    float v = be2[0]; for (int i = 0; i < 16; i++) v += e1[i] * We2[i];
    outp[576 + g] = v;
  }
}

extern "C" void kernel_launch(void* const* d_in, const int* in_sizes, int n_in,
                              void* d_out, int out_size, void* d_ws, size_t ws_size,
                              hipStream_t stream)
{
  const float* x    = (const float*)d_in[0];
  const int*   ei   = (const int*)d_in[1];
  const int*   batch= (const int*)d_in[2];
  const float* W1   = (const float*)d_in[3];
  const float* as1  = (const float*)d_in[4];
  const float* ad1  = (const float*)d_in[5];
  const float* bi1  = (const float*)d_in[6];
  const float* W2   = (const float*)d_in[7];
  const float* as2  = (const float*)d_in[8];
  const float* ad2  = (const float*)d_in[9];
  const float* bi2  = (const float*)d_in[10];
  const float* bn1g = (const float*)d_in[11];
  const float* bn1b = (const float*)d_in[12];
  const float* bn1m = (const float*)d_in[13];
  const float* bn1v = (const float*)d_in[14];
  const float* bn2g = (const float*)d_in[15];
  const float* bn2b = (const float*)d_in[16];
  const float* bn2m = (const float*)d_in[17];
  const float* bn2v = (const float*)d_in[18];
  const float* bn3g = (const float*)d_in[19];
  const float* bn3b = (const float*)d_in[20];
  const float* bn3m = (const float*)d_in[21];
  const float* bn3v = (const float*)d_in[22];
  const float* Wg   = (const float*)d_in[23];
  const float* bg   = (const float*)d_in[24];
  const float* Wr   = (const float*)d_in[25];
  const float* br   = (const float*)d_in[26];
  const float* Wh1  = (const float*)d_in[27];
  const float* bh1  = (const float*)d_in[28];
  const float* Wh2  = (const float*)d_in[29];
  const float* bh2  = (const float*)d_in[30];
  const float* Wh3  = (const float*)d_in[31];
  const float* bh3  = (const float*)d_in[32];
  const float* Wl1  = (const float*)d_in[33];
  const float* bl1  = (const float*)d_in[34];
  const float* Wl2  = (const float*)d_in[35];
  const float* bl2  = (const float*)d_in[36];
  const float* We1  = (const float*)d_in[37];
  const float* be1  = (const float*)d_in[38];
  const float* We2  = (const float*)d_in[39];
  const float* be2  = (const float*)d_in[40];

  const int n  = in_sizes[2];         // 50000 nodes
  const int ne = in_sizes[1] / 2;     // 500000 edges
  const int e2 = ne + n;              // with self-loops

  float* ws = (float*)d_ws;
  size_t off = 0;
  float* bufA = ws + off; off += (size_t)n * 256;   // hW (layer1 then layer2)
  float* bufB = ws + off; off += (size_t)n * 256;   // activations
  float* es   = ws + off; off += (size_t)n * 4;
  float* ed   = ws + off; off += (size_t)n * 4;
  int* rowptr = (int*)(ws + off); off += (size_t)n + 1;
  int* deg    = (int*)(ws + off); off += (size_t)n;
  int* cursor = (int*)(ws + off); off += (size_t)n;
  int* col    = (int*)(ws + off); off += (size_t)e2;
  int* partials = (int*)(ws + off); off += 64;
  float* xw = bufA;   // alias: bufA dead after GAT2 aggregate

  float* outp = (float*)d_out;
  float* hout = outp + 640;            // node embeddings region
  const int xg_off = 640 + n * 64;

  const int eb   = (e2 + 255) / 256;
  const int gb1  = (n + 3) / 4;
  const int gb2  = (n + 31) / 32;
  const int nsb  = (n + SCAN_BLK - 1) / SCAN_BLK;

  // ---------- CSR build (by destination) ----------
  hipMemsetAsync(deg, 0, (size_t)n * sizeof(int), stream);
  hipMemsetAsync(cursor, 0, (size_t)n * sizeof(int), stream);
  k_count<<<eb, 256, 0, stream>>>(ei, deg, ne, e2);
  k_scan1<<<nsb, SCAN_BLK, 0, stream>>>(deg, rowptr, partials, n);
  k_scan2<<<nsb, SCAN_BLK, 0, stream>>>(rowptr, partials, n);
  k_fill<<<eb, 256, 0, stream>>>(ei, rowptr, cursor, col, ne, e2);

  // ---------- GAT layer 1 ----------
  k_gemm1<<<gb1, 256, 0, stream>>>(x, W1, as1, ad1, bufA, es, ed, n);
  k_gat_agg<<<gb1, 256, 0, stream>>>(rowptr, deg, col, es, ed, bufA,
                                     bi1, bn1g, bn1b, bn1m, bn1v, bufB, n);

  // ---------- GAT layer 2 ----------
  k_gemm256<true><<<gb2, 256, 0, stream>>>(bufB, W2, bufA, as2, ad2, es, ed, n);
  k_gat_agg<<<gb1, 256, 0, stream>>>(rowptr, deg, col, es, ed, bufA,
                                     bi2, bn2g, bn2b, bn2m, bn2v, bufB, n);

  // ---------- GCN ----------
  k_gemm64<<<gb2, 256, 0, stream>>>(bufB, Wg, xw, n);
  k_gcn_agg<<<gb1, 256, 0, stream>>>(rowptr, deg, col, xw,
                                     bg, bn3g, bn3b, bn3m, bn3v, hout, n);

  // ---------- fused pooling + heads ----------
  k_poolheads<<<64, 256, 0, stream>>>(hout, batch, Wr, br,
                                      Wh1, bh1, Wh2, bh2, Wh3, bh3,
                                      Wl1, bl1, Wl2, bl2, We1, be1, We2, be2,
                                      outp, n, xg_off);
}

// Round 4
// 487.424 us; speedup vs baseline: 9.3155x; 1.2441x over previous
//
#include <hip/hip_runtime.h>
#include <math.h>

#define SCAN_BLK 1024

typedef __attribute__((ext_vector_type(8))) short short8;
typedef __attribute__((ext_vector_type(4))) short short4v;
typedef __attribute__((ext_vector_type(4))) float f32x4;

__device__ __forceinline__ float eluf(float x){ return x > 0.f ? x : (expf(x) - 1.f); }
__device__ __forceinline__ unsigned short f2bf(float f){
  unsigned u = __float_as_uint(f);
  u += 0x7FFFu + ((u >> 16) & 1u);          // RNE
  return (unsigned short)(u >> 16);
}
__device__ __forceinline__ float bf2f(unsigned short s){
  return __uint_as_float(((unsigned)s) << 16);
}

// ---------------- CSR build ----------------
__global__ void k_count(const int* __restrict__ ei, int* __restrict__ deg, int ne, int e2)
{
  int t = blockIdx.x * 256 + threadIdx.x;
  if (t >= e2) return;
  int dst = (t < ne) ? ei[ne + t] : t - ne;
  atomicAdd(&deg[dst], 1);
}

__global__ void k_scan1(const int* __restrict__ deg, int* __restrict__ rowptr,
                        int* __restrict__ partials, int n)
{
  __shared__ int sh[SCAN_BLK];
  int t = threadIdx.x, base = blockIdx.x * SCAN_BLK;
  int v = (base + t < n) ? deg[base + t] : 0;
  sh[t] = v;
  __syncthreads();
  for (int off = 1; off < SCAN_BLK; off <<= 1) {
    int u = 0;
    if (t >= off) u = sh[t - off];
    __syncthreads();
    if (t >= off) sh[t] += u;
    __syncthreads();
  }
  if (base + t < n) rowptr[base + t] = sh[t] - v;   // exclusive
  if (t == SCAN_BLK - 1) partials[blockIdx.x] = sh[t];
}

__global__ void k_scan2(int* __restrict__ rowptr, const int* __restrict__ partials, int n)
{
  int base = blockIdx.x * SCAN_BLK;
  int add = 0;
  for (int i = 0; i < blockIdx.x; i++) add += partials[i];
  int t = threadIdx.x;
  if (base + t < n) rowptr[base + t] += add;
}

__global__ void k_fill(const int* __restrict__ ei, const int* __restrict__ rowptr,
                       int* __restrict__ cursor, int* __restrict__ col, int ne, int e2)
{
  int t = blockIdx.x * 256 + threadIdx.x;
  if (t >= e2) return;
  int src, dst;
  if (t < ne) { src = ei[t]; dst = ei[ne + t]; } else { src = dst = t - ne; }
  int pos = rowptr[dst] + atomicAdd(&cursor[dst], 1);
  col[pos] = src;
}

// ---------------- weight pack for MFMA B-fragments ----------------
// Wp[((ct*8+ks)*64+lane)*8 + j] = bf16( W[(ks*32 + (lane>>4)*8 + j)*N + ct*16 + (lane&15)] )
__global__ void k_pack(const float* __restrict__ W, unsigned short* __restrict__ Wp, int N)
{
  int tid = threadIdx.x;              // 512
  int l = tid >> 3, j = tid & 7;
  int ct = blockIdx.x >> 3, ks = blockIdx.x & 7;
  int k = ks * 32 + (l >> 4) * 8 + j;
  int c = ct * 16 + (l & 15);
  Wp[(size_t)blockIdx.x * 512 + tid] = f2bf(W[(size_t)k * N + c]);
}

// ---------------- GAT1 GEMM: x[N,10] @ W1[10,256] + es/ed epilogue, bf16 h out ---------
__global__ void k_gemm1(const float* __restrict__ x, const float* __restrict__ W1,
                        const float* __restrict__ a_s, const float* __restrict__ a_d,
                        unsigned short* __restrict__ hWb,
                        float* __restrict__ es, float* __restrict__ ed, int n)
{
  __shared__ float xl[4][10];
  int tid = threadIdx.x;
  int n0 = blockIdx.x * 4;
  if (tid < 40) {
    int m = tid / 10, k = tid % 10;
    int nn = n0 + m;
    xl[m][k] = (nn < n) ? x[(size_t)nn * 10 + k] : 0.f;
  }
  __syncthreads();
  float acc[4] = {0.f, 0.f, 0.f, 0.f};
  #pragma unroll
  for (int k = 0; k < 10; k++) {
    float w = W1[k * 256 + tid];
    acc[0] += xl[0][k] * w; acc[1] += xl[1][k] * w;
    acc[2] += xl[2][k] * w; acc[3] += xl[3][k] * w;
  }
  int wave = tid >> 6, lane = tid & 63;
  float sa = a_s[tid], da = a_d[tid];
  #pragma unroll
  for (int m = 0; m < 4; m++) {
    int nn = n0 + m;
    float pes = acc[m] * sa, ped = acc[m] * da;
    for (int off = 1; off < 64; off <<= 1) {
      pes += __shfl_xor(pes, off, 64);
      ped += __shfl_xor(ped, off, 64);
    }
    if (nn < n) {
      hWb[(size_t)nn * 256 + tid] = f2bf(acc[m]);
      if (lane == 0) { es[nn * 4 + wave] = pes; ed[nn * 4 + wave] = ped; }
    }
  }
}

// ---------------- MFMA GEMM: act[n,256](bf16) @ Wp -> out[n, NCT*16](bf16) -------------
// 4 waves/block, wave handles 16 rows x NCT*16 cols. Optional GAT attention epilogue.
template<int NCT, bool ATT>
__global__ __launch_bounds__(256) void k_mfma_gemm(
    const unsigned short* __restrict__ act, const unsigned short* __restrict__ Wp,
    unsigned short* __restrict__ outb,
    const float* __restrict__ asf, const float* __restrict__ adf,
    float* __restrict__ es, float* __restrict__ ed, int n)
{
  int tid = threadIdx.x, wave = tid >> 6, lane = tid & 63;
  int l15 = lane & 15, lg = lane >> 4;
  int rbase = blockIdx.x * 64 + wave * 16;
  int arow = rbase + l15; if (arow > n - 1) arow = n - 1;
  const unsigned short* ap = &act[(size_t)arow * 256 + lg * 8];

  f32x4 acc[NCT];
  f32x4 z = {0.f, 0.f, 0.f, 0.f};
  #pragma unroll
  for (int ct = 0; ct < NCT; ct++) acc[ct] = z;

  #pragma unroll
  for (int ks = 0; ks < 8; ks++) {
    short8 a = *(const short8*)(ap + ks * 32);
    #pragma unroll
    for (int ct = 0; ct < NCT; ct++) {
      short8 b = *(const short8*)&Wp[(size_t)((ct * 8 + ks) * 64 + lane) * 8];
      acc[ct] = __builtin_amdgcn_mfma_f32_16x16x32_bf16(a, b, acc[ct], 0, 0, 0);
    }
  }

  #pragma unroll
  for (int r = 0; r < 4; r++) {
    int row = rbase + lg * 4 + r;
    if (row < n) {
      #pragma unroll
      for (int ct = 0; ct < NCT; ct++)
        outb[(size_t)row * (NCT * 16) + ct * 16 + l15] = f2bf(acc[ct][r]);
    }
  }

  if (ATT) {
    float asl[NCT], adl[NCT];
    #pragma unroll
    for (int ct = 0; ct < NCT; ct++) {
      asl[ct] = asf[ct * 16 + l15];
      adl[ct] = adf[ct * 16 + l15];
    }
    #pragma unroll
    for (int r = 0; r < 4; r++) {
      int row = rbase + lg * 4 + r;
      #pragma unroll
      for (int hd = 0; hd < 4; hd++) {
        float ps = 0.f, pd = 0.f;
        #pragma unroll
        for (int q = 0; q < 4; q++) {
          ps += acc[hd * 4 + q][r] * asl[hd * 4 + q];
          pd += acc[hd * 4 + q][r] * adl[hd * 4 + q];
        }
        #pragma unroll
        for (int off = 1; off < 16; off <<= 1) {
          ps += __shfl_xor(ps, off, 16);
          pd += __shfl_xor(pd, off, 16);
        }
        if (l15 == 0 && row < n) { es[row * 4 + hd] = ps; ed[row * 4 + hd] = pd; }
      }
    }
  }
}

// ---------------- GAT aggregate: per-dst softmax + bf16 gather + BN/ELU -> bf16 --------
__global__ void k_gat_agg(const int* __restrict__ rowptr, const int* __restrict__ deg,
                          const int* __restrict__ col,
                          const float* __restrict__ es, const float* __restrict__ ed,
                          const unsigned short* __restrict__ hWb,
                          const float* __restrict__ bias,
                          const float* __restrict__ gg, const float* __restrict__ bb,
                          const float* __restrict__ mm, const float* __restrict__ vv,
                          unsigned short* __restrict__ outb, int n)
{
  int d = blockIdx.x * 4 + (threadIdx.x >> 6);
  if (d >= n) return;
  int lane = threadIdx.x & 63;
  int head = lane >> 4, sub = lane & 15;
  int start = rowptr[d], cnt = deg[d];
  float edh = ed[d * 4 + head];

  float m = -1e30f;
  for (int i = sub; i < cnt; i += 16) {
    int s = col[start + i];
    float a = es[s * 4 + head] + edh;
    a = a > 0.f ? a : 0.2f * a;
    m = fmaxf(m, a);
  }
  #pragma unroll
  for (int off = 1; off < 16; off <<= 1) m = fmaxf(m, __shfl_xor(m, off, 16));

  float ssum = 0.f;
  for (int i = sub; i < cnt; i += 16) {
    int s = col[start + i];
    float a = es[s * 4 + head] + edh;
    a = a > 0.f ? a : 0.2f * a;
    ssum += expf(a - m);
  }
  #pragma unroll
  for (int off = 1; off < 16; off <<= 1) ssum += __shfl_xor(ssum, off, 16);
  float inv_s = 1.f / (ssum + 1e-16f);

  float a0 = 0.f, a1 = 0.f, a2 = 0.f, a3 = 0.f;
  for (int i = 0; i < cnt; i++) {
    int s = col[start + i];
    float a = es[s * 4 + head] + edh;
    a = a > 0.f ? a : 0.2f * a;
    float alpha = expf(a - m) * inv_s;
    short4v hv = *(const short4v*)&hWb[(size_t)s * 256 + lane * 4];
    a0 += bf2f((unsigned short)hv[0]) * alpha;
    a1 += bf2f((unsigned short)hv[1]) * alpha;
    a2 += bf2f((unsigned short)hv[2]) * alpha;
    a3 += bf2f((unsigned short)hv[3]) * alpha;
  }
  int c = lane * 4;
  float4 bi = *(const float4*)&bias[c];
  float4 g4 = *(const float4*)&gg[c];
  float4 b4 = *(const float4*)&bb[c];
  float4 m4 = *(const float4*)&mm[c];
  float4 v4 = *(const float4*)&vv[c];
  float r0 = ((a0 + bi.x) - m4.x) * rsqrtf(v4.x + 1e-5f) * g4.x + b4.x;
  float r1 = ((a1 + bi.y) - m4.y) * rsqrtf(v4.y + 1e-5f) * g4.y + b4.y;
  float r2 = ((a2 + bi.z) - m4.z) * rsqrtf(v4.z + 1e-5f) * g4.z + b4.z;
  float r3 = ((a3 + bi.w) - m4.w) * rsqrtf(v4.w + 1e-5f) * g4.w + b4.w;
  short4v o;
  o[0] = (short)f2bf(eluf(r0));
  o[1] = (short)f2bf(eluf(r1));
  o[2] = (short)f2bf(eluf(r2));
  o[3] = (short)f2bf(eluf(r3));
  *(short4v*)&outb[(size_t)d * 256 + c] = o;
}

// ---------------- GCN aggregate: bf16 gather + BN/ELU -> fp32 h ----------------
__global__ void k_gcn_agg(const int* __restrict__ rowptr, const int* __restrict__ deg,
                          const int* __restrict__ col, const unsigned short* __restrict__ xwb,
                          const float* __restrict__ bias,
                          const float* __restrict__ gg, const float* __restrict__ bb,
                          const float* __restrict__ mm, const float* __restrict__ vv,
                          float* __restrict__ hout, int n)
{
  int d = blockIdx.x * 4 + (threadIdx.x >> 6);
  if (d >= n) return;
  int lane = threadIdx.x & 63;
  int start = rowptr[d], cnt = deg[d];
  float dinvd = rsqrtf(fmaxf((float)cnt, 1.f));
  float acc = 0.f;
  for (int i = 0; i < cnt; i++) {
    int s = col[start + i];
    float norm = rsqrtf(fmaxf((float)deg[s], 1.f)) * dinvd;
    acc += bf2f(xwb[(size_t)s * 64 + lane]) * norm;
  }
  float r = ((acc + bias[lane]) - mm[lane]) * rsqrtf(vv[lane] + 1e-5f) * gg[lane] + bb[lane];
  hout[(size_t)d * 64 + lane] = eluf(r);
}

// ---------------- fused pooling + heads: one block per graph ----------------
__global__ void k_poolheads(const float* __restrict__ hout, const int* __restrict__ batch,
                            const float* __restrict__ Wr, const float* __restrict__ br,
                            const float* __restrict__ Wh1, const float* __restrict__ bh1,
                            const float* __restrict__ Wh2, const float* __restrict__ bh2,
                            const float* __restrict__ Wh3, const float* __restrict__ bh3,
                            const float* __restrict__ Wl1, const float* __restrict__ bl1,
                            const float* __restrict__ Wl2, const float* __restrict__ bl2,
                            const float* __restrict__ We1, const float* __restrict__ be1,
                            const float* __restrict__ We2, const float* __restrict__ be2,
                            float* __restrict__ outp, int n, int xg_off)
{
  __shared__ float ssum[4][64], smax[4][64];
  __shared__ float cat[128], xg[64], t1[32], t2[16], l1[32], e1[16];
  int g = blockIdx.x;
  int tid = threadIdx.x, wave = tid >> 6, lane = tid & 63;

  int lo = 0, hi = n;
  while (lo < hi) { int mid = (lo + hi) >> 1; if (batch[mid] < g) lo = mid + 1; else hi = mid; }
  int start = lo;
  lo = start; hi = n;
  while (lo < hi) { int mid = (lo + hi) >> 1; if (batch[mid] < g + 1) lo = mid + 1; else hi = mid; }
  int end = lo;
  int cntg = end - start;

  float s = 0.f, mx = -1e30f;
  for (int node = start + wave; node < end; node += 4) {
    float v = hout[(size_t)node * 64 + lane];
    s += v;
    mx = fmaxf(mx, v);
  }
  ssum[wave][lane] = s;
  smax[wave][lane] = mx;
  __syncthreads();

  int c = tid;
  if (c < 64) {
    float su = ssum[0][c] + ssum[1][c] + ssum[2][c] + ssum[3][c];
    float mu = fmaxf(fmaxf(smax[0][c], smax[1][c]), fmaxf(smax[2][c], smax[3][c]));
    float mean = su / fmaxf((float)cntg, 1.f);
    float mxv = (cntg > 0) ? mu : 0.f;
    cat[c] = mean; cat[64 + c] = mxv;
  }
  __syncthreads();
  if (c < 64) {
    float a = br[c];
    for (int i = 0; i < 128; i++) a += cat[i] * Wr[i * 64 + c];
    xg[c] = a;
    outp[xg_off + g * 64 + c] = a;
  }
  __syncthreads();
  if (c < 32) {
    float u = bh1[c]; for (int i = 0; i < 64; i++) u += xg[i] * Wh1[i * 32 + c];
    t1[c] = fmaxf(u, 0.f);
    float v = bl1[c]; for (int i = 0; i < 64; i++) v += xg[i] * Wl1[i * 32 + c];
    l1[c] = fmaxf(v, 0.f);
  }
  __syncthreads();
  if (c < 16) {
    float u = bh2[c]; for (int i = 0; i < 32; i++) u += t1[i] * Wh2[i * 16 + c];
    t2[c] = fmaxf(u, 0.f);
    float v = be1[c]; for (int i = 0; i < 64; i++) v += xg[i] * We1[i * 16 + c];
    e1[c] = fmaxf(v, 0.f);
  }
  __syncthreads();
  if (c < 8) {
    float v = bl2[c]; for (int i = 0; i < 32; i++) v += l1[i] * Wl2[i * 8 + c];
    outp[64 + g * 8 + c] = v;
  }
  if (c == 0) {
    float u = bh3[0]; for (int i = 0; i < 16; i++) u += t2[i] * Wh3[i];
    outp[g] = 100.f / (1.f + expf(-u));
    float v = be2[0]; for (int i = 0; i < 16; i++) v += e1[i] * We2[i];
    outp[576 + g] = v;
  }
}

extern "C" void kernel_launch(void* const* d_in, const int* in_sizes, int n_in,
                              void* d_out, int out_size, void* d_ws, size_t ws_size,
                              hipStream_t stream)
{
  const float* x    = (const float*)d_in[0];
  const int*   ei   = (const int*)d_in[1];
  const int*   batch= (const int*)d_in[2];
  const float* W1   = (const float*)d_in[3];
  const float* as1  = (const float*)d_in[4];
  const float* ad1  = (const float*)d_in[5];
  const float* bi1  = (const float*)d_in[6];
  const float* W2   = (const float*)d_in[7];
  const float* as2  = (const float*)d_in[8];
  const float* ad2  = (const float*)d_in[9];
  const float* bi2  = (const float*)d_in[10];
  const float* bn1g = (const float*)d_in[11];
  const float* bn1b = (const float*)d_in[12];
  const float* bn1m = (const float*)d_in[13];
  const float* bn1v = (const float*)d_in[14];
  const float* bn2g = (const float*)d_in[15];
  const float* bn2b = (const float*)d_in[16];
  const float* bn2m = (const float*)d_in[17];
  const float* bn2v = (const float*)d_in[18];
  const float* bn3g = (const float*)d_in[19];
  const float* bn3b = (const float*)d_in[20];
  const float* bn3m = (const float*)d_in[21];
  const float* bn3v = (const float*)d_in[22];
  const float* Wg   = (const float*)d_in[23];
  const float* bg   = (const float*)d_in[24];
  const float* Wr   = (const float*)d_in[25];
  const float* br   = (const float*)d_in[26];
  const float* Wh1  = (const float*)d_in[27];
  const float* bh1  = (const float*)d_in[28];
  const float* Wh2  = (const float*)d_in[29];
  const float* bh2  = (const float*)d_in[30];
  const float* Wh3  = (const float*)d_in[31];
  const float* bh3  = (const float*)d_in[32];
  const float* Wl1  = (const float*)d_in[33];
  const float* bl1  = (const float*)d_in[34];
  const float* Wl2  = (const float*)d_in[35];
  const float* bl2  = (const float*)d_in[36];
  const float* We1  = (const float*)d_in[37];
  const float* be1  = (const float*)d_in[38];
  const float* We2  = (const float*)d_in[39];
  const float* be2  = (const float*)d_in[40];

  const int n  = in_sizes[2];         // 50000 nodes
  const int ne = in_sizes[1] / 2;     // 500000 edges
  const int e2 = ne + n;              // with self-loops

  float* ws = (float*)d_ws;
  size_t off = 0;
  unsigned short* actA = (unsigned short*)(ws + off); off += (size_t)n * 128; // n*256 bf16
  unsigned short* hWb  = (unsigned short*)(ws + off); off += (size_t)n * 128; // n*256 bf16
  float* es   = ws + off; off += (size_t)n * 4;
  float* ed   = ws + off; off += (size_t)n * 4;
  int* rowptr = (int*)(ws + off); off += (size_t)n + 1;
  int* deg    = (int*)(ws + off); off += (size_t)n;
  int* cursor = (int*)(ws + off); off += (size_t)n;
  int* col    = (int*)(ws + off); off += (size_t)e2;
  int* partials = (int*)(ws + off); off += 64;
  unsigned short* Wp2 = (unsigned short*)(ws + off); off += 32768;  // 65536 bf16
  unsigned short* Wpg = (unsigned short*)(ws + off); off += 8192;   // 16384 bf16
  unsigned short* xwb = hWb;   // alias: hWb dead after GAT2 aggregate

  float* outp = (float*)d_out;
  float* hout = outp + 640;            // node embeddings region
  const int xg_off = 640 + n * 64;

  const int eb   = (e2 + 255) / 256;
  const int gb1  = (n + 3) / 4;
  const int gmb  = (n + 63) / 64;
  const int nsb  = (n + SCAN_BLK - 1) / SCAN_BLK;

  // ---------- CSR build (by destination) + weight packing ----------
  hipMemsetAsync(deg, 0, (size_t)n * sizeof(int), stream);
  hipMemsetAsync(cursor, 0, (size_t)n * sizeof(int), stream);
  k_count<<<eb, 256, 0, stream>>>(ei, deg, ne, e2);
  k_scan1<<<nsb, SCAN_BLK, 0, stream>>>(deg, rowptr, partials, n);
  k_scan2<<<nsb, SCAN_BLK, 0, stream>>>(rowptr, partials, n);
  k_fill<<<eb, 256, 0, stream>>>(ei, rowptr, cursor, col, ne, e2);
  k_pack<<<128, 512, 0, stream>>>(W2, Wp2, 256);
  k_pack<<<32, 512, 0, stream>>>(Wg, Wpg, 64);

  // ---------- GAT layer 1 ----------
  k_gemm1<<<gb1, 256, 0, stream>>>(x, W1, as1, ad1, hWb, es, ed, n);
  k_gat_agg<<<gb1, 256, 0, stream>>>(rowptr, deg, col, es, ed, hWb,
                                     bi1, bn1g, bn1b, bn1m, bn1v, actA, n);

  // ---------- GAT layer 2 ----------
  k_mfma_gemm<16, true><<<gmb, 256, 0, stream>>>(actA, Wp2, hWb, as2, ad2, es, ed, n);
  k_gat_agg<<<gb1, 256, 0, stream>>>(rowptr, deg, col, es, ed, hWb,
                                     bi2, bn2g, bn2b, bn2m, bn2v, actA, n);

  // ---------- GCN ----------
  k_mfma_gemm<4, false><<<gmb, 256, 0, stream>>>(actA, Wpg, xwb, nullptr, nullptr,
                                                 nullptr, nullptr, n);
  k_gcn_agg<<<gb1, 256, 0, stream>>>(rowptr, deg, col, xwb,
                                     bg, bn3g, bn3b, bn3m, bn3v, hout, n);

  // ---------- fused pooling + heads ----------
  k_poolheads<<<64, 256, 0, stream>>>(hout, batch, Wr, br,
                                      Wh1, bh1, Wh2, bh2, Wh3, bh3,
                                      Wl1, bl1, Wl2, bl2, We1, be1, We2, be2,
                                      outp, n, xg_off);
}

// Round 5
// 445.432 us; speedup vs baseline: 10.1937x; 1.0943x over previous
//
#include <hip/hip_runtime.h>
#include <math.h>

#define SCAN_BLK 1024

typedef __attribute__((ext_vector_type(8))) short short8;
typedef __attribute__((ext_vector_type(4))) short short4v;
typedef __attribute__((ext_vector_type(4))) float f32x4;

__device__ __forceinline__ float eluf(float x){ return x > 0.f ? x : (expf(x) - 1.f); }
__device__ __forceinline__ unsigned short f2bf(float f){
  unsigned u = __float_as_uint(f);
  u += 0x7FFFu + ((u >> 16) & 1u);          // RNE
  return (unsigned short)(u >> 16);
}
__device__ __forceinline__ float bf2f(unsigned short s){
  return __uint_as_float(((unsigned)s) << 16);
}

// ---------------- CSR build ----------------
__global__ void k_count(const int* __restrict__ ei, int* __restrict__ deg, int ne, int e2)
{
  int t = blockIdx.x * 256 + threadIdx.x;
  if (t >= e2) return;
  int dst = (t < ne) ? ei[ne + t] : t - ne;
  atomicAdd(&deg[dst], 1);
}

__global__ void k_scan1(const int* __restrict__ deg, int* __restrict__ rowptr,
                        int* __restrict__ partials, int n)
{
  __shared__ int sh[SCAN_BLK];
  int t = threadIdx.x, base = blockIdx.x * SCAN_BLK;
  int v = (base + t < n) ? deg[base + t] : 0;
  sh[t] = v;
  __syncthreads();
  for (int off = 1; off < SCAN_BLK; off <<= 1) {
    int u = 0;
    if (t >= off) u = sh[t - off];
    __syncthreads();
    if (t >= off) sh[t] += u;
    __syncthreads();
  }
  if (base + t < n) rowptr[base + t] = sh[t] - v;   // exclusive
  if (t == SCAN_BLK - 1) partials[blockIdx.x] = sh[t];
}

__global__ void k_scan2(int* __restrict__ rowptr, const int* __restrict__ partials, int n)
{
  int base = blockIdx.x * SCAN_BLK;
  int add = 0;
  for (int i = 0; i < blockIdx.x; i++) add += partials[i];
  int t = threadIdx.x;
  if (base + t < n) rowptr[base + t] += add;
}

__global__ void k_fill(const int* __restrict__ ei, const int* __restrict__ rowptr,
                       int* __restrict__ cursor, int* __restrict__ col, int ne, int e2)
{
  int t = blockIdx.x * 256 + threadIdx.x;
  if (t >= e2) return;
  int src, dst;
  if (t < ne) { src = ei[t]; dst = ei[ne + t]; } else { src = dst = t - ne; }
  int pos = rowptr[dst] + atomicAdd(&cursor[dst], 1);
  col[pos] = src;
}

// dinv = rsqrt(max(deg,1))
__global__ void k_dinv(const int* __restrict__ deg, float* __restrict__ dinv, int n)
{
  int t = blockIdx.x * 256 + threadIdx.x;
  if (t < n) dinv[t] = rsqrtf(fmaxf((float)deg[t], 1.f));
}

// ---------------- weight pack for MFMA B-fragments ----------------
__global__ void k_pack(const float* __restrict__ W, unsigned short* __restrict__ Wp, int N)
{
  int tid = threadIdx.x;              // 512
  int l = tid >> 3, j = tid & 7;
  int ct = blockIdx.x >> 3, ks = blockIdx.x & 7;
  int k = ks * 32 + (l >> 4) * 8 + j;
  int c = ct * 16 + (l & 15);
  Wp[(size_t)blockIdx.x * 512 + tid] = f2bf(W[(size_t)k * N + c]);
}

// ---------------- GAT1 GEMM: x[N,10] @ W1[10,256] + es/ed epilogue, bf16 h out ---------
__global__ void k_gemm1(const float* __restrict__ x, const float* __restrict__ W1,
                        const float* __restrict__ a_s, const float* __restrict__ a_d,
                        unsigned short* __restrict__ hWb,
                        float* __restrict__ es, float* __restrict__ ed, int n)
{
  __shared__ float xl[4][10];
  int tid = threadIdx.x;
  int n0 = blockIdx.x * 4;
  if (tid < 40) {
    int m = tid / 10, k = tid % 10;
    int nn = n0 + m;
    xl[m][k] = (nn < n) ? x[(size_t)nn * 10 + k] : 0.f;
  }
  __syncthreads();
  float acc[4] = {0.f, 0.f, 0.f, 0.f};
  #pragma unroll
  for (int k = 0; k < 10; k++) {
    float w = W1[k * 256 + tid];
    acc[0] += xl[0][k] * w; acc[1] += xl[1][k] * w;
    acc[2] += xl[2][k] * w; acc[3] += xl[3][k] * w;
  }
  int wave = tid >> 6, lane = tid & 63;
  float sa = a_s[tid], da = a_d[tid];
  #pragma unroll
  for (int m = 0; m < 4; m++) {
    int nn = n0 + m;
    float pes = acc[m] * sa, ped = acc[m] * da;
    for (int off = 1; off < 64; off <<= 1) {
      pes += __shfl_xor(pes, off, 64);
      ped += __shfl_xor(ped, off, 64);
    }
    if (nn < n) {
      hWb[(size_t)nn * 256 + tid] = f2bf(acc[m]);
      if (lane == 0) { es[nn * 4 + wave] = pes; ed[nn * 4 + wave] = ped; }
    }
  }
}

// ---------------- MFMA GEMM: act[n,256](bf16) @ Wp -> out[n, NCT*16](bf16) -------------
template<int NCT, bool ATT>
__global__ __launch_bounds__(256) void k_mfma_gemm(
    const unsigned short* __restrict__ act, const unsigned short* __restrict__ Wp,
    unsigned short* __restrict__ outb,
    const float* __restrict__ asf, const float* __restrict__ adf,
    float* __restrict__ es, float* __restrict__ ed, int n)
{
  int tid = threadIdx.x, wave = tid >> 6, lane = tid & 63;
  int l15 = lane & 15, lg = lane >> 4;
  int rbase = blockIdx.x * 64 + wave * 16;
  int arow = rbase + l15; if (arow > n - 1) arow = n - 1;
  const unsigned short* ap = &act[(size_t)arow * 256 + lg * 8];

  f32x4 acc[NCT];
  f32x4 z = {0.f, 0.f, 0.f, 0.f};
  #pragma unroll
  for (int ct = 0; ct < NCT; ct++) acc[ct] = z;

  #pragma unroll
  for (int ks = 0; ks < 8; ks++) {
    short8 a = *(const short8*)(ap + ks * 32);
    #pragma unroll
    for (int ct = 0; ct < NCT; ct++) {
      short8 b = *(const short8*)&Wp[(size_t)((ct * 8 + ks) * 64 + lane) * 8];
      acc[ct] = __builtin_amdgcn_mfma_f32_16x16x32_bf16(a, b, acc[ct], 0, 0, 0);
    }
  }

  #pragma unroll
  for (int r = 0; r < 4; r++) {
    int row = rbase + lg * 4 + r;
    if (row < n) {
      #pragma unroll
      for (int ct = 0; ct < NCT; ct++)
        outb[(size_t)row * (NCT * 16) + ct * 16 + l15] = f2bf(acc[ct][r]);
    }
  }

  if (ATT) {
    float asl[NCT], adl[NCT];
    #pragma unroll
    for (int ct = 0; ct < NCT; ct++) {
      asl[ct] = asf[ct * 16 + l15];
      adl[ct] = adf[ct * 16 + l15];
    }
    #pragma unroll
    for (int r = 0; r < 4; r++) {
      int row = rbase + lg * 4 + r;
      #pragma unroll
      for (int hd = 0; hd < 4; hd++) {
        float ps = 0.f, pd = 0.f;
        #pragma unroll
        for (int q = 0; q < 4; q++) {
          ps += acc[hd * 4 + q][r] * asl[hd * 4 + q];
          pd += acc[hd * 4 + q][r] * adl[hd * 4 + q];
        }
        #pragma unroll
        for (int off = 1; off < 16; off <<= 1) {
          ps += __shfl_xor(ps, off, 16);
          pd += __shfl_xor(pd, off, 16);
        }
        if (l15 == 0 && row < n) { es[row * 4 + hd] = ps; ed[row * 4 + hd] = pd; }
      }
    }
  }
}

// ---------------- attention softmax: per-dst max/sum, alpha -> alp buffer ----------------
// one wave per dst, 16 lanes per head; exactly one expf per (edge,head)
__global__ void k_att_ms(const int* __restrict__ rowptr, const int* __restrict__ deg,
                         const int* __restrict__ col,
                         const float* __restrict__ es, const float* __restrict__ ed,
                         float* __restrict__ alp, int n)
{
  int d = blockIdx.x * 4 + (threadIdx.x >> 6);
  if (d >= n) return;
  int lane = threadIdx.x & 63;
  int head = lane >> 4, sub = lane & 15;
  int start = rowptr[d], cnt = deg[d];
  float edh = ed[d * 4 + head];

  float m = -1e30f;
  for (int i = sub; i < cnt; i += 16) {
    int s = col[start + i];
    float a = es[s * 4 + head] + edh;
    a = a > 0.f ? a : 0.2f * a;
    m = fmaxf(m, a);
  }
  #pragma unroll
  for (int off = 1; off < 16; off <<= 1) m = fmaxf(m, __shfl_xor(m, off, 16));

  float ssum = 0.f;
  for (int i = sub; i < cnt; i += 16) {
    int s = col[start + i];
    float a = es[s * 4 + head] + edh;
    a = a > 0.f ? a : 0.2f * a;
    float ex = expf(a - m);
    alp[(size_t)(start + i) * 4 + head] = ex;
    ssum += ex;
  }
  #pragma unroll
  for (int off = 1; off < 16; off <<= 1) ssum += __shfl_xor(ssum, off, 16);
  float inv_s = 1.f / (ssum + 1e-16f);

  for (int i = sub; i < cnt; i += 16)
    alp[(size_t)(start + i) * 4 + head] *= inv_s;
}

// ---------------- GAT gather: 2-edge unrolled, 16B/lane, + BN/ELU -> bf16 ----------------
__global__ void k_gat_gather(const int* __restrict__ rowptr, const int* __restrict__ deg,
                             const int* __restrict__ col, const float* __restrict__ alp,
                             const unsigned short* __restrict__ hWb,
                             const float* __restrict__ bias,
                             const float* __restrict__ gg, const float* __restrict__ bb,
                             const float* __restrict__ mm, const float* __restrict__ vv,
                             unsigned short* __restrict__ outb, int n)
{
  int d = blockIdx.x * 4 + (threadIdx.x >> 6);
  if (d >= n) return;
  int lane = threadIdx.x & 63;
  int half = lane >> 5, l32 = lane & 31;
  int c8 = l32 * 8, head = l32 >> 3;
  int start = rowptr[d], cnt = deg[d];

  float acc[8] = {0.f,0.f,0.f,0.f,0.f,0.f,0.f,0.f};
  for (int i = half; i < cnt; i += 2) {
    int s = col[start + i];
    float alpha = alp[(size_t)(start + i) * 4 + head];
    short8 hv = *(const short8*)&hWb[(size_t)s * 256 + c8];
    #pragma unroll
    for (int j = 0; j < 8; j++)
      acc[j] += bf2f((unsigned short)hv[j]) * alpha;
  }
  #pragma unroll
  for (int j = 0; j < 8; j++)
    acc[j] += __shfl_xor(acc[j], 32, 64);

  if (half == 0) {
    float4 bi0 = *(const float4*)&bias[c8],   bi1 = *(const float4*)&bias[c8 + 4];
    float4 g0  = *(const float4*)&gg[c8],     g1  = *(const float4*)&gg[c8 + 4];
    float4 b0  = *(const float4*)&bb[c8],     b1  = *(const float4*)&bb[c8 + 4];
    float4 m0  = *(const float4*)&mm[c8],     m1  = *(const float4*)&mm[c8 + 4];
    float4 v0  = *(const float4*)&vv[c8],     v1  = *(const float4*)&vv[c8 + 4];
    float rb[8];
    rb[0] = ((acc[0] + bi0.x) - m0.x) * rsqrtf(v0.x + 1e-5f) * g0.x + b0.x;
    rb[1] = ((acc[1] + bi0.y) - m0.y) * rsqrtf(v0.y + 1e-5f) * g0.y + b0.y;
    rb[2] = ((acc[2] + bi0.z) - m0.z) * rsqrtf(v0.z + 1e-5f) * g0.z + b0.z;
    rb[3] = ((acc[3] + bi0.w) - m0.w) * rsqrtf(v0.w + 1e-5f) * g0.w + b0.w;
    rb[4] = ((acc[4] + bi1.x) - m1.x) * rsqrtf(v1.x + 1e-5f) * g1.x + b1.x;
    rb[5] = ((acc[5] + bi1.y) - m1.y) * rsqrtf(v1.y + 1e-5f) * g1.y + b1.y;
    rb[6] = ((acc[6] + bi1.z) - m1.z) * rsqrtf(v1.z + 1e-5f) * g1.z + b1.z;
    rb[7] = ((acc[7] + bi1.w) - m1.w) * rsqrtf(v1.w + 1e-5f) * g1.w + b1.w;
    short8 o;
    #pragma unroll
    for (int j = 0; j < 8; j++) o[j] = (short)f2bf(eluf(rb[j]));
    *(short8*)&outb[(size_t)d * 256 + c8] = o;
  }
}

// ---------------- GCN gather: 8-edge unrolled, 16B/lane, + BN/ELU -> fp32 ----------------
__global__ void k_gcn_gather(const int* __restrict__ rowptr, const int* __restrict__ deg,
                             const int* __restrict__ col, const float* __restrict__ dinv,
                             const unsigned short* __restrict__ xwb,
                             const float* __restrict__ bias,
                             const float* __restrict__ gg, const float* __restrict__ bb,
                             const float* __restrict__ mm, const float* __restrict__ vv,
                             float* __restrict__ hout, int n)
{
  int d = blockIdx.x * 4 + (threadIdx.x >> 6);
  if (d >= n) return;
  int lane = threadIdx.x & 63;
  int slot = lane >> 3, cg = (lane & 7) * 8;
  int start = rowptr[d], cnt = deg[d];
  float dinvd = rsqrtf(fmaxf((float)cnt, 1.f));

  float acc[8] = {0.f,0.f,0.f,0.f,0.f,0.f,0.f,0.f};
  for (int i = slot; i < cnt; i += 8) {
    int s = col[start + i];
    float norm = dinv[s] * dinvd;
    short8 hv = *(const short8*)&xwb[(size_t)s * 64 + cg];
    #pragma unroll
    for (int j = 0; j < 8; j++)
      acc[j] += bf2f((unsigned short)hv[j]) * norm;
  }
  #pragma unroll
  for (int j = 0; j < 8; j++) {
    acc[j] += __shfl_xor(acc[j], 8, 64);
    acc[j] += __shfl_xor(acc[j], 16, 64);
    acc[j] += __shfl_xor(acc[j], 32, 64);
  }

  if (lane < 8) {
    float out[8];
    #pragma unroll
    for (int j = 0; j < 8; j++) {
      int c = cg + j;
      float r = ((acc[j] + bias[c]) - mm[c]) * rsqrtf(vv[c] + 1e-5f) * gg[c] + bb[c];
      out[j] = eluf(r);
    }
    *(float4*)&hout[(size_t)d * 64 + cg]     = make_float4(out[0], out[1], out[2], out[3]);
    *(float4*)&hout[(size_t)d * 64 + cg + 4] = make_float4(out[4], out[5], out[6], out[7]);
  }
}

// ---------------- fused pooling + heads: one block per graph ----------------
__global__ void k_poolheads(const float* __restrict__ hout, const int* __restrict__ batch,
                            const float* __restrict__ Wr, const float* __restrict__ br,
                            const float* __restrict__ Wh1, const float* __restrict__ bh1,
                            const float* __restrict__ Wh2, const float* __restrict__ bh2,
                            const float* __restrict__ Wh3, const float* __restrict__ bh3,
                            const float* __restrict__ Wl1, const float* __restrict__ bl1,
                            const float* __restrict__ Wl2, const float* __restrict__ bl2,
                            const float* __restrict__ We1, const float* __restrict__ be1,
                            const float* __restrict__ We2, const float* __restrict__ be2,
                            float* __restrict__ outp, int n, int xg_off)
{
  __shared__ float ssum[4][64], smax[4][64];
  __shared__ float cat[128], xg[64], t1[32], t2[16], l1[32], e1[16];
  int g = blockIdx.x;
  int tid = threadIdx.x, wave = tid >> 6, lane = tid & 63;

  int lo = 0, hi = n;
  while (lo < hi) { int mid = (lo + hi) >> 1; if (batch[mid] < g) lo = mid + 1; else hi = mid; }
  int start = lo;
  lo = start; hi = n;
  while (lo < hi) { int mid = (lo + hi) >> 1; if (batch[mid] < g + 1) lo = mid + 1; else hi = mid; }
  int end = lo;
  int cntg = end - start;

  float s = 0.f, mx = -1e30f;
  for (int node = start + wave; node < end; node += 4) {
    float v = hout[(size_t)node * 64 + lane];
    s += v;
    mx = fmaxf(mx, v);
  }
  ssum[wave][lane] = s;
  smax[wave][lane] = mx;
  __syncthreads();

  int c = tid;
  if (c < 64) {
    float su = ssum[0][c] + ssum[1][c] + ssum[2][c] + ssum[3][c];
    float mu = fmaxf(fmaxf(smax[0][c], smax[1][c]), fmaxf(smax[2][c], smax[3][c]));
    float mean = su / fmaxf((float)cntg, 1.f);
    float mxv = (cntg > 0) ? mu : 0.f;
    cat[c] = mean; cat[64 + c] = mxv;
  }
  __syncthreads();
  if (c < 64) {
    float a = br[c];
    for (int i = 0; i < 128; i++) a += cat[i] * Wr[i * 64 + c];
    xg[c] = a;
    outp[xg_off + g * 64 + c] = a;
  }
  __syncthreads();
  if (c < 32) {
    float u = bh1[c]; for (int i = 0; i < 64; i++) u += xg[i] * Wh1[i * 32 + c];
    t1[c] = fmaxf(u, 0.f);
    float v = bl1[c]; for (int i = 0; i < 64; i++) v += xg[i] * Wl1[i * 32 + c];
    l1[c] = fmaxf(v, 0.f);
  }
  __syncthreads();
  if (c < 16) {
    float u = bh2[c]; for (int i = 0; i < 32; i++) u += t1[i] * Wh2[i * 16 + c];
    t2[c] = fmaxf(u, 0.f);
    float v = be1[c]; for (int i = 0; i < 64; i++) v += xg[i] * We1[i * 16 + c];
    e1[c] = fmaxf(v, 0.f);
  }
  __syncthreads();
  if (c < 8) {
    float v = bl2[c]; for (int i = 0; i < 32; i++) v += l1[i] * Wl2[i * 8 + c];
    outp[64 + g * 8 + c] = v;
  }
  if (c == 0) {
    float u = bh3[0]; for (int i = 0; i < 16; i++) u += t2[i] * Wh3[i];
    outp[g] = 100.f / (1.f + expf(-u));
    float v = be2[0]; for (int i = 0; i < 16; i++) v += e1[i] * We2[i];
    outp[576 + g] = v;
  }
}

extern "C" void kernel_launch(void* const* d_in, const int* in_sizes, int n_in,
                              void* d_out, int out_size, void* d_ws, size_t ws_size,
                              hipStream_t stream)
{
  const float* x    = (const float*)d_in[0];
  const int*   ei   = (const int*)d_in[1];
  const int*   batch= (const int*)d_in[2];
  const float* W1   = (const float*)d_in[3];
  const float* as1  = (const float*)d_in[4];
  const float* ad1  = (const float*)d_in[5];
  const float* bi1  = (const float*)d_in[6];
  const float* W2   = (const float*)d_in[7];
  const float* as2  = (const float*)d_in[8];
  const float* ad2  = (const float*)d_in[9];
  const float* bi2  = (const float*)d_in[10];
  const float* bn1g = (const float*)d_in[11];
  const float* bn1b = (const float*)d_in[12];
  const float* bn1m = (const float*)d_in[13];
  const float* bn1v = (const float*)d_in[14];
  const float* bn2g = (const float*)d_in[15];
  const float* bn2b = (const float*)d_in[16];
  const float* bn2m = (const float*)d_in[17];
  const float* bn2v = (const float*)d_in[18];
  const float* bn3g = (const float*)d_in[19];
  const float* bn3b = (const float*)d_in[20];
  const float* bn3m = (const float*)d_in[21];
  const float* bn3v = (const float*)d_in[22];
  const float* Wg   = (const float*)d_in[23];
  const float* bg   = (const float*)d_in[24];
  const float* Wr   = (const float*)d_in[25];
  const float* br   = (const float*)d_in[26];
  const float* Wh1  = (const float*)d_in[27];
  const float* bh1  = (const float*)d_in[28];
  const float* Wh2  = (const float*)d_in[29];
  const float* bh2  = (const float*)d_in[30];
  const float* Wh3  = (const float*)d_in[31];
  const float* bh3  = (const float*)d_in[32];
  const float* Wl1  = (const float*)d_in[33];
  const float* bl1  = (const float*)d_in[34];
  const float* Wl2  = (const float*)d_in[35];
  const float* bl2  = (const float*)d_in[36];
  const float* We1  = (const float*)d_in[37];
  const float* be1  = (const float*)d_in[38];
  const float* We2  = (const float*)d_in[39];
  const float* be2  = (const float*)d_in[40];

  const int n  = in_sizes[2];         // 50000 nodes
  const int ne = in_sizes[1] / 2;     // 500000 edges
  const int e2 = ne + n;              // with self-loops

  float* ws = (float*)d_ws;
  size_t off = 0;
  unsigned short* actA = (unsigned short*)(ws + off); off += (size_t)n * 128; // n*256 bf16
  unsigned short* hWb  = (unsigned short*)(ws + off); off += (size_t)n * 128; // n*256 bf16
  float* es   = ws + off; off += (size_t)n * 4;
  float* ed   = ws + off; off += (size_t)n * 4;
  float* alp  = ws + off; off += (size_t)e2 * 4;
  float* dinv = ws + off; off += (size_t)n;
  int* rowptr = (int*)(ws + off); off += (size_t)n + 1;
  int* deg    = (int*)(ws + off); off += (size_t)n;
  int* cursor = (int*)(ws + off); off += (size_t)n;
  int* col    = (int*)(ws + off); off += (size_t)e2;
  int* partials = (int*)(ws + off); off += 64;
  unsigned short* Wp2 = (unsigned short*)(ws + off); off += 32768;  // 65536 bf16
  unsigned short* Wpg = (unsigned short*)(ws + off); off += 8192;   // 16384 bf16
  unsigned short* xwb = hWb;   // alias: hWb dead after GAT2 gather

  float* outp = (float*)d_out;
  float* hout = outp + 640;            // node embeddings region
  const int xg_off = 640 + n * 64;

  const int eb   = (e2 + 255) / 256;
  const int gb1  = (n + 3) / 4;
  const int gmb  = (n + 63) / 64;
  const int nsb  = (n + SCAN_BLK - 1) / SCAN_BLK;

  // ---------- CSR build (by destination) + weight packing ----------
  hipMemsetAsync(deg, 0, (size_t)n * sizeof(int), stream);
  hipMemsetAsync(cursor, 0, (size_t)n * sizeof(int), stream);
  k_count<<<eb, 256, 0, stream>>>(ei, deg, ne, e2);
  k_scan1<<<nsb, SCAN_BLK, 0, stream>>>(deg, rowptr, partials, n);
  k_scan2<<<nsb, SCAN_BLK, 0, stream>>>(rowptr, partials, n);
  k_fill<<<eb, 256, 0, stream>>>(ei, rowptr, cursor, col, ne, e2);
  k_dinv<<<(n + 255) / 256, 256, 0, stream>>>(deg, dinv, n);
  k_pack<<<128, 512, 0, stream>>>(W2, Wp2, 256);
  k_pack<<<32, 512, 0, stream>>>(Wg, Wpg, 64);

  // ---------- GAT layer 1 ----------
  k_gemm1<<<gb1, 256, 0, stream>>>(x, W1, as1, ad1, hWb, es, ed, n);
  k_att_ms<<<gb1, 256, 0, stream>>>(rowptr, deg, col, es, ed, alp, n);
  k_gat_gather<<<gb1, 256, 0, stream>>>(rowptr, deg, col, alp, hWb,
                                        bi1, bn1g, bn1b, bn1m, bn1v, actA, n);

  // ---------- GAT layer 2 ----------
  k_mfma_gemm<16, true><<<gmb, 256, 0, stream>>>(actA, Wp2, hWb, as2, ad2, es, ed, n);
  k_att_ms<<<gb1, 256, 0, stream>>>(rowptr, deg, col, es, ed, alp, n);
  k_gat_gather<<<gb1, 256, 0, stream>>>(rowptr, deg, col, alp, hWb,
                                        bi2, bn2g, bn2b, bn2m, bn2v, actA, n);

  // ---------- GCN ----------
  k_mfma_gemm<4, false><<<gmb, 256, 0, stream>>>(actA, Wpg, xwb, nullptr, nullptr,
                                                 nullptr, nullptr, n);
  k_gcn_gather<<<gb1, 256, 0, stream>>>(rowptr, deg, col, dinv, xwb,
                                        bg, bn3g, bn3b, bn3m, bn3v, hout, n);

  // ---------- fused pooling + heads ----------
  k_poolheads<<<64, 256, 0, stream>>>(hout, batch, Wr, br,
                                      Wh1, bh1, Wh2, bh2, Wh3, bh3,
                                      Wl1, bl1, Wl2, bl2, We1, be1, We2, be2,
                                      outp, n, xg_off);
}

// Round 6
// 401.664 us; speedup vs baseline: 11.3044x; 1.1090x over previous
//
#include <hip/hip_runtime.h>
#include <math.h>

#define SCAN_BLK 1024

typedef __attribute__((ext_vector_type(8))) short short8;
typedef __attribute__((ext_vector_type(4))) short short4v;
typedef __attribute__((ext_vector_type(4))) float f32x4;

__device__ __forceinline__ float eluf(float x){ return x > 0.f ? x : (expf(x) - 1.f); }
__device__ __forceinline__ unsigned short f2bf(float f){
  unsigned u = __float_as_uint(f);
  u += 0x7FFFu + ((u >> 16) & 1u);          // RNE
  return (unsigned short)(u >> 16);
}
__device__ __forceinline__ float bf2f(unsigned short s){
  return __uint_as_float(((unsigned)s) << 16);
}

// ---------------- CSR build ----------------
__global__ void k_count(const int* __restrict__ ei, int* __restrict__ deg, int ne, int e2)
{
  int t = blockIdx.x * 256 + threadIdx.x;
  if (t >= e2) return;
  int dst = (t < ne) ? ei[ne + t] : t - ne;
  atomicAdd(&deg[dst], 1);
}

__global__ void k_scan1(const int* __restrict__ deg, int* __restrict__ rowptr,
                        int* __restrict__ partials, int n)
{
  __shared__ int sh[SCAN_BLK];
  int t = threadIdx.x, base = blockIdx.x * SCAN_BLK;
  int v = (base + t < n) ? deg[base + t] : 0;
  sh[t] = v;
  __syncthreads();
  for (int off = 1; off < SCAN_BLK; off <<= 1) {
    int u = 0;
    if (t >= off) u = sh[t - off];
    __syncthreads();
    if (t >= off) sh[t] += u;
    __syncthreads();
  }
  if (base + t < n) rowptr[base + t] = sh[t] - v;   // exclusive
  if (t == SCAN_BLK - 1) partials[blockIdx.x] = sh[t];
}

__global__ void k_scan2(int* __restrict__ rowptr, const int* __restrict__ partials, int n)
{
  int base = blockIdx.x * SCAN_BLK;
  int add = 0;
  for (int i = 0; i < blockIdx.x; i++) add += partials[i];
  int t = threadIdx.x;
  if (base + t < n) rowptr[base + t] += add;
}

__global__ void k_fill(const int* __restrict__ ei, const int* __restrict__ rowptr,
                       int* __restrict__ cursor, int* __restrict__ col, int ne, int e2)
{
  int t = blockIdx.x * 256 + threadIdx.x;
  if (t >= e2) return;
  int src, dst;
  if (t < ne) { src = ei[t]; dst = ei[ne + t]; } else { src = dst = t - ne; }
  int pos = rowptr[dst] + atomicAdd(&cursor[dst], 1);
  col[pos] = src;
}

// dinv = rsqrt(max(deg,1))
__global__ void k_dinv(const int* __restrict__ deg, float* __restrict__ dinv, int n)
{
  int t = blockIdx.x * 256 + threadIdx.x;
  if (t < n) dinv[t] = rsqrtf(fmaxf((float)deg[t], 1.f));
}

// ---------------- weight pack for MFMA B-fragments ----------------
// layout: Wp[((ks*NCT + ct)*64 + lane)*8 + j]  (ks-major so each K-step tile is contiguous)
__global__ void k_pack(const float* __restrict__ W, unsigned short* __restrict__ Wp,
                       int N, int nct)
{
  int tid = threadIdx.x;              // 512
  int l = tid >> 3, j = tid & 7;
  int ct = blockIdx.x >> 3, ks = blockIdx.x & 7;
  int k = ks * 32 + (l >> 4) * 8 + j;
  int c = ct * 16 + (l & 15);
  Wp[(size_t)(ks * nct + ct) * 512 + tid] = f2bf(W[(size_t)k * N + c]);
}

// ---------------- GAT1 GEMM: x[N,10] @ W1[10,256] + es/ed epilogue, bf16 h out ---------
__global__ void k_gemm1(const float* __restrict__ x, const float* __restrict__ W1,
                        const float* __restrict__ a_s, const float* __restrict__ a_d,
                        unsigned short* __restrict__ hWb,
                        float* __restrict__ es, float* __restrict__ ed, int n)
{
  __shared__ float xl[4][10];
  int tid = threadIdx.x;
  int n0 = blockIdx.x * 4;
  if (tid < 40) {
    int m = tid / 10, k = tid % 10;
    int nn = n0 + m;
    xl[m][k] = (nn < n) ? x[(size_t)nn * 10 + k] : 0.f;
  }
  __syncthreads();
  float acc[4] = {0.f, 0.f, 0.f, 0.f};
  #pragma unroll
  for (int k = 0; k < 10; k++) {
    float w = W1[k * 256 + tid];
    acc[0] += xl[0][k] * w; acc[1] += xl[1][k] * w;
    acc[2] += xl[2][k] * w; acc[3] += xl[3][k] * w;
  }
  int wave = tid >> 6, lane = tid & 63;
  float sa = a_s[tid], da = a_d[tid];
  #pragma unroll
  for (int m = 0; m < 4; m++) {
    int nn = n0 + m;
    float pes = acc[m] * sa, ped = acc[m] * da;
    for (int off = 1; off < 64; off <<= 1) {
      pes += __shfl_xor(pes, off, 64);
      ped += __shfl_xor(ped, off, 64);
    }
    if (nn < n) {
      hWb[(size_t)nn * 256 + tid] = f2bf(acc[m]);
      if (lane == 0) { es[nn * 4 + wave] = pes; ed[nn * 4 + wave] = ped; }
    }
  }
}

// ---------------- MFMA GEMM with LDS-staged B ----------------
// act[n,256](bf16) @ Wp -> out[n, NCT*16](bf16); 4 waves/block, 64 rows/block.
// Per ks-step: 4 waves cooperatively stage the NCT-KB B-tile into LDS
// (loads issued BEFORE the barrier so L2 latency overlaps prior MFMAs),
// then each wave does NCT x {ds_read_b128 + mfma}.
template<int NCT, bool ATT>
__global__ __launch_bounds__(256) void k_mfma_gemm(
    const unsigned short* __restrict__ act, const unsigned short* __restrict__ Wp,
    unsigned short* __restrict__ outb,
    const float* __restrict__ asf, const float* __restrict__ adf,
    float* __restrict__ es, float* __restrict__ ed, int n)
{
  __shared__ unsigned short bsh[NCT * 512];
  int tid = threadIdx.x, wave = tid >> 6, lane = tid & 63;
  int l15 = lane & 15, lg = lane >> 4;
  int rbase = blockIdx.x * 64 + wave * 16;
  int arow = rbase + l15; if (arow > n - 1) arow = n - 1;
  const unsigned short* ap = &act[(size_t)arow * 256 + lg * 8];

  constexpr int NCH = (NCT >= 4) ? NCT / 4 : 1;   // 1KB chunks per wave
  f32x4 acc[NCT];
  f32x4 z = {0.f, 0.f, 0.f, 0.f};
  #pragma unroll
  for (int ct = 0; ct < NCT; ct++) acc[ct] = z;

  for (int ks = 0; ks < 8; ks++) {
    // issue staging loads early (overlap with previous iteration's MFMAs)
    const unsigned short* src = Wp + (size_t)ks * NCT * 512 + wave * NCT * 128;
    short8 stg[NCH];
    #pragma unroll
    for (int c = 0; c < NCH; c++)
      stg[c] = *(const short8*)(src + c * 512 + lane * 8);
    short8 a = *(const short8*)(ap + ks * 32);
    __syncthreads();                 // previous iteration's LDS reads complete
    #pragma unroll
    for (int c = 0; c < NCH; c++)
      *(short8*)&bsh[wave * NCT * 128 + c * 512 + lane * 8] = stg[c];
    __syncthreads();                 // staged tile visible to all waves
    #pragma unroll
    for (int ct = 0; ct < NCT; ct++) {
      short8 b = *(const short8*)&bsh[(ct * 64 + lane) * 8];
      acc[ct] = __builtin_amdgcn_mfma_f32_16x16x32_bf16(a, b, acc[ct], 0, 0, 0);
    }
  }

  #pragma unroll
  for (int r = 0; r < 4; r++) {
    int row = rbase + lg * 4 + r;
    if (row < n) {
      #pragma unroll
      for (int ct = 0; ct < NCT; ct++)
        outb[(size_t)row * (NCT * 16) + ct * 16 + l15] = f2bf(acc[ct][r]);
    }
  }

  if (ATT) {
    float asl[NCT], adl[NCT];
    #pragma unroll
    for (int ct = 0; ct < NCT; ct++) {
      asl[ct] = asf[ct * 16 + l15];
      adl[ct] = adf[ct * 16 + l15];
    }
    #pragma unroll
    for (int r = 0; r < 4; r++) {
      int row = rbase + lg * 4 + r;
      #pragma unroll
      for (int hd = 0; hd < 4; hd++) {
        float ps = 0.f, pd = 0.f;
        #pragma unroll
        for (int q = 0; q < 4; q++) {
          ps += acc[hd * 4 + q][r] * asl[hd * 4 + q];
          pd += acc[hd * 4 + q][r] * adl[hd * 4 + q];
        }
        #pragma unroll
        for (int off = 1; off < 16; off <<= 1) {
          ps += __shfl_xor(ps, off, 16);
          pd += __shfl_xor(pd, off, 16);
        }
        if (l15 == 0 && row < n) { es[row * 4 + hd] = ps; ed[row * 4 + hd] = pd; }
      }
    }
  }
}

// ---------------- attention softmax: per-dst max/sum, alpha -> alp buffer ----------------
__global__ void k_att_ms(const int* __restrict__ rowptr, const int* __restrict__ deg,
                         const int* __restrict__ col,
                         const float* __restrict__ es, const float* __restrict__ ed,
                         float* __restrict__ alp, int n)
{
  int d = blockIdx.x * 4 + (threadIdx.x >> 6);
  if (d >= n) return;
  int lane = threadIdx.x & 63;
  int head = lane >> 4, sub = lane & 15;
  int start = rowptr[d], cnt = deg[d];
  float edh = ed[d * 4 + head];

  float m = -1e30f;
  for (int i = sub; i < cnt; i += 16) {
    int s = col[start + i];
    float a = es[s * 4 + head] + edh;
    a = a > 0.f ? a : 0.2f * a;
    m = fmaxf(m, a);
  }
  #pragma unroll
  for (int off = 1; off < 16; off <<= 1) m = fmaxf(m, __shfl_xor(m, off, 16));

  float ssum = 0.f;
  for (int i = sub; i < cnt; i += 16) {
    int s = col[start + i];
    float a = es[s * 4 + head] + edh;
    a = a > 0.f ? a : 0.2f * a;
    float ex = expf(a - m);
    alp[(size_t)(start + i) * 4 + head] = ex;
    ssum += ex;
  }
  #pragma unroll
  for (int off = 1; off < 16; off <<= 1) ssum += __shfl_xor(ssum, off, 16);
  float inv_s = 1.f / (ssum + 1e-16f);

  for (int i = sub; i < cnt; i += 16)
    alp[(size_t)(start + i) * 4 + head] *= inv_s;
}

// ---------------- GAT gather: 2-edge unrolled, 16B/lane, + BN/ELU -> bf16 ----------------
__global__ void k_gat_gather(const int* __restrict__ rowptr, const int* __restrict__ deg,
                             const int* __restrict__ col, const float* __restrict__ alp,
                             const unsigned short* __restrict__ hWb,
                             const float* __restrict__ bias,
                             const float* __restrict__ gg, const float* __restrict__ bb,
                             const float* __restrict__ mm, const float* __restrict__ vv,
                             unsigned short* __restrict__ outb, int n)
{
  int d = blockIdx.x * 4 + (threadIdx.x >> 6);
  if (d >= n) return;
  int lane = threadIdx.x & 63;
  int half = lane >> 5, l32 = lane & 31;
  int c8 = l32 * 8, head = l32 >> 3;
  int start = rowptr[d], cnt = deg[d];

  float acc[8] = {0.f,0.f,0.f,0.f,0.f,0.f,0.f,0.f};
  for (int i = half; i < cnt; i += 2) {
    int s = col[start + i];
    float alpha = alp[(size_t)(start + i) * 4 + head];
    short8 hv = *(const short8*)&hWb[(size_t)s * 256 + c8];
    #pragma unroll
    for (int j = 0; j < 8; j++)
      acc[j] += bf2f((unsigned short)hv[j]) * alpha;
  }
  #pragma unroll
  for (int j = 0; j < 8; j++)
    acc[j] += __shfl_xor(acc[j], 32, 64);

  if (half == 0) {
    float4 bi0 = *(const float4*)&bias[c8],   bi1 = *(const float4*)&bias[c8 + 4];
    float4 g0  = *(const float4*)&gg[c8],     g1  = *(const float4*)&gg[c8 + 4];
    float4 b0  = *(const float4*)&bb[c8],     b1  = *(const float4*)&bb[c8 + 4];
    float4 m0  = *(const float4*)&mm[c8],     m1  = *(const float4*)&mm[c8 + 4];
    float4 v0  = *(const float4*)&vv[c8],     v1  = *(const float4*)&vv[c8 + 4];
    float rb[8];
    rb[0] = ((acc[0] + bi0.x) - m0.x) * rsqrtf(v0.x + 1e-5f) * g0.x + b0.x;
    rb[1] = ((acc[1] + bi0.y) - m0.y) * rsqrtf(v0.y + 1e-5f) * g0.y + b0.y;
    rb[2] = ((acc[2] + bi0.z) - m0.z) * rsqrtf(v0.z + 1e-5f) * g0.z + b0.z;
    rb[3] = ((acc[3] + bi0.w) - m0.w) * rsqrtf(v0.w + 1e-5f) * g0.w + b0.w;
    rb[4] = ((acc[4] + bi1.x) - m1.x) * rsqrtf(v1.x + 1e-5f) * g1.x + b1.x;
    rb[5] = ((acc[5] + bi1.y) - m1.y) * rsqrtf(v1.y + 1e-5f) * g1.y + b1.y;
    rb[6] = ((acc[6] + bi1.z) - m1.z) * rsqrtf(v1.z + 1e-5f) * g1.z + b1.z;
    rb[7] = ((acc[7] + bi1.w) - m1.w) * rsqrtf(v1.w + 1e-5f) * g1.w + b1.w;
    short8 o;
    #pragma unroll
    for (int j = 0; j < 8; j++) o[j] = (short)f2bf(eluf(rb[j]));
    *(short8*)&outb[(size_t)d * 256 + c8] = o;
  }
}

// ---------------- GCN gather: 8-edge unrolled, 16B/lane, + BN/ELU -> fp32 ----------------
__global__ void k_gcn_gather(const int* __restrict__ rowptr, const int* __restrict__ deg,
                             const int* __restrict__ col, const float* __restrict__ dinv,
                             const unsigned short* __restrict__ xwb,
                             const float* __restrict__ bias,
                             const float* __restrict__ gg, const float* __restrict__ bb,
                             const float* __restrict__ mm, const float* __restrict__ vv,
                             float* __restrict__ hout, int n)
{
  int d = blockIdx.x * 4 + (threadIdx.x >> 6);
  if (d >= n) return;
  int lane = threadIdx.x & 63;
  int slot = lane >> 3, cg = (lane & 7) * 8;
  int start = rowptr[d], cnt = deg[d];
  float dinvd = rsqrtf(fmaxf((float)cnt, 1.f));

  float acc[8] = {0.f,0.f,0.f,0.f,0.f,0.f,0.f,0.f};
  for (int i = slot; i < cnt; i += 8) {
    int s = col[start + i];
    float norm = dinv[s] * dinvd;
    short8 hv = *(const short8*)&xwb[(size_t)s * 64 + cg];
    #pragma unroll
    for (int j = 0; j < 8; j++)
      acc[j] += bf2f((unsigned short)hv[j]) * norm;
  }
  #pragma unroll
  for (int j = 0; j < 8; j++) {
    acc[j] += __shfl_xor(acc[j], 8, 64);
    acc[j] += __shfl_xor(acc[j], 16, 64);
    acc[j] += __shfl_xor(acc[j], 32, 64);
  }

  if (lane < 8) {
    float out[8];
    #pragma unroll
    for (int j = 0; j < 8; j++) {
      int c = cg + j;
      float r = ((acc[j] + bias[c]) - mm[c]) * rsqrtf(vv[c] + 1e-5f) * gg[c] + bb[c];
      out[j] = eluf(r);
    }
    *(float4*)&hout[(size_t)d * 64 + cg]     = make_float4(out[0], out[1], out[2], out[3]);
    *(float4*)&hout[(size_t)d * 64 + cg + 4] = make_float4(out[4], out[5], out[6], out[7]);
  }
}

// ---------------- fused pooling + heads: one block per graph ----------------
__global__ void k_poolheads(const float* __restrict__ hout, const int* __restrict__ batch,
                            const float* __restrict__ Wr, const float* __restrict__ br,
                            const float* __restrict__ Wh1, const float* __restrict__ bh1,
                            const float* __restrict__ Wh2, const float* __restrict__ bh2,
                            const float* __restrict__ Wh3, const float* __restrict__ bh3,
                            const float* __restrict__ Wl1, const float* __restrict__ bl1,
                            const float* __restrict__ Wl2, const float* __restrict__ bl2,
                            const float* __restrict__ We1, const float* __restrict__ be1,
                            const float* __restrict__ We2, const float* __restrict__ be2,
                            float* __restrict__ outp, int n, int xg_off)
{
  __shared__ float ssum[4][64], smax[4][64];
  __shared__ float cat[128], xg[64], t1[32], t2[16], l1[32], e1[16];
  int g = blockIdx.x;
  int tid = threadIdx.x, wave = tid >> 6, lane = tid & 63;

  int lo = 0, hi = n;
  while (lo < hi) { int mid = (lo + hi) >> 1; if (batch[mid] < g) lo = mid + 1; else hi = mid; }
  int start = lo;
  lo = start; hi = n;
  while (lo < hi) { int mid = (lo + hi) >> 1; if (batch[mid] < g + 1) lo = mid + 1; else hi = mid; }
  int end = lo;
  int cntg = end - start;

  float s = 0.f, mx = -1e30f;
  for (int node = start + wave; node < end; node += 4) {
    float v = hout[(size_t)node * 64 + lane];
    s += v;
    mx = fmaxf(mx, v);
  }
  ssum[wave][lane] = s;
  smax[wave][lane] = mx;
  __syncthreads();

  int c = tid;
  if (c < 64) {
    float su = ssum[0][c] + ssum[1][c] + ssum[2][c] + ssum[3][c];
    float mu = fmaxf(fmaxf(smax[0][c], smax[1][c]), fmaxf(smax[2][c], smax[3][c]));
    float mean = su / fmaxf((float)cntg, 1.f);
    float mxv = (cntg > 0) ? mu : 0.f;
    cat[c] = mean; cat[64 + c] = mxv;
  }
  __syncthreads();
  if (c < 64) {
    float a = br[c];
    for (int i = 0; i < 128; i++) a += cat[i] * Wr[i * 64 + c];
    xg[c] = a;
    outp[xg_off + g * 64 + c] = a;
  }
  __syncthreads();
  if (c < 32) {
    float u = bh1[c]; for (int i = 0; i < 64; i++) u += xg[i] * Wh1[i * 32 + c];
    t1[c] = fmaxf(u, 0.f);
    float v = bl1[c]; for (int i = 0; i < 64; i++) v += xg[i] * Wl1[i * 32 + c];
    l1[c] = fmaxf(v, 0.f);
  }
  __syncthreads();
  if (c < 16) {
    float u = bh2[c]; for (int i = 0; i < 32; i++) u += t1[i] * Wh2[i * 16 + c];
    t2[c] = fmaxf(u, 0.f);
    float v = be1[c]; for (int i = 0; i < 64; i++) v += xg[i] * We1[i * 16 + c];
    e1[c] = fmaxf(v, 0.f);
  }
  __syncthreads();
  if (c < 8) {
    float v = bl2[c]; for (int i = 0; i < 32; i++) v += l1[i] * Wl2[i * 8 + c];
    outp[64 + g * 8 + c] = v;
  }
  if (c == 0) {
    float u = bh3[0]; for (int i = 0; i < 16; i++) u += t2[i] * Wh3[i];
    outp[g] = 100.f / (1.f + expf(-u));
    float v = be2[0]; for (int i = 0; i < 16; i++) v += e1[i] * We2[i];
    outp[576 + g] = v;
  }
}

extern "C" void kernel_launch(void* const* d_in, const int* in_sizes, int n_in,
                              void* d_out, int out_size, void* d_ws, size_t ws_size,
                              hipStream_t stream)
{
  const float* x    = (const float*)d_in[0];
  const int*   ei   = (const int*)d_in[1];
  const int*   batch= (const int*)d_in[2];
  const float* W1   = (const float*)d_in[3];
  const float* as1  = (const float*)d_in[4];
  const float* ad1  = (const float*)d_in[5];
  const float* bi1  = (const float*)d_in[6];
  const float* W2   = (const float*)d_in[7];
  const float* as2  = (const float*)d_in[8];
  const float* ad2  = (const float*)d_in[9];
  const float* bi2  = (const float*)d_in[10];
  const float* bn1g = (const float*)d_in[11];
  const float* bn1b = (const float*)d_in[12];
  const float* bn1m = (const float*)d_in[13];
  const float* bn1v = (const float*)d_in[14];
  const float* bn2g = (const float*)d_in[15];
  const float* bn2b = (const float*)d_in[16];
  const float* bn2m = (const float*)d_in[17];
  const float* bn2v = (const float*)d_in[18];
  const float* bn3g = (const float*)d_in[19];
  const float* bn3b = (const float*)d_in[20];
  const float* bn3m = (const float*)d_in[21];
  const float* bn3v = (const float*)d_in[22];
  const float* Wg   = (const float*)d_in[23];
  const float* bg   = (const float*)d_in[24];
  const float* Wr   = (const float*)d_in[25];
  const float* br   = (const float*)d_in[26];
  const float* Wh1  = (const float*)d_in[27];
  const float* bh1  = (const float*)d_in[28];
  const float* Wh2  = (const float*)d_in[29];
  const float* bh2  = (const float*)d_in[30];
  const float* Wh3  = (const float*)d_in[31];
  const float* bh3  = (const float*)d_in[32];
  const float* Wl1  = (const float*)d_in[33];
  const float* bl1  = (const float*)d_in[34];
  const float* Wl2  = (const float*)d_in[35];
  const float* bl2  = (const float*)d_in[36];
  const float* We1  = (const float*)d_in[37];
  const float* be1  = (const float*)d_in[38];
  const float* We2  = (const float*)d_in[39];
  const float* be2  = (const float*)d_in[40];

  const int n  = in_sizes[2];         // 50000 nodes
  const int ne = in_sizes[1] / 2;     // 500000 edges
  const int e2 = ne + n;              // with self-loops

  float* ws = (float*)d_ws;
  size_t off = 0;
  unsigned short* actA = (unsigned short*)(ws + off); off += (size_t)n * 128; // n*256 bf16
  unsigned short* hWb  = (unsigned short*)(ws + off); off += (size_t)n * 128; // n*256 bf16
  float* es   = ws + off; off += (size_t)n * 4;
  float* ed   = ws + off; off += (size_t)n * 4;
  float* alp  = ws + off; off += (size_t)e2 * 4;
  float* dinv = ws + off; off += (size_t)n;
  int* rowptr = (int*)(ws + off); off += (size_t)n + 1;
  int* deg    = (int*)(ws + off); off += (size_t)n;
  int* cursor = (int*)(ws + off); off += (size_t)n;
  int* col    = (int*)(ws + off); off += (size_t)e2;
  int* partials = (int*)(ws + off); off += 64;
  unsigned short* Wp2 = (unsigned short*)(ws + off); off += 32768;  // 65536 bf16
  unsigned short* Wpg = (unsigned short*)(ws + off); off += 8192;   // 16384 bf16
  unsigned short* xwb = hWb;   // alias: hWb dead after GAT2 gather

  float* outp = (float*)d_out;
  float* hout = outp + 640;            // node embeddings region
  const int xg_off = 640 + n * 64;

  const int eb   = (e2 + 255) / 256;
  const int gb1  = (n + 3) / 4;
  const int gmb  = (n + 63) / 64;
  const int nsb  = (n + SCAN_BLK - 1) / SCAN_BLK;

  // ---------- CSR build (by destination) + weight packing ----------
  hipMemsetAsync(deg, 0, (size_t)n * sizeof(int), stream);
  hipMemsetAsync(cursor, 0, (size_t)n * sizeof(int), stream);
  k_count<<<eb, 256, 0, stream>>>(ei, deg, ne, e2);
  k_scan1<<<nsb, SCAN_BLK, 0, stream>>>(deg, rowptr, partials, n);
  k_scan2<<<nsb, SCAN_BLK, 0, stream>>>(rowptr, partials, n);
  k_fill<<<eb, 256, 0, stream>>>(ei, rowptr, cursor, col, ne, e2);
  k_dinv<<<(n + 255) / 256, 256, 0, stream>>>(deg, dinv, n);
  k_pack<<<128, 512, 0, stream>>>(W2, Wp2, 256, 16);
  k_pack<<<32, 512, 0, stream>>>(Wg, Wpg, 64, 4);

  // ---------- GAT layer 1 ----------
  k_gemm1<<<gb1, 256, 0, stream>>>(x, W1, as1, ad1, hWb, es, ed, n);
  k_att_ms<<<gb1, 256, 0, stream>>>(rowptr, deg, col, es, ed, alp, n);
  k_gat_gather<<<gb1, 256, 0, stream>>>(rowptr, deg, col, alp, hWb,
                                        bi1, bn1g, bn1b, bn1m, bn1v, actA, n);

  // ---------- GAT layer 2 ----------
  k_mfma_gemm<16, true><<<gmb, 256, 0, stream>>>(actA, Wp2, hWb, as2, ad2, es, ed, n);
  k_att_ms<<<gb1, 256, 0, stream>>>(rowptr, deg, col, es, ed, alp, n);
  k_gat_gather<<<gb1, 256, 0, stream>>>(rowptr, deg, col, alp, hWb,
                                        bi2, bn2g, bn2b, bn2m, bn2v, actA, n);

  // ---------- GCN ----------
  k_mfma_gemm<4, false><<<gmb, 256, 0, stream>>>(actA, Wpg, xwb, nullptr, nullptr,
                                                 nullptr, nullptr, n);
  k_gcn_gather<<<gb1, 256, 0, stream>>>(rowptr, deg, col, dinv, xwb,
                                        bg, bn3g, bn3b, bn3m, bn3v, hout, n);

  // ---------- fused pooling + heads ----------
  k_poolheads<<<64, 256, 0, stream>>>(hout, batch, Wr, br,
                                      Wh1, bh1, Wh2, bh2, Wh3, bh3,
                                      Wl1, bl1, Wl2, bl2, We1, be1, We2, be2,
                                      outp, n, xg_off);
}

// Round 7
// 374.922 us; speedup vs baseline: 12.1108x; 1.0713x over previous
//
#include <hip/hip_runtime.h>
#include <math.h>

#define SCAN_BLK 1024

typedef __attribute__((ext_vector_type(8))) short short8;
typedef __attribute__((ext_vector_type(4))) short short4v;
typedef __attribute__((ext_vector_type(4))) float f32x4;

__device__ __forceinline__ float eluf(float x){ return x > 0.f ? x : (expf(x) - 1.f); }
__device__ __forceinline__ unsigned short f2bf(float f){
  unsigned u = __float_as_uint(f);
  u += 0x7FFFu + ((u >> 16) & 1u);          // RNE
  return (unsigned short)(u >> 16);
}
__device__ __forceinline__ float bf2f(unsigned short s){
  return __uint_as_float(((unsigned)s) << 16);
}
__device__ __forceinline__ unsigned fmap(float f){
  unsigned b = __float_as_uint(f);
  return (b & 0x80000000u) ? ~b : (b | 0x80000000u);
}
__device__ __forceinline__ float funmap(unsigned u){
  unsigned b = (u & 0x80000000u) ? (u ^ 0x80000000u) : ~u;
  return __uint_as_float(b);
}

// ---------------- CSR build ----------------
__global__ void k_count(const int* __restrict__ ei, int* __restrict__ deg, int ne, int e2)
{
  int t = blockIdx.x * 256 + threadIdx.x;
  if (t >= e2) return;
  int dst = (t < ne) ? ei[ne + t] : t - ne;
  atomicAdd(&deg[dst], 1);
}

__global__ void k_scan1(const int* __restrict__ deg, int* __restrict__ rowptr,
                        int* __restrict__ partials, int n)
{
  __shared__ int sh[SCAN_BLK];
  int t = threadIdx.x, base = blockIdx.x * SCAN_BLK;
  int v = (base + t < n) ? deg[base + t] : 0;
  sh[t] = v;
  __syncthreads();
  for (int off = 1; off < SCAN_BLK; off <<= 1) {
    int u = 0;
    if (t >= off) u = sh[t - off];
    __syncthreads();
    if (t >= off) sh[t] += u;
    __syncthreads();
  }
  if (base + t < n) rowptr[base + t] = sh[t] - v;   // exclusive
  if (t == SCAN_BLK - 1) partials[blockIdx.x] = sh[t];
}

__global__ void k_scan2(int* __restrict__ rowptr, const int* __restrict__ partials, int n)
{
  int base = blockIdx.x * SCAN_BLK;
  int add = 0;
  for (int i = 0; i < blockIdx.x; i++) add += partials[i];
  int t = threadIdx.x;
  if (base + t < n) rowptr[base + t] += add;
}

__global__ void k_fill(const int* __restrict__ ei, const int* __restrict__ rowptr,
                       int* __restrict__ cursor, int* __restrict__ col, int ne, int e2)
{
  int t = blockIdx.x * 256 + threadIdx.x;
  if (t >= e2) return;
  int src, dst;
  if (t < ne) { src = ei[t]; dst = ei[ne + t]; } else { src = dst = t - ne; }
  int pos = rowptr[dst] + atomicAdd(&cursor[dst], 1);
  col[pos] = src;
}

// dinv = rsqrt(max(deg,1))
__global__ void k_dinv(const int* __restrict__ deg, float* __restrict__ dinv, int n)
{
  int t = blockIdx.x * 256 + threadIdx.x;
  if (t < n) dinv[t] = rsqrtf(fmaxf((float)deg[t], 1.f));
}

// ---------------- weight pack for MFMA B-fragments ----------------
__global__ void k_pack(const float* __restrict__ W, unsigned short* __restrict__ Wp,
                       int N, int nct)
{
  int tid = threadIdx.x;              // 512
  int l = tid >> 3, j = tid & 7;
  int ct = blockIdx.x >> 3, ks = blockIdx.x & 7;
  int k = ks * 32 + (l >> 4) * 8 + j;
  int c = ct * 16 + (l & 15);
  Wp[(size_t)(ks * nct + ct) * 512 + tid] = f2bf(W[(size_t)k * N + c]);
}

// ---------------- GAT1 GEMM: x[N,10] @ W1[10,256] + es/ed epilogue, bf16 h out ---------
__global__ void k_gemm1(const float* __restrict__ x, const float* __restrict__ W1,
                        const float* __restrict__ a_s, const float* __restrict__ a_d,
                        unsigned short* __restrict__ hWb,
                        float* __restrict__ es, float* __restrict__ ed, int n)
{
  __shared__ float xl[4][10];
  int tid = threadIdx.x;
  int n0 = blockIdx.x * 4;
  if (tid < 40) {
    int m = tid / 10, k = tid % 10;
    int nn = n0 + m;
    xl[m][k] = (nn < n) ? x[(size_t)nn * 10 + k] : 0.f;
  }
  __syncthreads();
  float acc[4] = {0.f, 0.f, 0.f, 0.f};
  #pragma unroll
  for (int k = 0; k < 10; k++) {
    float w = W1[k * 256 + tid];
    acc[0] += xl[0][k] * w; acc[1] += xl[1][k] * w;
    acc[2] += xl[2][k] * w; acc[3] += xl[3][k] * w;
  }
  int wave = tid >> 6, lane = tid & 63;
  float sa = a_s[tid], da = a_d[tid];
  #pragma unroll
  for (int m = 0; m < 4; m++) {
    int nn = n0 + m;
    float pes = acc[m] * sa, ped = acc[m] * da;
    for (int off = 1; off < 64; off <<= 1) {
      pes += __shfl_xor(pes, off, 64);
      ped += __shfl_xor(ped, off, 64);
    }
    if (nn < n) {
      hWb[(size_t)nn * 256 + tid] = f2bf(acc[m]);
      if (lane == 0) { es[nn * 4 + wave] = pes; ed[nn * 4 + wave] = ped; }
    }
  }
}

// ---------------- MFMA GEMM with LDS-staged B ----------------
template<int NCT, bool ATT>
__global__ __launch_bounds__(256) void k_mfma_gemm(
    const unsigned short* __restrict__ act, const unsigned short* __restrict__ Wp,
    unsigned short* __restrict__ outb,
    const float* __restrict__ asf, const float* __restrict__ adf,
    float* __restrict__ es, float* __restrict__ ed, int n)
{
  __shared__ unsigned short bsh[NCT * 512];
  int tid = threadIdx.x, wave = tid >> 6, lane = tid & 63;
  int l15 = lane & 15, lg = lane >> 4;
  int rbase = blockIdx.x * 64 + wave * 16;
  int arow = rbase + l15; if (arow > n - 1) arow = n - 1;
  const unsigned short* ap = &act[(size_t)arow * 256 + lg * 8];

  constexpr int NCH = (NCT >= 4) ? NCT / 4 : 1;   // 1KB chunks per wave
  f32x4 acc[NCT];
  f32x4 z = {0.f, 0.f, 0.f, 0.f};
  #pragma unroll
  for (int ct = 0; ct < NCT; ct++) acc[ct] = z;

  for (int ks = 0; ks < 8; ks++) {
    const unsigned short* src = Wp + (size_t)ks * NCT * 512 + wave * NCT * 128;
    short8 stg[NCH];
    #pragma unroll
    for (int c = 0; c < NCH; c++)
      stg[c] = *(const short8*)(src + c * 512 + lane * 8);
    short8 a = *(const short8*)(ap + ks * 32);
    __syncthreads();
    #pragma unroll
    for (int c = 0; c < NCH; c++)
      *(short8*)&bsh[wave * NCT * 128 + c * 512 + lane * 8] = stg[c];
    __syncthreads();
    #pragma unroll
    for (int ct = 0; ct < NCT; ct++) {
      short8 b = *(const short8*)&bsh[(ct * 64 + lane) * 8];
      acc[ct] = __builtin_amdgcn_mfma_f32_16x16x32_bf16(a, b, acc[ct], 0, 0, 0);
    }
  }

  #pragma unroll
  for (int r = 0; r < 4; r++) {
    int row = rbase + lg * 4 + r;
    if (row < n) {
      #pragma unroll
      for (int ct = 0; ct < NCT; ct++)
        outb[(size_t)row * (NCT * 16) + ct * 16 + l15] = f2bf(acc[ct][r]);
    }
  }

  if (ATT) {
    float asl[NCT], adl[NCT];
    #pragma unroll
    for (int ct = 0; ct < NCT; ct++) {
      asl[ct] = asf[ct * 16 + l15];
      adl[ct] = adf[ct * 16 + l15];
    }
    #pragma unroll
    for (int r = 0; r < 4; r++) {
      int row = rbase + lg * 4 + r;
      #pragma unroll
      for (int hd = 0; hd < 4; hd++) {
        float ps = 0.f, pd = 0.f;
        #pragma unroll
        for (int q = 0; q < 4; q++) {
          ps += acc[hd * 4 + q][r] * asl[hd * 4 + q];
          pd += acc[hd * 4 + q][r] * adl[hd * 4 + q];
        }
        #pragma unroll
        for (int off = 1; off < 16; off <<= 1) {
          ps += __shfl_xor(ps, off, 16);
          pd += __shfl_xor(pd, off, 16);
        }
        if (l15 == 0 && row < n) { es[row * 4 + hd] = ps; ed[row * 4 + hd] = pd; }
      }
    }
  }
}

// ---------------- attention softmax: per-dst max/sum, alpha -> alp buffer ----------------
__global__ void k_att_ms(const int* __restrict__ rowptr, const int* __restrict__ deg,
                         const int* __restrict__ col,
                         const float* __restrict__ es, const float* __restrict__ ed,
                         float* __restrict__ alp, int n)
{
  int d = blockIdx.x * 4 + (threadIdx.x >> 6);
  if (d >= n) return;
  int lane = threadIdx.x & 63;
  int head = lane >> 4, sub = lane & 15;
  int start = rowptr[d], cnt = deg[d];
  float edh = ed[d * 4 + head];

  float m = -1e30f;
  for (int i = sub; i < cnt; i += 16) {
    int s = col[start + i];
    float a = es[s * 4 + head] + edh;
    a = a > 0.f ? a : 0.2f * a;
    m = fmaxf(m, a);
  }
  #pragma unroll
  for (int off = 1; off < 16; off <<= 1) m = fmaxf(m, __shfl_xor(m, off, 16));

  float ssum = 0.f;
  for (int i = sub; i < cnt; i += 16) {
    int s = col[start + i];
    float a = es[s * 4 + head] + edh;
    a = a > 0.f ? a : 0.2f * a;
    float ex = expf(a - m);
    alp[(size_t)(start + i) * 4 + head] = ex;
    ssum += ex;
  }
  #pragma unroll
  for (int off = 1; off < 16; off <<= 1) ssum += __shfl_xor(ssum, off, 16);
  float inv_s = 1.f / (ssum + 1e-16f);

  for (int i = sub; i < cnt; i += 16)
    alp[(size_t)(start + i) * 4 + head] *= inv_s;
}

// ---------------- GAT gather: 2-edge unrolled, 16B/lane, + BN/ELU -> bf16 ----------------
__global__ void k_gat_gather(const int* __restrict__ rowptr, const int* __restrict__ deg,
                             const int* __restrict__ col, const float* __restrict__ alp,
                             const unsigned short* __restrict__ hWb,
                             const float* __restrict__ bias,
                             const float* __restrict__ gg, const float* __restrict__ bb,
                             const float* __restrict__ mm, const float* __restrict__ vv,
                             unsigned short* __restrict__ outb, int n)
{
  int d = blockIdx.x * 4 + (threadIdx.x >> 6);
  if (d >= n) return;
  int lane = threadIdx.x & 63;
  int half = lane >> 5, l32 = lane & 31;
  int c8 = l32 * 8, head = l32 >> 3;
  int start = rowptr[d], cnt = deg[d];

  float acc[8] = {0.f,0.f,0.f,0.f,0.f,0.f,0.f,0.f};
  for (int i = half; i < cnt; i += 2) {
    int s = col[start + i];
    float alpha = alp[(size_t)(start + i) * 4 + head];
    short8 hv = *(const short8*)&hWb[(size_t)s * 256 + c8];
    #pragma unroll
    for (int j = 0; j < 8; j++)
      acc[j] += bf2f((unsigned short)hv[j]) * alpha;
  }
  #pragma unroll
  for (int j = 0; j < 8; j++)
    acc[j] += __shfl_xor(acc[j], 32, 64);

  if (half == 0) {
    float4 bi0 = *(const float4*)&bias[c8],   bi1 = *(const float4*)&bias[c8 + 4];
    float4 g0  = *(const float4*)&gg[c8],     g1  = *(const float4*)&gg[c8 + 4];
    float4 b0  = *(const float4*)&bb[c8],     b1  = *(const float4*)&bb[c8 + 4];
    float4 m0  = *(const float4*)&mm[c8],     m1  = *(const float4*)&mm[c8 + 4];
    float4 v0  = *(const float4*)&vv[c8],     v1  = *(const float4*)&vv[c8 + 4];
    float rb[8];
    rb[0] = ((acc[0] + bi0.x) - m0.x) * rsqrtf(v0.x + 1e-5f) * g0.x + b0.x;
    rb[1] = ((acc[1] + bi0.y) - m0.y) * rsqrtf(v0.y + 1e-5f) * g0.y + b0.y;
    rb[2] = ((acc[2] + bi0.z) - m0.z) * rsqrtf(v0.z + 1e-5f) * g0.z + b0.z;
    rb[3] = ((acc[3] + bi0.w) - m0.w) * rsqrtf(v0.w + 1e-5f) * g0.w + b0.w;
    rb[4] = ((acc[4] + bi1.x) - m1.x) * rsqrtf(v1.x + 1e-5f) * g1.x + b1.x;
    rb[5] = ((acc[5] + bi1.y) - m1.y) * rsqrtf(v1.y + 1e-5f) * g1.y + b1.y;
    rb[6] = ((acc[6] + bi1.z) - m1.z) * rsqrtf(v1.z + 1e-5f) * g1.z + b1.z;
    rb[7] = ((acc[7] + bi1.w) - m1.w) * rsqrtf(v1.w + 1e-5f) * g1.w + b1.w;
    short8 o;
    #pragma unroll
    for (int j = 0; j < 8; j++) o[j] = (short)f2bf(eluf(rb[j]));
    *(short8*)&outb[(size_t)d * 256 + c8] = o;
  }
}

// ---------------- GCN gather: 8-edge unrolled, 16B/lane, + BN/ELU -> fp32 ----------------
__global__ void k_gcn_gather(const int* __restrict__ rowptr, const int* __restrict__ deg,
                             const int* __restrict__ col, const float* __restrict__ dinv,
                             const unsigned short* __restrict__ xwb,
                             const float* __restrict__ bias,
                             const float* __restrict__ gg, const float* __restrict__ bb,
                             const float* __restrict__ mm, const float* __restrict__ vv,
                             float* __restrict__ hout, int n)
{
  int d = blockIdx.x * 4 + (threadIdx.x >> 6);
  if (d >= n) return;
  int lane = threadIdx.x & 63;
  int slot = lane >> 3, cg = (lane & 7) * 8;
  int start = rowptr[d], cnt = deg[d];
  float dinvd = rsqrtf(fmaxf((float)cnt, 1.f));

  float acc[8] = {0.f,0.f,0.f,0.f,0.f,0.f,0.f,0.f};
  for (int i = slot; i < cnt; i += 8) {
    int s = col[start + i];
    float norm = dinv[s] * dinvd;
    short8 hv = *(const short8*)&xwb[(size_t)s * 64 + cg];
    #pragma unroll
    for (int j = 0; j < 8; j++)
      acc[j] += bf2f((unsigned short)hv[j]) * norm;
  }
  #pragma unroll
  for (int j = 0; j < 8; j++) {
    acc[j] += __shfl_xor(acc[j], 8, 64);
    acc[j] += __shfl_xor(acc[j], 16, 64);
    acc[j] += __shfl_xor(acc[j], 32, 64);
  }

  if (lane < 8) {
    float out[8];
    #pragma unroll
    for (int j = 0; j < 8; j++) {
      int c = cg + j;
      float r = ((acc[j] + bias[c]) - mm[c]) * rsqrtf(vv[c] + 1e-5f) * gg[c] + bb[c];
      out[j] = eluf(r);
    }
    *(float4*)&hout[(size_t)d * 64 + cg]     = make_float4(out[0], out[1], out[2], out[3]);
    *(float4*)&hout[(size_t)d * 64 + cg + 4] = make_float4(out[4], out[5], out[6], out[7]);
  }
}

// ---------------- pooling: partial per-wave accumulation, rare flushes ----------------
// batch sorted; each wave owns 32 contiguous nodes (spans <=2 groups typically).
// Accumulate sum/max in registers while group unchanged; flush once per group-run.
__global__ void k_pool_partial(const float* __restrict__ hout, const int* __restrict__ batch,
                               float* __restrict__ psum, unsigned* __restrict__ pmaxu,
                               int n)
{
  int wave = threadIdx.x >> 6, lane = threadIdx.x & 63;
  int wbase = blockIdx.x * 128 + wave * 32;
  int wend = wbase + 32; if (wend > n) wend = n;
  if (wbase >= n) return;

  int g_cur = -1;
  float s = 0.f, mx = -1e30f;
  for (int node = wbase; node < wend; node++) {
    int g = batch[node];
    if (g != g_cur) {
      if (g_cur >= 0) {
        atomicAdd(&psum[g_cur * 64 + lane], s);
        atomicMax(&pmaxu[g_cur * 64 + lane], fmap(mx));
      }
      g_cur = g; s = 0.f; mx = -1e30f;
    }
    float v = hout[(size_t)node * 64 + lane];
    s += v;
    mx = fmaxf(mx, v);
  }
  if (g_cur >= 0) {
    atomicAdd(&psum[g_cur * 64 + lane], s);
    atomicMax(&pmaxu[g_cur * 64 + lane], fmap(mx));
  }
}

// ---------------- heads: one block (64 thr) per graph ----------------
__global__ void k_heads(const float* __restrict__ psum, const unsigned* __restrict__ pmaxu,
                        const int* __restrict__ batch,
                        const float* __restrict__ Wr, const float* __restrict__ br,
                        const float* __restrict__ Wh1, const float* __restrict__ bh1,
                        const float* __restrict__ Wh2, const float* __restrict__ bh2,
                        const float* __restrict__ Wh3, const float* __restrict__ bh3,
                        const float* __restrict__ Wl1, const float* __restrict__ bl1,
                        const float* __restrict__ Wl2, const float* __restrict__ bl2,
                        const float* __restrict__ We1, const float* __restrict__ be1,
                        const float* __restrict__ We2, const float* __restrict__ be2,
                        float* __restrict__ outp, int n, int xg_off)
{
  __shared__ float cat[128], xg[64], t1[32], t2[16], l1[32], e1[16];
  int g = blockIdx.x, c = threadIdx.x;  // 64 threads

  // count of nodes in group g via binary search on sorted batch
  int lo = 0, hi = n;
  while (lo < hi) { int mid = (lo + hi) >> 1; if (batch[mid] < g) lo = mid + 1; else hi = mid; }
  int start = lo;
  lo = start; hi = n;
  while (lo < hi) { int mid = (lo + hi) >> 1; if (batch[mid] < g + 1) lo = mid + 1; else hi = mid; }
  int cntg = lo - start;

  float mean = psum[g * 64 + c] / fmaxf((float)cntg, 1.f);
  float mxv = (cntg > 0) ? funmap(pmaxu[g * 64 + c]) : 0.f;
  cat[c] = mean; cat[64 + c] = mxv;
  __syncthreads();
  float a = br[c];
  for (int i = 0; i < 128; i++) a += cat[i] * Wr[i * 64 + c];
  xg[c] = a;
  outp[xg_off + g * 64 + c] = a;
  __syncthreads();
  if (c < 32) {
    float u = bh1[c]; for (int i = 0; i < 64; i++) u += xg[i] * Wh1[i * 32 + c];
    t1[c] = fmaxf(u, 0.f);
    float v = bl1[c]; for (int i = 0; i < 64; i++) v += xg[i] * Wl1[i * 32 + c];
    l1[c] = fmaxf(v, 0.f);
  }
  __syncthreads();
  if (c < 16) {
    float u = bh2[c]; for (int i = 0; i < 32; i++) u += t1[i] * Wh2[i * 16 + c];
    t2[c] = fmaxf(u, 0.f);
    float v = be1[c]; for (int i = 0; i < 64; i++) v += xg[i] * We1[i * 16 + c];
    e1[c] = fmaxf(v, 0.f);
  }
  __syncthreads();
  if (c < 8) {
    float v = bl2[c]; for (int i = 0; i < 32; i++) v += l1[i] * Wl2[i * 8 + c];
    outp[64 + g * 8 + c] = v;
  }
  if (c == 0) {
    float u = bh3[0]; for (int i = 0; i < 16; i++) u += t2[i] * Wh3[i];
    outp[g] = 100.f / (1.f + expf(-u));
    float v = be2[0]; for (int i = 0; i < 16; i++) v += e1[i] * We2[i];
    outp[576 + g] = v;
  }
}

extern "C" void kernel_launch(void* const* d_in, const int* in_sizes, int n_in,
                              void* d_out, int out_size, void* d_ws, size_t ws_size,
                              hipStream_t stream)
{
  const float* x    = (const float*)d_in[0];
  const int*   ei   = (const int*)d_in[1];
  const int*   batch= (const int*)d_in[2];
  const float* W1   = (const float*)d_in[3];
  const float* as1  = (const float*)d_in[4];
  const float* ad1  = (const float*)d_in[5];
  const float* bi1  = (const float*)d_in[6];
  const float* W2   = (const float*)d_in[7];
  const float* as2  = (const float*)d_in[8];
  const float* ad2  = (const float*)d_in[9];
  const float* bi2  = (const float*)d_in[10];
  const float* bn1g = (const float*)d_in[11];
  const float* bn1b = (const float*)d_in[12];
  const float* bn1m = (const float*)d_in[13];
  const float* bn1v = (const float*)d_in[14];
  const float* bn2g = (const float*)d_in[15];
  const float* bn2b = (const float*)d_in[16];
  const float* bn2m = (const float*)d_in[17];
  const float* bn2v = (const float*)d_in[18];
  const float* bn3g = (const float*)d_in[19];
  const float* bn3b = (const float*)d_in[20];
  const float* bn3m = (const float*)d_in[21];
  const float* bn3v = (const float*)d_in[22];
  const float* Wg   = (const float*)d_in[23];
  const float* bg   = (const float*)d_in[24];
  const float* Wr   = (const float*)d_in[25];
  const float* br   = (const float*)d_in[26];
  const float* Wh1  = (const float*)d_in[27];
  const float* bh1  = (const float*)d_in[28];
  const float* Wh2  = (const float*)d_in[29];
  const float* bh2  = (const float*)d_in[30];
  const float* Wh3  = (const float*)d_in[31];
  const float* bh3  = (const float*)d_in[32];
  const float* Wl1  = (const float*)d_in[33];
  const float* bl1  = (const float*)d_in[34];
  const float* Wl2  = (const float*)d_in[35];
  const float* bl2  = (const float*)d_in[36];
  const float* We1  = (const float*)d_in[37];
  const float* be1  = (const float*)d_in[38];
  const float* We2  = (const float*)d_in[39];
  const float* be2  = (const float*)d_in[40];

  const int n  = in_sizes[2];         // 50000 nodes
  const int ne = in_sizes[1] / 2;     // 500000 edges
  const int e2 = ne + n;              // with self-loops

  float* ws = (float*)d_ws;
  size_t off = 0;
  unsigned short* actA = (unsigned short*)(ws + off); off += (size_t)n * 128; // n*256 bf16
  unsigned short* hWb  = (unsigned short*)(ws + off); off += (size_t)n * 128; // n*256 bf16
  float* es   = ws + off; off += (size_t)n * 4;
  float* ed   = ws + off; off += (size_t)n * 4;
  float* alp  = ws + off; off += (size_t)e2 * 4;
  float* dinv = ws + off; off += (size_t)n;
  int* rowptr = (int*)(ws + off); off += (size_t)n + 1;
  int* deg    = (int*)(ws + off); off += (size_t)n;
  int* cursor = (int*)(ws + off); off += (size_t)n;
  int* col    = (int*)(ws + off); off += (size_t)e2;
  int* partials = (int*)(ws + off); off += 64;
  unsigned short* Wp2 = (unsigned short*)(ws + off); off += 32768;  // 65536 bf16
  unsigned short* Wpg = (unsigned short*)(ws + off); off += 8192;   // 16384 bf16
  float* psum = ws + off; off += 64 * 64;
  unsigned* pmaxu = (unsigned*)(ws + off); off += 64 * 64;
  unsigned short* xwb = hWb;   // alias: hWb dead after GAT2 gather

  float* outp = (float*)d_out;
  float* hout = outp + 640;            // node embeddings region
  const int xg_off = 640 + n * 64;

  const int eb   = (e2 + 255) / 256;
  const int gb1  = (n + 3) / 4;
  const int gmb  = (n + 63) / 64;
  const int nsb  = (n + SCAN_BLK - 1) / SCAN_BLK;

  // ---------- CSR build (by destination) + weight packing ----------
  hipMemsetAsync(deg, 0, (size_t)n * sizeof(int), stream);
  hipMemsetAsync(cursor, 0, (size_t)n * sizeof(int), stream);
  k_count<<<eb, 256, 0, stream>>>(ei, deg, ne, e2);
  k_scan1<<<nsb, SCAN_BLK, 0, stream>>>(deg, rowptr, partials, n);
  k_scan2<<<nsb, SCAN_BLK, 0, stream>>>(rowptr, partials, n);
  k_fill<<<eb, 256, 0, stream>>>(ei, rowptr, cursor, col, ne, e2);
  k_dinv<<<(n + 255) / 256, 256, 0, stream>>>(deg, dinv, n);
  k_pack<<<128, 512, 0, stream>>>(W2, Wp2, 256, 16);
  k_pack<<<32, 512, 0, stream>>>(Wg, Wpg, 64, 4);

  // ---------- GAT layer 1 ----------
  k_gemm1<<<gb1, 256, 0, stream>>>(x, W1, as1, ad1, hWb, es, ed, n);
  k_att_ms<<<gb1, 256, 0, stream>>>(rowptr, deg, col, es, ed, alp, n);
  k_gat_gather<<<gb1, 256, 0, stream>>>(rowptr, deg, col, alp, hWb,
                                        bi1, bn1g, bn1b, bn1m, bn1v, actA, n);

  // ---------- GAT layer 2 ----------
  k_mfma_gemm<16, true><<<gmb, 256, 0, stream>>>(actA, Wp2, hWb, as2, ad2, es, ed, n);
  k_att_ms<<<gb1, 256, 0, stream>>>(rowptr, deg, col, es, ed, alp, n);
  k_gat_gather<<<gb1, 256, 0, stream>>>(rowptr, deg, col, alp, hWb,
                                        bi2, bn2g, bn2b, bn2m, bn2v, actA, n);

  // ---------- GCN ----------
  k_mfma_gemm<4, false><<<gmb, 256, 0, stream>>>(actA, Wpg, xwb, nullptr, nullptr,
                                                 nullptr, nullptr, n);
  k_gcn_gather<<<gb1, 256, 0, stream>>>(rowptr, deg, col, dinv, xwb,
                                        bg, bn3g, bn3b, bn3m, bn3v, hout, n);

  // ---------- pooling + heads ----------
  hipMemsetAsync(psum, 0, 64 * 64 * sizeof(float), stream);
  hipMemsetAsync(pmaxu, 0, 64 * 64 * sizeof(unsigned), stream);
  k_pool_partial<<<(n + 127) / 128, 256, 0, stream>>>(hout, batch, psum, pmaxu, n);
  k_heads<<<64, 64, 0, stream>>>(psum, pmaxu, batch, Wr, br,
                                 Wh1, bh1, Wh2, bh2, Wh3, bh3,
                                 Wl1, bl1, Wl2, bl2, We1, be1, We2, be2,
                                 outp, n, xg_off);
}

// Round 8
// 371.599 us; speedup vs baseline: 12.2190x; 1.0089x over previous
//
#include <hip/hip_runtime.h>
#include <math.h>

#define SCAN_BLK 1024
#define BN_EPS 1e-5f

typedef __attribute__((ext_vector_type(8))) short short8;
typedef __attribute__((ext_vector_type(4))) short short4v;
typedef __attribute__((ext_vector_type(4))) float f32x4;

__device__ __forceinline__ float eluf(float x){ return x > 0.f ? x : (expf(x) - 1.f); }
__device__ __forceinline__ unsigned short f2bf(float f){
  unsigned u = __float_as_uint(f);
  u += 0x7FFFu + ((u >> 16) & 1u);          // RNE
  return (unsigned short)(u >> 16);
}
__device__ __forceinline__ float bf2f(unsigned short s){
  return __uint_as_float(((unsigned)s) << 16);
}
__device__ __forceinline__ unsigned fmap(float f){
  unsigned b = __float_as_uint(f);
  return (b & 0x80000000u) ? ~b : (b | 0x80000000u);
}
__device__ __forceinline__ float funmap(unsigned u){
  unsigned b = (u & 0x80000000u) ? (u ^ 0x80000000u) : ~u;
  return __uint_as_float(b);
}

// ---------------- CSR build ----------------
__global__ void k_count(const int* __restrict__ ei, int* __restrict__ deg, int ne, int e2)
{
  int t = blockIdx.x * 256 + threadIdx.x;
  if (t >= e2) return;
  int dst = (t < ne) ? ei[ne + t] : t - ne;
  atomicAdd(&deg[dst], 1);
}

__global__ void k_scan1(const int* __restrict__ deg, int* __restrict__ rowptr,
                        int* __restrict__ partials, int n)
{
  __shared__ int sh[SCAN_BLK];
  int t = threadIdx.x, base = blockIdx.x * SCAN_BLK;
  int v = (base + t < n) ? deg[base + t] : 0;
  sh[t] = v;
  __syncthreads();
  for (int off = 1; off < SCAN_BLK; off <<= 1) {
    int u = 0;
    if (t >= off) u = sh[t - off];
    __syncthreads();
    if (t >= off) sh[t] += u;
    __syncthreads();
  }
  if (base + t < n) rowptr[base + t] = sh[t] - v;   // exclusive
  if (t == SCAN_BLK - 1) partials[blockIdx.x] = sh[t];
}

__global__ void k_scan2(int* __restrict__ rowptr, const int* __restrict__ partials, int n)
{
  int base = blockIdx.x * SCAN_BLK;
  int add = 0;
  for (int i = 0; i < blockIdx.x; i++) add += partials[i];
  int t = threadIdx.x;
  if (base + t < n) rowptr[base + t] += add;
}

__global__ void k_fill(const int* __restrict__ ei, const int* __restrict__ rowptr,
                       int* __restrict__ cursor, int* __restrict__ col, int ne, int e2)
{
  int t = blockIdx.x * 256 + threadIdx.x;
  if (t >= e2) return;
  int src, dst;
  if (t < ne) { src = ei[t]; dst = ei[ne + t]; } else { src = dst = t - ne; }
  int pos = rowptr[dst] + atomicAdd(&cursor[dst], 1);
  col[pos] = src;
}

__global__ void k_dinv(const int* __restrict__ deg, float* __restrict__ dinv, int n)
{
  int t = blockIdx.x * 256 + threadIdx.x;
  if (t < n) dinv[t] = rsqrtf(fmaxf((float)deg[t], 1.f));
}

// ---------------- weight pack for MFMA B-fragments ----------------
__global__ void k_pack(const float* __restrict__ W, unsigned short* __restrict__ Wp,
                       int N, int nct)
{
  int tid = threadIdx.x;              // 512
  int l = tid >> 3, j = tid & 7;
  int ct = blockIdx.x >> 3, ks = blockIdx.x & 7;
  int k = ks * 32 + (l >> 4) * 8 + j;
  int c = ct * 16 + (l & 15);
  Wp[(size_t)(ks * nct + ct) * 512 + tid] = f2bf(W[(size_t)k * N + c]);
}

// ---------------- precompute: Ws1/Wd1[10][4] = W1 . a_{s,d}1 ----------------
__global__ void k_prep1(const float* __restrict__ W1, const float* __restrict__ as1,
                        const float* __restrict__ ad1,
                        float* __restrict__ Ws1, float* __restrict__ Wd1)
{
  int t = threadIdx.x;
  if (t >= 80) return;
  int half = t / 40, r = t % 40;
  int k = r / 4, h = r % 4;
  const float* a = half ? ad1 : as1;
  float s = 0.f;
  for (int c = 0; c < 64; c++) s += W1[k * 256 + h * 64 + c] * a[h * 64 + c];
  (half ? Wd1 : Ws1)[k * 4 + h] = s;
}

// ---------------- precompute: Was2/Wad2[256][4] = W2 . a_{s,d}2 ----------------
__global__ void k_prep2(const float* __restrict__ W2, const float* __restrict__ as2,
                        const float* __restrict__ ad2,
                        float* __restrict__ Was2, float* __restrict__ Wad2)
{
  int g = blockIdx.x * 256 + threadIdx.x;    // 0..2047
  if (g >= 2048) return;
  int half = g >= 1024, r = g & 1023;
  int i = r >> 2, h = r & 3;
  const float* a = half ? ad2 : as2;
  float s = 0.f;
  for (int c = 0; c < 64; c++) s += W2[(size_t)i * 256 + h * 64 + c] * a[h * 64 + c];
  (half ? Wad2 : Was2)[i * 4 + h] = s;
}

// ---------------- precompute fused BN scale/shift: y*A + B ----------------
__global__ void k_prep_bn(const float* __restrict__ bi1, const float* __restrict__ g1,
                          const float* __restrict__ b1, const float* __restrict__ m1,
                          const float* __restrict__ v1,
                          const float* __restrict__ bi2, const float* __restrict__ g2,
                          const float* __restrict__ b2, const float* __restrict__ m2,
                          const float* __restrict__ v2,
                          float* __restrict__ A1, float* __restrict__ B1,
                          float* __restrict__ A2, float* __restrict__ B2)
{
  int c = threadIdx.x;
  if (c < 256) {
    float a = rsqrtf(v1[c] + BN_EPS) * g1[c];
    A1[c] = a; B1[c] = (bi1[c] - m1[c]) * a + b1[c];
    a = rsqrtf(v2[c] + BN_EPS) * g2[c];
    A2[c] = a; B2[c] = (bi2[c] - m2[c]) * a + b2[c];
  }
}

// ---------------- es1/ed1 = x @ Ws1/Wd1 ----------------
__global__ void k_es1(const float* __restrict__ x, const float* __restrict__ Ws1,
                      const float* __restrict__ Wd1,
                      float* __restrict__ es, float* __restrict__ ed, int n)
{
  int t = blockIdx.x * 256 + threadIdx.x;
  if (t >= n) return;
  float xr[10];
  #pragma unroll
  for (int k = 0; k < 10; k++) xr[k] = x[(size_t)t * 10 + k];
  float e0[4] = {0,0,0,0}, e1[4] = {0,0,0,0};
  #pragma unroll
  for (int k = 0; k < 10; k++) {
    #pragma unroll
    for (int h = 0; h < 4; h++) {
      e0[h] += xr[k] * Ws1[k * 4 + h];
      e1[h] += xr[k] * Wd1[k * 4 + h];
    }
  }
  *(float4*)&es[t * 4] = make_float4(e0[0], e0[1], e0[2], e0[3]);
  *(float4*)&ed[t * 4] = make_float4(e1[0], e1[1], e1[2], e1[3]);
}

// ---------------- es2/ed2 = actA(bf16) @ Was2/Wad2 (wave per node) ----------------
__global__ void k_esed2(const unsigned short* __restrict__ act,
                        const float* __restrict__ Was2, const float* __restrict__ Wad2,
                        float* __restrict__ es, float* __restrict__ ed, int n)
{
  int nn = blockIdx.x * 4 + (threadIdx.x >> 6);
  if (nn >= n) return;
  int lane = threadIdx.x & 63;
  short4v av = *(const short4v*)&act[(size_t)nn * 256 + lane * 4];
  float e0[4] = {0,0,0,0}, e1[4] = {0,0,0,0};
  #pragma unroll
  for (int j = 0; j < 4; j++) {
    int c = lane * 4 + j;
    float v = bf2f((unsigned short)av[j]);
    float4 ws = *(const float4*)&Was2[c * 4];
    float4 wd = *(const float4*)&Wad2[c * 4];
    e0[0] += v * ws.x; e0[1] += v * ws.y; e0[2] += v * ws.z; e0[3] += v * ws.w;
    e1[0] += v * wd.x; e1[1] += v * wd.y; e1[2] += v * wd.z; e1[3] += v * wd.w;
  }
  #pragma unroll
  for (int off = 1; off < 64; off <<= 1) {
    #pragma unroll
    for (int h = 0; h < 4; h++) {
      e0[h] += __shfl_xor(e0[h], off, 64);
      e1[h] += __shfl_xor(e1[h], off, 64);
    }
  }
  if (lane == 0) {
    *(float4*)&es[nn * 4] = make_float4(e0[0], e0[1], e0[2], e0[3]);
    *(float4*)&ed[nn * 4] = make_float4(e1[0], e1[1], e1[2], e1[3]);
  }
}

// ---------------- attention: per-dst max + exp store + 1/sum -> sinv ----------------
__global__ void k_att_ms(const int* __restrict__ rowptr, const int* __restrict__ deg,
                         const int* __restrict__ col,
                         const float* __restrict__ es, const float* __restrict__ ed,
                         float* __restrict__ alp, float* __restrict__ sinv, int n)
{
  int d = blockIdx.x * 4 + (threadIdx.x >> 6);
  if (d >= n) return;
  int lane = threadIdx.x & 63;
  int head = lane >> 4, sub = lane & 15;
  int start = rowptr[d], cnt = deg[d];
  float edh = ed[d * 4 + head];

  float m = -1e30f;
  for (int i = sub; i < cnt; i += 16) {
    int s = col[start + i];
    float a = es[s * 4 + head] + edh;
    a = a > 0.f ? a : 0.2f * a;
    m = fmaxf(m, a);
  }
  #pragma unroll
  for (int off = 1; off < 16; off <<= 1) m = fmaxf(m, __shfl_xor(m, off, 16));

  float ssum = 0.f;
  for (int i = sub; i < cnt; i += 16) {
    int s = col[start + i];
    float a = es[s * 4 + head] + edh;
    a = a > 0.f ? a : 0.2f * a;
    float ex = expf(a - m);
    alp[(size_t)(start + i) * 4 + head] = ex;
    ssum += ex;
  }
  #pragma unroll
  for (int off = 1; off < 16; off <<= 1) ssum += __shfl_xor(ssum, off, 16);
  if (sub == 0) sinv[d * 4 + head] = 1.f / (ssum + 1e-16f);
}

// ---------------- layer-1: aggregate raw x per head -> xa[N][4][10] f32 ----------------
__global__ void k_xagg(const int* __restrict__ rowptr, const int* __restrict__ deg,
                       const int* __restrict__ col, const float* __restrict__ alp,
                       const float* __restrict__ sinv, const float* __restrict__ x,
                       float* __restrict__ xa, int n)
{
  int d = blockIdx.x * 4 + (threadIdx.x >> 6);
  if (d >= n) return;
  int lane = threadIdx.x & 63;
  int h = lane >> 4, k = lane & 15;
  int start = rowptr[d], cnt = deg[d];
  bool active = (k < 10);
  float acc = 0.f;
  for (int i = 0; i < cnt; i++) {
    int s = col[start + i];
    float a = alp[(size_t)(start + i) * 4 + h];
    if (active) acc += a * x[(size_t)s * 10 + k];
  }
  if (active) xa[(size_t)d * 40 + h * 10 + k] = acc * sinv[d * 4 + h];
}

// ---------------- layer-1 GEMM: xa @ W1 (per head) + BN1 + ELU -> actA bf16 -----------
__global__ void k_gemm_xa(const float* __restrict__ xa, const float* __restrict__ W1,
                          const float* __restrict__ A1, const float* __restrict__ B1,
                          unsigned short* __restrict__ actA, int n)
{
  __shared__ float xal[160];
  int tid = threadIdx.x;
  int n0 = blockIdx.x * 4;
  if (tid < 160 && (size_t)n0 * 40 + tid < (size_t)n * 40)
    xal[tid] = xa[(size_t)n0 * 40 + tid];
  __syncthreads();
  int c = tid, h = c >> 6;
  float w[10];
  #pragma unroll
  for (int k = 0; k < 10; k++) w[k] = W1[k * 256 + c];
  float a1 = A1[c], b1 = B1[c];
  #pragma unroll
  for (int m = 0; m < 4; m++) {
    int nn = n0 + m;
    if (nn >= n) break;
    float acc = 0.f;
    #pragma unroll
    for (int k = 0; k < 10; k++) acc += xal[m * 40 + h * 10 + k] * w[k];
    actA[(size_t)nn * 256 + c] = f2bf(eluf(acc * a1 + b1));
  }
}

// ---------------- layer-2 gather (raw): agg2[dst] = (sum ex*act[src]) * sinv ----------
__global__ void k_gat_gather(const int* __restrict__ rowptr, const int* __restrict__ deg,
                             const int* __restrict__ col, const float* __restrict__ alp,
                             const float* __restrict__ sinv,
                             const unsigned short* __restrict__ act,
                             unsigned short* __restrict__ outb, int n)
{
  int d = blockIdx.x * 4 + (threadIdx.x >> 6);
  if (d >= n) return;
  int lane = threadIdx.x & 63;
  int half = lane >> 5, l32 = lane & 31;
  int c8 = l32 * 8, head = l32 >> 3;
  int start = rowptr[d], cnt = deg[d];

  float acc[8] = {0.f,0.f,0.f,0.f,0.f,0.f,0.f,0.f};
  int T = (cnt > half) ? ((cnt - half + 1) >> 1) : 0;
  int ebase = start + half;
  int t = 0;
  for (; t + 2 <= T; t += 2) {
    int e0 = ebase + 2 * t, e1 = e0 + 2;
    int s0 = col[e0], s1 = col[e1];
    float a0 = alp[(size_t)e0 * 4 + head];
    float a1 = alp[(size_t)e1 * 4 + head];
    short8 h0 = *(const short8*)&act[(size_t)s0 * 256 + c8];
    short8 h1 = *(const short8*)&act[(size_t)s1 * 256 + c8];
    #pragma unroll
    for (int j = 0; j < 8; j++) {
      acc[j] += bf2f((unsigned short)h0[j]) * a0;
      acc[j] += bf2f((unsigned short)h1[j]) * a1;
    }
  }
  if (t < T) {
    int e0 = ebase + 2 * t;
    int s0 = col[e0];
    float a0 = alp[(size_t)e0 * 4 + head];
    short8 h0 = *(const short8*)&act[(size_t)s0 * 256 + c8];
    #pragma unroll
    for (int j = 0; j < 8; j++) acc[j] += bf2f((unsigned short)h0[j]) * a0;
  }
  #pragma unroll
  for (int j = 0; j < 8; j++)
    acc[j] += __shfl_xor(acc[j], 32, 64);

  if (half == 0) {
    float sv = sinv[d * 4 + head];
    short8 o;
    #pragma unroll
    for (int j = 0; j < 8; j++) o[j] = (short)f2bf(acc[j] * sv);
    *(short8*)&outb[(size_t)d * 256 + c8] = o;
  }
}

// ---------------- MFMA GEMM with LDS-staged B; optional fused BN+ELU epilogue ---------
template<int NCT, bool BNEPI>
__global__ __launch_bounds__(256) void k_mfma_gemm(
    const unsigned short* __restrict__ act, const unsigned short* __restrict__ Wp,
    unsigned short* __restrict__ outb,
    const float* __restrict__ Abn, const float* __restrict__ Bbn, int n)
{
  __shared__ unsigned short bsh[NCT * 512];
  int tid = threadIdx.x, wave = tid >> 6, lane = tid & 63;
  int l15 = lane & 15, lg = lane >> 4;
  int rbase = blockIdx.x * 64 + wave * 16;
  int arow = rbase + l15; if (arow > n - 1) arow = n - 1;
  const unsigned short* ap = &act[(size_t)arow * 256 + lg * 8];

  constexpr int NCH = (NCT >= 4) ? NCT / 4 : 1;
  f32x4 acc[NCT];
  f32x4 z = {0.f, 0.f, 0.f, 0.f};
  #pragma unroll
  for (int ct = 0; ct < NCT; ct++) acc[ct] = z;

  for (int ks = 0; ks < 8; ks++) {
    const unsigned short* src = Wp + (size_t)ks * NCT * 512 + wave * NCT * 128;
    short8 stg[NCH];
    #pragma unroll
    for (int c = 0; c < NCH; c++)
      stg[c] = *(const short8*)(src + c * 512 + lane * 8);
    short8 a = *(const short8*)(ap + ks * 32);
    __syncthreads();
    #pragma unroll
    for (int c = 0; c < NCH; c++)
      *(short8*)&bsh[wave * NCT * 128 + c * 512 + lane * 8] = stg[c];
    __syncthreads();
    #pragma unroll
    for (int ct = 0; ct < NCT; ct++) {
      short8 b = *(const short8*)&bsh[(ct * 64 + lane) * 8];
      acc[ct] = __builtin_amdgcn_mfma_f32_16x16x32_bf16(a, b, acc[ct], 0, 0, 0);
    }
  }

  float abn[NCT], bbn[NCT];
  if (BNEPI) {
    #pragma unroll
    for (int ct = 0; ct < NCT; ct++) {
      abn[ct] = Abn[ct * 16 + l15];
      bbn[ct] = Bbn[ct * 16 + l15];
    }
  }
  #pragma unroll
  for (int r = 0; r < 4; r++) {
    int row = rbase + lg * 4 + r;
    if (row < n) {
      #pragma unroll
      for (int ct = 0; ct < NCT; ct++) {
        float v = acc[ct][r];
        if (BNEPI) v = eluf(v * abn[ct] + bbn[ct]);
        outb[(size_t)row * (NCT * 16) + ct * 16 + l15] = f2bf(v);
      }
    }
  }
}

// ---------------- GCN gather: 8-edge unrolled + BN/ELU -> fp32 hout ----------------
__global__ void k_gcn_gather(const int* __restrict__ rowptr, const int* __restrict__ deg,
                             const int* __restrict__ col, const float* __restrict__ dinv,
                             const unsigned short* __restrict__ xwb,
                             const float* __restrict__ bias,
                             const float* __restrict__ gg, const float* __restrict__ bb,
                             const float* __restrict__ mm, const float* __restrict__ vv,
                             float* __restrict__ hout, int n)
{
  int d = blockIdx.x * 4 + (threadIdx.x >> 6);
  if (d >= n) return;
  int lane = threadIdx.x & 63;
  int slot = lane >> 3, cg = (lane & 7) * 8;
  int start = rowptr[d], cnt = deg[d];
  float dinvd = rsqrtf(fmaxf((float)cnt, 1.f));

  float acc[8] = {0.f,0.f,0.f,0.f,0.f,0.f,0.f,0.f};
  for (int i = slot; i < cnt; i += 8) {
    int s = col[start + i];
    float norm = dinv[s] * dinvd;
    short8 hv = *(const short8*)&xwb[(size_t)s * 64 + cg];
    #pragma unroll
    for (int j = 0; j < 8; j++)
      acc[j] += bf2f((unsigned short)hv[j]) * norm;
  }
  #pragma unroll
  for (int j = 0; j < 8; j++) {
    acc[j] += __shfl_xor(acc[j], 8, 64);
    acc[j] += __shfl_xor(acc[j], 16, 64);
    acc[j] += __shfl_xor(acc[j], 32, 64);
  }

  if (lane < 8) {
    float out[8];
    #pragma unroll
    for (int j = 0; j < 8; j++) {
      int c = cg + j;
      float r = ((acc[j] + bias[c]) - mm[c]) * rsqrtf(vv[c] + BN_EPS) * gg[c] + bb[c];
      out[j] = eluf(r);
    }
    *(float4*)&hout[(size_t)d * 64 + cg]     = make_float4(out[0], out[1], out[2], out[3]);
    *(float4*)&hout[(size_t)d * 64 + cg + 4] = make_float4(out[4], out[5], out[6], out[7]);
  }
}

// ---------------- pooling: per-wave run accumulation, rare flushes ----------------
__global__ void k_pool_partial(const float* __restrict__ hout, const int* __restrict__ batch,
                               float* __restrict__ psum, unsigned* __restrict__ pmaxu,
                               int n)
{
  int wave = threadIdx.x >> 6, lane = threadIdx.x & 63;
  int wbase = blockIdx.x * 128 + wave * 32;
  int wend = wbase + 32; if (wend > n) wend = n;
  if (wbase >= n) return;

  int g_cur = -1;
  float s = 0.f, mx = -1e30f;
  for (int node = wbase; node < wend; node++) {
    int g = batch[node];
    if (g != g_cur) {
      if (g_cur >= 0) {
        atomicAdd(&psum[g_cur * 64 + lane], s);
        atomicMax(&pmaxu[g_cur * 64 + lane], fmap(mx));
      }
      g_cur = g; s = 0.f; mx = -1e30f;
    }
    float v = hout[(size_t)node * 64 + lane];
    s += v;
    mx = fmaxf(mx, v);
  }
  if (g_cur >= 0) {
    atomicAdd(&psum[g_cur * 64 + lane], s);
    atomicMax(&pmaxu[g_cur * 64 + lane], fmap(mx));
  }
}

// ---------------- heads: one block (64 thr) per graph ----------------
__global__ void k_heads(const float* __restrict__ psum, const unsigned* __restrict__ pmaxu,
                        const int* __restrict__ batch,
                        const float* __restrict__ Wr, const float* __restrict__ br,
                        const float* __restrict__ Wh1, const float* __restrict__ bh1,
                        const float* __restrict__ Wh2, const float* __restrict__ bh2,
                        const float* __restrict__ Wh3, const float* __restrict__ bh3,
                        const float* __restrict__ Wl1, const float* __restrict__ bl1,
                        const float* __restrict__ Wl2, const float* __restrict__ bl2,
                        const float* __restrict__ We1, const float* __restrict__ be1,
                        const float* __restrict__ We2, const float* __restrict__ be2,
                        float* __restrict__ outp, int n, int xg_off)
{
  __shared__ float cat[128], xg[64], t1[32], t2[16], l1[32], e1[16];
  int g = blockIdx.x, c = threadIdx.x;  // 64 threads

  int lo = 0, hi = n;
  while (lo < hi) { int mid = (lo + hi) >> 1; if (batch[mid] < g) lo = mid + 1; else hi = mid; }
  int start = lo;
  lo = start; hi = n;
  while (lo < hi) { int mid = (lo + hi) >> 1; if (batch[mid] < g + 1) lo = mid + 1; else hi = mid; }
  int cntg = lo - start;

  float mean = psum[g * 64 + c] / fmaxf((float)cntg, 1.f);
  float mxv = (cntg > 0) ? funmap(pmaxu[g * 64 + c]) : 0.f;
  cat[c] = mean; cat[64 + c] = mxv;
  __syncthreads();
  float a = br[c];
  for (int i = 0; i < 128; i++) a += cat[i] * Wr[i * 64 + c];
  xg[c] = a;
  outp[xg_off + g * 64 + c] = a;
  __syncthreads();
  if (c < 32) {
    float u = bh1[c]; for (int i = 0; i < 64; i++) u += xg[i] * Wh1[i * 32 + c];
    t1[c] = fmaxf(u, 0.f);
    float v = bl1[c]; for (int i = 0; i < 64; i++) v += xg[i] * Wl1[i * 32 + c];
    l1[c] = fmaxf(v, 0.f);
  }
  __syncthreads();
  if (c < 16) {
    float u = bh2[c]; for (int i = 0; i < 32; i++) u += t1[i] * Wh2[i * 16 + c];
    t2[c] = fmaxf(u, 0.f);
    float v = be1[c]; for (int i = 0; i < 64; i++) v += xg[i] * We1[i * 16 + c];
    e1[c] = fmaxf(v, 0.f);
  }
  __syncthreads();
  if (c < 8) {
    float v = bl2[c]; for (int i = 0; i < 32; i++) v += l1[i] * Wl2[i * 8 + c];
    outp[64 + g * 8 + c] = v;
  }
  if (c == 0) {
    float u = bh3[0]; for (int i = 0; i < 16; i++) u += t2[i] * Wh3[i];
    outp[g] = 100.f / (1.f + expf(-u));
    float v = be2[0]; for (int i = 0; i < 16; i++) v += e1[i] * We2[i];
    outp[576 + g] = v;
  }
}

extern "C" void kernel_launch(void* const* d_in, const int* in_sizes, int n_in,
                              void* d_out, int out_size, void* d_ws, size_t ws_size,
                              hipStream_t stream)
{
  const float* x    = (const float*)d_in[0];
  const int*   ei   = (const int*)d_in[1];
  const int*   batch= (const int*)d_in[2];
  const float* W1   = (const float*)d_in[3];
  const float* as1  = (const float*)d_in[4];
  const float* ad1  = (const float*)d_in[5];
  const float* bi1  = (const float*)d_in[6];
  const float* W2   = (const float*)d_in[7];
  const float* as2  = (const float*)d_in[8];
  const float* ad2  = (const float*)d_in[9];
  const float* bi2  = (const float*)d_in[10];
  const float* bn1g = (const float*)d_in[11];
  const float* bn1b = (const float*)d_in[12];
  const float* bn1m = (const float*)d_in[13];
  const float* bn1v = (const float*)d_in[14];
  const float* bn2g = (const float*)d_in[15];
  const float* bn2b = (const float*)d_in[16];
  const float* bn2m = (const float*)d_in[17];
  const float* bn2v = (const float*)d_in[18];
  const float* bn3g = (const float*)d_in[19];
  const float* bn3b = (const float*)d_in[20];
  const float* bn3m = (const float*)d_in[21];
  const float* bn3v = (const float*)d_in[22];
  const float* Wg   = (const float*)d_in[23];
  const float* bg   = (const float*)d_in[24];
  const float* Wr   = (const float*)d_in[25];
  const float* br   = (const float*)d_in[26];
  const float* Wh1  = (const float*)d_in[27];
  const float* bh1  = (const float*)d_in[28];
  const float* Wh2  = (const float*)d_in[29];
  const float* bh2  = (const float*)d_in[30];
  const float* Wh3  = (const float*)d_in[31];
  const float* bh3  = (const float*)d_in[32];
  const float* Wl1  = (const float*)d_in[33];
  const float* bl1  = (const float*)d_in[34];
  const float* Wl2  = (const float*)d_in[35];
  const float* bl2  = (const float*)d_in[36];
  const float* We1  = (const float*)d_in[37];
  const float* be1  = (const float*)d_in[38];
  const float* We2  = (const float*)d_in[39];
  const float* be2  = (const float*)d_in[40];

  const int n  = in_sizes[2];         // 50000 nodes
  const int ne = in_sizes[1] / 2;     // 500000 edges
  const int e2 = ne + n;              // with self-loops

  float* ws = (float*)d_ws;
  size_t off = 0;
  unsigned short* bufA = (unsigned short*)(ws + off); off += (size_t)n * 128; // actA / actB
  unsigned short* bufB = (unsigned short*)(ws + off); off += (size_t)n * 128; // agg2 / xwb
  float* xa   = ws + off; off += (size_t)n * 40;
  float* es   = ws + off; off += (size_t)n * 4;
  float* ed   = ws + off; off += (size_t)n * 4;
  float* alp  = ws + off; off += (size_t)e2 * 4;
  float* sinv = ws + off; off += (size_t)n * 4;
  float* dinv = ws + off; off += (size_t)n;
  int* rowptr = (int*)(ws + off); off += (size_t)n + 1;
  int* deg    = (int*)(ws + off); off += (size_t)n;
  int* cursor = (int*)(ws + off); off += (size_t)n;
  int* col    = (int*)(ws + off); off += (size_t)e2;
  int* partials = (int*)(ws + off); off += 64;
  unsigned short* Wp2 = (unsigned short*)(ws + off); off += 32768;  // 65536 bf16
  unsigned short* Wpg = (unsigned short*)(ws + off); off += 8192;   // 16384 bf16
  float* Ws1  = ws + off; off += 40;
  float* Wd1  = ws + off; off += 40;
  float* Was2 = ws + off; off += 1024;
  float* Wad2 = ws + off; off += 1024;
  float* A1   = ws + off; off += 256;
  float* B1   = ws + off; off += 256;
  float* A2   = ws + off; off += 256;
  float* B2   = ws + off; off += 256;
  float* psum = ws + off; off += 64 * 64;
  unsigned* pmaxu = (unsigned*)(ws + off); off += 64 * 64;

  unsigned short* actA = bufA;
  unsigned short* agg2 = bufB;
  unsigned short* actB = bufA;   // actA dead after gather + esed2
  unsigned short* xwb  = bufB;   // agg2 dead after layer-2 GEMM

  float* outp = (float*)d_out;
  float* hout = outp + 640;            // node embeddings region
  const int xg_off = 640 + n * 64;

  const int eb   = (e2 + 255) / 256;
  const int gb1  = (n + 3) / 4;
  const int gmb  = (n + 63) / 64;
  const int nsb  = (n + SCAN_BLK - 1) / SCAN_BLK;

  // ---------- CSR build + precomputes ----------
  hipMemsetAsync(deg, 0, (size_t)n * sizeof(int), stream);
  hipMemsetAsync(cursor, 0, (size_t)n * sizeof(int), stream);
  k_count<<<eb, 256, 0, stream>>>(ei, deg, ne, e2);
  k_scan1<<<nsb, SCAN_BLK, 0, stream>>>(deg, rowptr, partials, n);
  k_scan2<<<nsb, SCAN_BLK, 0, stream>>>(rowptr, partials, n);
  k_fill<<<eb, 256, 0, stream>>>(ei, rowptr, cursor, col, ne, e2);
  k_dinv<<<(n + 255) / 256, 256, 0, stream>>>(deg, dinv, n);
  k_pack<<<128, 512, 0, stream>>>(W2, Wp2, 256, 16);
  k_pack<<<32, 512, 0, stream>>>(Wg, Wpg, 64, 4);
  k_prep1<<<1, 128, 0, stream>>>(W1, as1, ad1, Ws1, Wd1);
  k_prep2<<<8, 256, 0, stream>>>(W2, as2, ad2, Was2, Wad2);
  k_prep_bn<<<1, 256, 0, stream>>>(bi1, bn1g, bn1b, bn1m, bn1v,
                                   bi2, bn2g, bn2b, bn2m, bn2v,
                                   A1, B1, A2, B2);

  // ---------- GAT layer 1 (aggregate-first) ----------
  k_es1<<<(n + 255) / 256, 256, 0, stream>>>(x, Ws1, Wd1, es, ed, n);
  k_att_ms<<<gb1, 256, 0, stream>>>(rowptr, deg, col, es, ed, alp, sinv, n);
  k_xagg<<<gb1, 256, 0, stream>>>(rowptr, deg, col, alp, sinv, x, xa, n);
  k_gemm_xa<<<gb1, 256, 0, stream>>>(xa, W1, A1, B1, actA, n);

  // ---------- GAT layer 2 (aggregate-first) ----------
  k_esed2<<<gb1, 256, 0, stream>>>(actA, Was2, Wad2, es, ed, n);
  k_att_ms<<<gb1, 256, 0, stream>>>(rowptr, deg, col, es, ed, alp, sinv, n);
  k_gat_gather<<<gb1, 256, 0, stream>>>(rowptr, deg, col, alp, sinv, actA, agg2, n);
  k_mfma_gemm<16, true><<<gmb, 256, 0, stream>>>(agg2, Wp2, actB, A2, B2, n);

  // ---------- GCN ----------
  k_mfma_gemm<4, false><<<gmb, 256, 0, stream>>>(actB, Wpg, xwb, nullptr, nullptr, n);
  k_gcn_gather<<<gb1, 256, 0, stream>>>(rowptr, deg, col, dinv, xwb,
                                        bg, bn3g, bn3b, bn3m, bn3v, hout, n);

  // ---------- pooling + heads ----------
  hipMemsetAsync(psum, 0, 64 * 64 * sizeof(float), stream);
  hipMemsetAsync(pmaxu, 0, 64 * 64 * sizeof(unsigned), stream);
  k_pool_partial<<<(n + 127) / 128, 256, 0, stream>>>(hout, batch, psum, pmaxu, n);
  k_heads<<<64, 64, 0, stream>>>(psum, pmaxu, batch, Wr, br,
                                 Wh1, bh1, Wh2, bh2, Wh3, bh3,
                                 Wl1, bl1, Wl2, bl2, We1, be1, We2, be2,
                                 outp, n, xg_off);
}

// Round 9
// 342.562 us; speedup vs baseline: 13.2548x; 1.0848x over previous
//
#include <hip/hip_runtime.h>
#include <math.h>

#define SCAN_BLK 1024
#define BN_EPS 1e-5f

typedef __attribute__((ext_vector_type(8))) short short8;
typedef __attribute__((ext_vector_type(4))) short short4v;
typedef __attribute__((ext_vector_type(4))) float f32x4;

__device__ __forceinline__ float eluf(float x){ return x > 0.f ? x : (expf(x) - 1.f); }
__device__ __forceinline__ unsigned short f2bf(float f){
  unsigned u = __float_as_uint(f);
  u += 0x7FFFu + ((u >> 16) & 1u);          // RNE
  return (unsigned short)(u >> 16);
}
__device__ __forceinline__ float bf2f(unsigned short s){
  return __uint_as_float(((unsigned)s) << 16);
}
__device__ __forceinline__ unsigned fmap(float f){
  unsigned b = __float_as_uint(f);
  return (b & 0x80000000u) ? ~b : (b | 0x80000000u);
}
__device__ __forceinline__ float funmap(unsigned u){
  unsigned b = (u & 0x80000000u) ? (u ^ 0x80000000u) : ~u;
  return __uint_as_float(b);
}

// ---------------- CSR build ----------------
__global__ void k_count(const int* __restrict__ ei, int* __restrict__ deg, int ne, int e2)
{
  int t = blockIdx.x * 256 + threadIdx.x;
  if (t >= e2) return;
  int dst = (t < ne) ? ei[ne + t] : t - ne;
  atomicAdd(&deg[dst], 1);
}

__global__ void k_scan1(const int* __restrict__ deg, int* __restrict__ rowptr,
                        int* __restrict__ partials, int n)
{
  __shared__ int sh[SCAN_BLK];
  int t = threadIdx.x, base = blockIdx.x * SCAN_BLK;
  int v = (base + t < n) ? deg[base + t] : 0;
  sh[t] = v;
  __syncthreads();
  for (int off = 1; off < SCAN_BLK; off <<= 1) {
    int u = 0;
    if (t >= off) u = sh[t - off];
    __syncthreads();
    if (t >= off) sh[t] += u;
    __syncthreads();
  }
  if (base + t < n) rowptr[base + t] = sh[t] - v;   // exclusive
  if (t == SCAN_BLK - 1) partials[blockIdx.x] = sh[t];
}

__global__ void k_scan2(int* __restrict__ rowptr, const int* __restrict__ partials, int n)
{
  int base = blockIdx.x * SCAN_BLK;
  int add = 0;
  for (int i = 0; i < blockIdx.x; i++) add += partials[i];
  int t = threadIdx.x;
  if (base + t < n) rowptr[base + t] += add;
}

__global__ void k_fill(const int* __restrict__ ei, const int* __restrict__ rowptr,
                       int* __restrict__ cursor, int* __restrict__ col, int ne, int e2)
{
  int t = blockIdx.x * 256 + threadIdx.x;
  if (t >= e2) return;
  int src, dst;
  if (t < ne) { src = ei[t]; dst = ei[ne + t]; } else { src = dst = t - ne; }
  int pos = rowptr[dst] + atomicAdd(&cursor[dst], 1);
  col[pos] = src;
}

__global__ void k_dinv(const int* __restrict__ deg, float* __restrict__ dinv, int n)
{
  int t = blockIdx.x * 256 + threadIdx.x;
  if (t < n) dinv[t] = rsqrtf(fmaxf((float)deg[t], 1.f));
}

// ---------------- weight pack for MFMA B-fragments ----------------
__global__ void k_pack(const float* __restrict__ W, unsigned short* __restrict__ Wp,
                       int N, int nct)
{
  int tid = threadIdx.x;              // 512
  int l = tid >> 3, j = tid & 7;
  int ct = blockIdx.x >> 3, ks = blockIdx.x & 7;
  int k = ks * 32 + (l >> 4) * 8 + j;
  int c = ct * 16 + (l & 15);
  Wp[(size_t)(ks * nct + ct) * 512 + tid] = f2bf(W[(size_t)k * N + c]);
}

// ---------------- precompute: Ws1/Wd1[10][4] = W1 . a_{s,d}1 ----------------
__global__ void k_prep1(const float* __restrict__ W1, const float* __restrict__ as1,
                        const float* __restrict__ ad1,
                        float* __restrict__ Ws1, float* __restrict__ Wd1)
{
  int t = threadIdx.x;
  if (t >= 80) return;
  int half = t / 40, r = t % 40;
  int k = r / 4, h = r % 4;
  const float* a = half ? ad1 : as1;
  float s = 0.f;
  for (int c = 0; c < 64; c++) s += W1[k * 256 + h * 64 + c] * a[h * 64 + c];
  (half ? Wd1 : Ws1)[k * 4 + h] = s;
}

// ---------------- precompute: Was2/Wad2[256][4] = W2 . a_{s,d}2 ----------------
__global__ void k_prep2(const float* __restrict__ W2, const float* __restrict__ as2,
                        const float* __restrict__ ad2,
                        float* __restrict__ Was2, float* __restrict__ Wad2)
{
  int g = blockIdx.x * 256 + threadIdx.x;    // 0..2047
  if (g >= 2048) return;
  int half = g >= 1024, r = g & 1023;
  int i = r >> 2, h = r & 3;
  const float* a = half ? ad2 : as2;
  float s = 0.f;
  for (int c = 0; c < 64; c++) s += W2[(size_t)i * 256 + h * 64 + c] * a[h * 64 + c];
  (half ? Wad2 : Was2)[i * 4 + h] = s;
}

// ---------------- precompute fused BN scale/shift: y*A + B ----------------
__global__ void k_prep_bn(const float* __restrict__ bi1, const float* __restrict__ g1,
                          const float* __restrict__ b1, const float* __restrict__ m1,
                          const float* __restrict__ v1,
                          const float* __restrict__ bi2, const float* __restrict__ g2,
                          const float* __restrict__ b2, const float* __restrict__ m2,
                          const float* __restrict__ v2,
                          float* __restrict__ A1, float* __restrict__ B1,
                          float* __restrict__ A2, float* __restrict__ B2)
{
  int c = threadIdx.x;
  if (c < 256) {
    float a = rsqrtf(v1[c] + BN_EPS) * g1[c];
    A1[c] = a; B1[c] = (bi1[c] - m1[c]) * a + b1[c];
    a = rsqrtf(v2[c] + BN_EPS) * g2[c];
    A2[c] = a; B2[c] = (bi2[c] - m2[c]) * a + b2[c];
  }
}

// ---------------- es1/ed1 = x @ Ws1/Wd1 ----------------
__global__ void k_es1(const float* __restrict__ x, const float* __restrict__ Ws1,
                      const float* __restrict__ Wd1,
                      float* __restrict__ es, float* __restrict__ ed, int n)
{
  int t = blockIdx.x * 256 + threadIdx.x;
  if (t >= n) return;
  float xr[10];
  #pragma unroll
  for (int k = 0; k < 10; k++) xr[k] = x[(size_t)t * 10 + k];
  float e0[4] = {0,0,0,0}, e1[4] = {0,0,0,0};
  #pragma unroll
  for (int k = 0; k < 10; k++) {
    #pragma unroll
    for (int h = 0; h < 4; h++) {
      e0[h] += xr[k] * Ws1[k * 4 + h];
      e1[h] += xr[k] * Wd1[k * 4 + h];
    }
  }
  *(float4*)&es[t * 4] = make_float4(e0[0], e0[1], e0[2], e0[3]);
  *(float4*)&ed[t * 4] = make_float4(e1[0], e1[1], e1[2], e1[3]);
}

// ---------------- es2/ed2 = actA(bf16) @ Was2/Wad2 (wave per node) ----------------
__global__ void k_esed2(const unsigned short* __restrict__ act,
                        const float* __restrict__ Was2, const float* __restrict__ Wad2,
                        float* __restrict__ es, float* __restrict__ ed, int n)
{
  int nn = blockIdx.x * 4 + (threadIdx.x >> 6);
  if (nn >= n) return;
  int lane = threadIdx.x & 63;
  short4v av = *(const short4v*)&act[(size_t)nn * 256 + lane * 4];
  float e0[4] = {0,0,0,0}, e1[4] = {0,0,0,0};
  #pragma unroll
  for (int j = 0; j < 4; j++) {
    int c = lane * 4 + j;
    float v = bf2f((unsigned short)av[j]);
    float4 ws = *(const float4*)&Was2[c * 4];
    float4 wd = *(const float4*)&Wad2[c * 4];
    e0[0] += v * ws.x; e0[1] += v * ws.y; e0[2] += v * ws.z; e0[3] += v * ws.w;
    e1[0] += v * wd.x; e1[1] += v * wd.y; e1[2] += v * wd.z; e1[3] += v * wd.w;
  }
  #pragma unroll
  for (int off = 1; off < 64; off <<= 1) {
    #pragma unroll
    for (int h = 0; h < 4; h++) {
      e0[h] += __shfl_xor(e0[h], off, 64);
      e1[h] += __shfl_xor(e1[h], off, 64);
    }
  }
  if (lane == 0) {
    *(float4*)&es[nn * 4] = make_float4(e0[0], e0[1], e0[2], e0[3]);
    *(float4*)&ed[nn * 4] = make_float4(e1[0], e1[1], e1[2], e1[3]);
  }
}

// ---------------- attention: per-dst max + exp store + 1/sum -> sinv ----------------
__global__ void k_att_ms(const int* __restrict__ rowptr, const int* __restrict__ deg,
                         const int* __restrict__ col,
                         const float* __restrict__ es, const float* __restrict__ ed,
                         float* __restrict__ alp, float* __restrict__ sinv, int n)
{
  int d = blockIdx.x * 4 + (threadIdx.x >> 6);
  if (d >= n) return;
  int lane = threadIdx.x & 63;
  int head = lane >> 4, sub = lane & 15;
  int start = rowptr[d], cnt = deg[d];
  float edh = ed[d * 4 + head];

  float m = -1e30f;
  for (int i = sub; i < cnt; i += 16) {
    int s = col[start + i];
    float a = es[s * 4 + head] + edh;
    a = a > 0.f ? a : 0.2f * a;
    m = fmaxf(m, a);
  }
  #pragma unroll
  for (int off = 1; off < 16; off <<= 1) m = fmaxf(m, __shfl_xor(m, off, 16));

  float ssum = 0.f;
  for (int i = sub; i < cnt; i += 16) {
    int s = col[start + i];
    float a = es[s * 4 + head] + edh;
    a = a > 0.f ? a : 0.2f * a;
    float ex = expf(a - m);
    alp[(size_t)(start + i) * 4 + head] = ex;
    ssum += ex;
  }
  #pragma unroll
  for (int off = 1; off < 16; off <<= 1) ssum += __shfl_xor(ssum, off, 16);
  if (sub == 0) sinv[d * 4 + head] = 1.f / (ssum + 1e-16f);
}

// ---------------- layer-1: edge-parallel aggregate of raw x -> xa[N][4][10] ----------
// 4 edge-slots x 16 lanes (k<10 active); each lane carries 4 head-accumulators.
__global__ void k_xagg(const int* __restrict__ rowptr, const int* __restrict__ deg,
                       const int* __restrict__ col, const float* __restrict__ alp,
                       const float* __restrict__ sinv, const float* __restrict__ x,
                       float* __restrict__ xa, int n)
{
  int d = blockIdx.x * 4 + (threadIdx.x >> 6);
  if (d >= n) return;
  int lane = threadIdx.x & 63;
  int slot = lane >> 4, k = lane & 15;
  int start = rowptr[d], cnt = deg[d];
  bool active = (k < 10);

  float a0 = 0.f, a1 = 0.f, a2 = 0.f, a3 = 0.f;
  int i = slot;
  for (; i + 4 < cnt; i += 8) {
    int e0 = start + i, e1 = start + i + 4;
    int s0 = col[e0], s1 = col[e1];
    float4 al0 = *(const float4*)&alp[(size_t)e0 * 4];
    float4 al1 = *(const float4*)&alp[(size_t)e1 * 4];
    float x0 = active ? x[(size_t)s0 * 10 + k] : 0.f;
    float x1 = active ? x[(size_t)s1 * 10 + k] : 0.f;
    a0 += al0.x * x0 + al1.x * x1;
    a1 += al0.y * x0 + al1.y * x1;
    a2 += al0.z * x0 + al1.z * x1;
    a3 += al0.w * x0 + al1.w * x1;
  }
  if (i < cnt) {
    int e0 = start + i;
    int s0 = col[e0];
    float4 al0 = *(const float4*)&alp[(size_t)e0 * 4];
    float x0 = active ? x[(size_t)s0 * 10 + k] : 0.f;
    a0 += al0.x * x0; a1 += al0.y * x0; a2 += al0.z * x0; a3 += al0.w * x0;
  }
  a0 += __shfl_xor(a0, 16, 64); a0 += __shfl_xor(a0, 32, 64);
  a1 += __shfl_xor(a1, 16, 64); a1 += __shfl_xor(a1, 32, 64);
  a2 += __shfl_xor(a2, 16, 64); a2 += __shfl_xor(a2, 32, 64);
  a3 += __shfl_xor(a3, 16, 64); a3 += __shfl_xor(a3, 32, 64);

  if (slot == 0 && active) {
    float4 sv = *(const float4*)&sinv[d * 4];
    float* xo = &xa[(size_t)d * 40];
    xo[k]      = a0 * sv.x;
    xo[10 + k] = a1 * sv.y;
    xo[20 + k] = a2 * sv.z;
    xo[30 + k] = a3 * sv.w;
  }
}

// ---------------- layer-1 GEMM: xa @ W1 (per head) + BN1 + ELU -> actA bf16 -----------
__global__ void k_gemm_xa(const float* __restrict__ xa, const float* __restrict__ W1,
                          const float* __restrict__ A1, const float* __restrict__ B1,
                          unsigned short* __restrict__ actA, int n)
{
  __shared__ float xal[160];
  int tid = threadIdx.x;
  int n0 = blockIdx.x * 4;
  if (tid < 160 && (size_t)n0 * 40 + tid < (size_t)n * 40)
    xal[tid] = xa[(size_t)n0 * 40 + tid];
  __syncthreads();
  int c = tid, h = c >> 6;
  float w[10];
  #pragma unroll
  for (int k = 0; k < 10; k++) w[k] = W1[k * 256 + c];
  float a1 = A1[c], b1 = B1[c];
  #pragma unroll
  for (int m = 0; m < 4; m++) {
    int nn = n0 + m;
    if (nn >= n) break;
    float acc = 0.f;
    #pragma unroll
    for (int k = 0; k < 10; k++) acc += xal[m * 40 + h * 10 + k] * w[k];
    actA[(size_t)nn * 256 + c] = f2bf(eluf(acc * a1 + b1));
  }
}

// ---------------- layer-2 gather: agg2[dst] = (sum ex*act[src]) * sinv, 4x unroll -----
__global__ void k_gat_gather(const int* __restrict__ rowptr, const int* __restrict__ deg,
                             const int* __restrict__ col, const float* __restrict__ alp,
                             const float* __restrict__ sinv,
                             const unsigned short* __restrict__ act,
                             unsigned short* __restrict__ outb, int n)
{
  int d = blockIdx.x * 4 + (threadIdx.x >> 6);
  if (d >= n) return;
  int lane = threadIdx.x & 63;
  int half = lane >> 5, l32 = lane & 31;
  int c8 = l32 * 8, head = l32 >> 3;
  int start = rowptr[d], cnt = deg[d];

  float acc[8] = {0.f,0.f,0.f,0.f,0.f,0.f,0.f,0.f};
  int T = (cnt > half) ? ((cnt - half + 1) >> 1) : 0;
  int ebase = start + half;
  int t = 0;
  for (; t + 4 <= T; t += 4) {
    int e0 = ebase + 2 * t, e1 = e0 + 2, e2 = e0 + 4, e3 = e0 + 6;
    int s0 = col[e0], s1 = col[e1], s2 = col[e2], s3 = col[e3];
    float a0 = alp[(size_t)e0 * 4 + head];
    float a1 = alp[(size_t)e1 * 4 + head];
    float a2 = alp[(size_t)e2 * 4 + head];
    float a3 = alp[(size_t)e3 * 4 + head];
    short8 h0 = *(const short8*)&act[(size_t)s0 * 256 + c8];
    short8 h1 = *(const short8*)&act[(size_t)s1 * 256 + c8];
    short8 h2 = *(const short8*)&act[(size_t)s2 * 256 + c8];
    short8 h3 = *(const short8*)&act[(size_t)s3 * 256 + c8];
    #pragma unroll
    for (int j = 0; j < 8; j++) {
      acc[j] += bf2f((unsigned short)h0[j]) * a0 + bf2f((unsigned short)h1[j]) * a1
              + bf2f((unsigned short)h2[j]) * a2 + bf2f((unsigned short)h3[j]) * a3;
    }
  }
  for (; t < T; t++) {
    int e0 = ebase + 2 * t;
    int s0 = col[e0];
    float a0 = alp[(size_t)e0 * 4 + head];
    short8 h0 = *(const short8*)&act[(size_t)s0 * 256 + c8];
    #pragma unroll
    for (int j = 0; j < 8; j++) acc[j] += bf2f((unsigned short)h0[j]) * a0;
  }
  #pragma unroll
  for (int j = 0; j < 8; j++)
    acc[j] += __shfl_xor(acc[j], 32, 64);

  if (half == 0) {
    float sv = sinv[d * 4 + head];
    short8 o;
    #pragma unroll
    for (int j = 0; j < 8; j++) o[j] = (short)f2bf(acc[j] * sv);
    *(short8*)&outb[(size_t)d * 256 + c8] = o;
  }
}

// ---------------- MFMA GEMM with LDS-staged B; optional fused BN+ELU epilogue ---------
template<int NCT, bool BNEPI>
__global__ __launch_bounds__(256) void k_mfma_gemm(
    const unsigned short* __restrict__ act, const unsigned short* __restrict__ Wp,
    unsigned short* __restrict__ outb,
    const float* __restrict__ Abn, const float* __restrict__ Bbn, int n)
{
  __shared__ unsigned short bsh[NCT * 512];
  int tid = threadIdx.x, wave = tid >> 6, lane = tid & 63;
  int l15 = lane & 15, lg = lane >> 4;
  int rbase = blockIdx.x * 64 + wave * 16;
  int arow = rbase + l15; if (arow > n - 1) arow = n - 1;
  const unsigned short* ap = &act[(size_t)arow * 256 + lg * 8];

  constexpr int NCH = (NCT >= 4) ? NCT / 4 : 1;
  f32x4 acc[NCT];
  f32x4 z = {0.f, 0.f, 0.f, 0.f};
  #pragma unroll
  for (int ct = 0; ct < NCT; ct++) acc[ct] = z;

  for (int ks = 0; ks < 8; ks++) {
    const unsigned short* src = Wp + (size_t)ks * NCT * 512 + wave * NCT * 128;
    short8 stg[NCH];
    #pragma unroll
    for (int c = 0; c < NCH; c++)
      stg[c] = *(const short8*)(src + c * 512 + lane * 8);
    short8 a = *(const short8*)(ap + ks * 32);
    __syncthreads();
    #pragma unroll
    for (int c = 0; c < NCH; c++)
      *(short8*)&bsh[wave * NCT * 128 + c * 512 + lane * 8] = stg[c];
    __syncthreads();
    #pragma unroll
    for (int ct = 0; ct < NCT; ct++) {
      short8 b = *(const short8*)&bsh[(ct * 64 + lane) * 8];
      acc[ct] = __builtin_amdgcn_mfma_f32_16x16x32_bf16(a, b, acc[ct], 0, 0, 0);
    }
  }

  float abn[NCT], bbn[NCT];
  if (BNEPI) {
    #pragma unroll
    for (int ct = 0; ct < NCT; ct++) {
      abn[ct] = Abn[ct * 16 + l15];
      bbn[ct] = Bbn[ct * 16 + l15];
    }
  }
  #pragma unroll
  for (int r = 0; r < 4; r++) {
    int row = rbase + lg * 4 + r;
    if (row < n) {
      #pragma unroll
      for (int ct = 0; ct < NCT; ct++) {
        float v = acc[ct][r];
        if (BNEPI) v = eluf(v * abn[ct] + bbn[ct]);
        outb[(size_t)row * (NCT * 16) + ct * 16 + l15] = f2bf(v);
      }
    }
  }
}

// ---------------- GCN gather: 8-edge unrolled + BN/ELU -> fp32 hout ----------------
__global__ void k_gcn_gather(const int* __restrict__ rowptr, const int* __restrict__ deg,
                             const int* __restrict__ col, const float* __restrict__ dinv,
                             const unsigned short* __restrict__ xwb,
                             const float* __restrict__ bias,
                             const float* __restrict__ gg, const float* __restrict__ bb,
                             const float* __restrict__ mm, const float* __restrict__ vv,
                             float* __restrict__ hout, int n)
{
  int d = blockIdx.x * 4 + (threadIdx.x >> 6);
  if (d >= n) return;
  int lane = threadIdx.x & 63;
  int slot = lane >> 3, cg = (lane & 7) * 8;
  int start = rowptr[d], cnt = deg[d];
  float dinvd = rsqrtf(fmaxf((float)cnt, 1.f));

  float acc[8] = {0.f,0.f,0.f,0.f,0.f,0.f,0.f,0.f};
  for (int i = slot; i < cnt; i += 8) {
    int s = col[start + i];
    float norm = dinv[s] * dinvd;
    short8 hv = *(const short8*)&xwb[(size_t)s * 64 + cg];
    #pragma unroll
    for (int j = 0; j < 8; j++)
      acc[j] += bf2f((unsigned short)hv[j]) * norm;
  }
  #pragma unroll
  for (int j = 0; j < 8; j++) {
    acc[j] += __shfl_xor(acc[j], 8, 64);
    acc[j] += __shfl_xor(acc[j], 16, 64);
    acc[j] += __shfl_xor(acc[j], 32, 64);
  }

  if (lane < 8) {
    float out[8];
    #pragma unroll
    for (int j = 0; j < 8; j++) {
      int c = cg + j;
      float r = ((acc[j] + bias[c]) - mm[c]) * rsqrtf(vv[c] + BN_EPS) * gg[c] + bb[c];
      out[j] = eluf(r);
    }
    *(float4*)&hout[(size_t)d * 64 + cg]     = make_float4(out[0], out[1], out[2], out[3]);
    *(float4*)&hout[(size_t)d * 64 + cg + 4] = make_float4(out[4], out[5], out[6], out[7]);
  }
}

// ---------------- pooling: per-wave run accumulation, rare flushes ----------------
__global__ void k_pool_partial(const float* __restrict__ hout, const int* __restrict__ batch,
                               float* __restrict__ psum, unsigned* __restrict__ pmaxu,
                               int n)
{
  int wave = threadIdx.x >> 6, lane = threadIdx.x & 63;
  int wbase = blockIdx.x * 128 + wave * 32;
  int wend = wbase + 32; if (wend > n) wend = n;
  if (wbase >= n) return;

  int g_cur = -1;
  float s = 0.f, mx = -1e30f;
  for (int node = wbase; node < wend; node++) {
    int g = batch[node];
    if (g != g_cur) {
      if (g_cur >= 0) {
        atomicAdd(&psum[g_cur * 64 + lane], s);
        atomicMax(&pmaxu[g_cur * 64 + lane], fmap(mx));
      }
      g_cur = g; s = 0.f; mx = -1e30f;
    }
    float v = hout[(size_t)node * 64 + lane];
    s += v;
    mx = fmaxf(mx, v);
  }
  if (g_cur >= 0) {
    atomicAdd(&psum[g_cur * 64 + lane], s);
    atomicMax(&pmaxu[g_cur * 64 + lane], fmap(mx));
  }
}

// ---------------- heads: one block (64 thr) per graph ----------------
__global__ void k_heads(const float* __restrict__ psum, const unsigned* __restrict__ pmaxu,
                        const int* __restrict__ batch,
                        const float* __restrict__ Wr, const float* __restrict__ br,
                        const float* __restrict__ Wh1, const float* __restrict__ bh1,
                        const float* __restrict__ Wh2, const float* __restrict__ bh2,
                        const float* __restrict__ Wh3, const float* __restrict__ bh3,
                        const float* __restrict__ Wl1, const float* __restrict__ bl1,
                        const float* __restrict__ Wl2, const float* __restrict__ bl2,
                        const float* __restrict__ We1, const float* __restrict__ be1,
                        const float* __restrict__ We2, const float* __restrict__ be2,
                        float* __restrict__ outp, int n, int xg_off)
{
  __shared__ float cat[128], xg[64], t1[32], t2[16], l1[32], e1[16];
  int g = blockIdx.x, c = threadIdx.x;  // 64 threads

  int lo = 0, hi = n;
  while (lo < hi) { int mid = (lo + hi) >> 1; if (batch[mid] < g) lo = mid + 1; else hi = mid; }
  int start = lo;
  lo = start; hi = n;
  while (lo < hi) { int mid = (lo + hi) >> 1; if (batch[mid] < g + 1) lo = mid + 1; else hi = mid; }
  int cntg = lo - start;

  float mean = psum[g * 64 + c] / fmaxf((float)cntg, 1.f);
  float mxv = (cntg > 0) ? funmap(pmaxu[g * 64 + c]) : 0.f;
  cat[c] = mean; cat[64 + c] = mxv;
  __syncthreads();
  float a = br[c];
  for (int i = 0; i < 128; i++) a += cat[i] * Wr[i * 64 + c];
  xg[c] = a;
  outp[xg_off + g * 64 + c] = a;
  __syncthreads();
  if (c < 32) {
    float u = bh1[c]; for (int i = 0; i < 64; i++) u += xg[i] * Wh1[i * 32 + c];
    t1[c] = fmaxf(u, 0.f);
    float v = bl1[c]; for (int i = 0; i < 64; i++) v += xg[i] * Wl1[i * 32 + c];
    l1[c] = fmaxf(v, 0.f);
  }
  __syncthreads();
  if (c < 16) {
    float u = bh2[c]; for (int i = 0; i < 32; i++) u += t1[i] * Wh2[i * 16 + c];
    t2[c] = fmaxf(u, 0.f);
    float v = be1[c]; for (int i = 0; i < 64; i++) v += xg[i] * We1[i * 16 + c];
    e1[c] = fmaxf(v, 0.f);
  }
  __syncthreads();
  if (c < 8) {
    float v = bl2[c]; for (int i = 0; i < 32; i++) v += l1[i] * Wl2[i * 8 + c];
    outp[64 + g * 8 + c] = v;
  }
  if (c == 0) {
    float u = bh3[0]; for (int i = 0; i < 16; i++) u += t2[i] * Wh3[i];
    outp[g] = 100.f / (1.f + expf(-u));
    float v = be2[0]; for (int i = 0; i < 16; i++) v += e1[i] * We2[i];
    outp[576 + g] = v;
  }
}

extern "C" void kernel_launch(void* const* d_in, const int* in_sizes, int n_in,
                              void* d_out, int out_size, void* d_ws, size_t ws_size,
                              hipStream_t stream)
{
  const float* x    = (const float*)d_in[0];
  const int*   ei   = (const int*)d_in[1];
  const int*   batch= (const int*)d_in[2];
  const float* W1   = (const float*)d_in[3];
  const float* as1  = (const float*)d_in[4];
  const float* ad1  = (const float*)d_in[5];
  const float* bi1  = (const float*)d_in[6];
  const float* W2   = (const float*)d_in[7];
  const float* as2  = (const float*)d_in[8];
  const float* ad2  = (const float*)d_in[9];
  const float* bi2  = (const float*)d_in[10];
  const float* bn1g = (const float*)d_in[11];
  const float* bn1b = (const float*)d_in[12];
  const float* bn1m = (const float*)d_in[13];
  const float* bn1v = (const float*)d_in[14];
  const float* bn2g = (const float*)d_in[15];
  const float* bn2b = (const float*)d_in[16];
  const float* bn2m = (const float*)d_in[17];
  const float* bn2v = (const float*)d_in[18];
  const float* bn3g = (const float*)d_in[19];
  const float* bn3b = (const float*)d_in[20];
  const float* bn3m = (const float*)d_in[21];
  const float* bn3v = (const float*)d_in[22];
  const float* Wg   = (const float*)d_in[23];
  const float* bg   = (const float*)d_in[24];
  const float* Wr   = (const float*)d_in[25];
  const float* br   = (const float*)d_in[26];
  const float* Wh1  = (const float*)d_in[27];
  const float* bh1  = (const float*)d_in[28];
  const float* Wh2  = (const float*)d_in[29];
  const float* bh2  = (const float*)d_in[30];
  const float* Wh3  = (const float*)d_in[31];
  const float* bh3  = (const float*)d_in[32];
  const float* Wl1  = (const float*)d_in[33];
  const float* bl1  = (const float*)d_in[34];
  const float* Wl2  = (const float*)d_in[35];
  const float* bl2  = (const float*)d_in[36];
  const float* We1  = (const float*)d_in[37];
  const float* be1  = (const float*)d_in[38];
  const float* We2  = (const float*)d_in[39];
  const float* be2  = (const float*)d_in[40];

  const int n  = in_sizes[2];         // 50000 nodes
  const int ne = in_sizes[1] / 2;     // 500000 edges
  const int e2 = ne + n;              // with self-loops

  float* ws = (float*)d_ws;
  size_t off = 0;
  unsigned short* bufA = (unsigned short*)(ws + off); off += (size_t)n * 128; // actA / actB
  unsigned short* bufB = (unsigned short*)(ws + off); off += (size_t)n * 128; // agg2 / xwb
  float* xa   = ws + off; off += (size_t)n * 40;
  float* es   = ws + off; off += (size_t)n * 4;
  float* ed   = ws + off; off += (size_t)n * 4;
  float* alp  = ws + off; off += (size_t)e2 * 4;
  float* sinv = ws + off; off += (size_t)n * 4;
  float* dinv = ws + off; off += (size_t)n;
  int* rowptr = (int*)(ws + off); off += (size_t)n + 1;
  int* deg    = (int*)(ws + off); off += (size_t)n;
  int* cursor = (int*)(ws + off); off += (size_t)n;
  int* col    = (int*)(ws + off); off += (size_t)e2;
  int* partials = (int*)(ws + off); off += 64;
  unsigned short* Wp2 = (unsigned short*)(ws + off); off += 32768;  // 65536 bf16
  unsigned short* Wpg = (unsigned short*)(ws + off); off += 8192;   // 16384 bf16
  float* Ws1  = ws + off; off += 40;
  float* Wd1  = ws + off; off += 40;
  float* Was2 = ws + off; off += 1024;
  float* Wad2 = ws + off; off += 1024;
  float* A1   = ws + off; off += 256;
  float* B1   = ws + off; off += 256;
  float* A2   = ws + off; off += 256;
  float* B2   = ws + off; off += 256;
  float* psum = ws + off; off += 64 * 64;
  unsigned* pmaxu = (unsigned*)(ws + off); off += 64 * 64;

  unsigned short* actA = bufA;
  unsigned short* agg2 = bufB;
  unsigned short* actB = bufA;   // actA dead after gather + esed2
  unsigned short* xwb  = bufB;   // agg2 dead after layer-2 GEMM

  float* outp = (float*)d_out;
  float* hout = outp + 640;            // node embeddings region
  const int xg_off = 640 + n * 64;

  const int eb   = (e2 + 255) / 256;
  const int gb1  = (n + 3) / 4;
  const int gmb  = (n + 63) / 64;
  const int nsb  = (n + SCAN_BLK - 1) / SCAN_BLK;

  // ---------- CSR build + precomputes ----------
  hipMemsetAsync(deg, 0, (size_t)n * sizeof(int), stream);
  hipMemsetAsync(cursor, 0, (size_t)n * sizeof(int), stream);
  k_count<<<eb, 256, 0, stream>>>(ei, deg, ne, e2);
  k_scan1<<<nsb, SCAN_BLK, 0, stream>>>(deg, rowptr, partials, n);
  k_scan2<<<nsb, SCAN_BLK, 0, stream>>>(rowptr, partials, n);
  k_fill<<<eb, 256, 0, stream>>>(ei, rowptr, cursor, col, ne, e2);
  k_dinv<<<(n + 255) / 256, 256, 0, stream>>>(deg, dinv, n);
  k_pack<<<128, 512, 0, stream>>>(W2, Wp2, 256, 16);
  k_pack<<<32, 512, 0, stream>>>(Wg, Wpg, 64, 4);
  k_prep1<<<1, 128, 0, stream>>>(W1, as1, ad1, Ws1, Wd1);
  k_prep2<<<8, 256, 0, stream>>>(W2, as2, ad2, Was2, Wad2);
  k_prep_bn<<<1, 256, 0, stream>>>(bi1, bn1g, bn1b, bn1m, bn1v,
                                   bi2, bn2g, bn2b, bn2m, bn2v,
                                   A1, B1, A2, B2);

  // ---------- GAT layer 1 (aggregate-first) ----------
  k_es1<<<(n + 255) / 256, 256, 0, stream>>>(x, Ws1, Wd1, es, ed, n);
  k_att_ms<<<gb1, 256, 0, stream>>>(rowptr, deg, col, es, ed, alp, sinv, n);
  k_xagg<<<gb1, 256, 0, stream>>>(rowptr, deg, col, alp, sinv, x, xa, n);
  k_gemm_xa<<<gb1, 256, 0, stream>>>(xa, W1, A1, B1, actA, n);

  // ---------- GAT layer 2 (aggregate-first) ----------
  k_esed2<<<gb1, 256, 0, stream>>>(actA, Was2, Wad2, es, ed, n);
  k_att_ms<<<gb1, 256, 0, stream>>>(rowptr, deg, col, es, ed, alp, sinv, n);
  k_gat_gather<<<gb1, 256, 0, stream>>>(rowptr, deg, col, alp, sinv, actA, agg2, n);
  k_mfma_gemm<16, true><<<gmb, 256, 0, stream>>>(agg2, Wp2, actB, A2, B2, n);

  // ---------- GCN ----------
  k_mfma_gemm<4, false><<<gmb, 256, 0, stream>>>(actB, Wpg, xwb, nullptr, nullptr, n);
  k_gcn_gather<<<gb1, 256, 0, stream>>>(rowptr, deg, col, dinv, xwb,
                                        bg, bn3g, bn3b, bn3m, bn3v, hout, n);

  // ---------- pooling + heads ----------
  hipMemsetAsync(psum, 0, 64 * 64 * sizeof(float), stream);
  hipMemsetAsync(pmaxu, 0, 64 * 64 * sizeof(unsigned), stream);
  k_pool_partial<<<(n + 127) / 128, 256, 0, stream>>>(hout, batch, psum, pmaxu, n);
  k_heads<<<64, 64, 0, stream>>>(psum, pmaxu, batch, Wr, br,
                                 Wh1, bh1, Wh2, bh2, Wh3, bh3,
                                 Wl1, bl1, Wl2, bl2, We1, be1, We2, be2,
                                 outp, n, xg_off);
}